// Round 8
// baseline (775.315 us; speedup 1.0000x reference)
//
#include <hip/hip_runtime.h>
#include <math.h>

#define B 8
#define N 8192
#define S 2048
#define C 256
#define CIN 512
#define CNT (B * N)  // 65536

typedef __attribute__((ext_vector_type(8))) short bf16x8;
typedef __attribute__((ext_vector_type(4))) float floatx4;
typedef __attribute__((ext_vector_type(8))) unsigned short ushort8v;
typedef __attribute__((ext_vector_type(4))) unsigned short ushort4v;

__device__ inline unsigned short f2bf(float f) {
  unsigned u = __builtin_bit_cast(unsigned, f);
  u += 0x7FFF + ((u >> 16) & 1);  // RNE
  return (unsigned short)(u >> 16);
}
__device__ inline float bf2f(unsigned short h) {
  unsigned u = ((unsigned)h) << 16;
  return __builtin_bit_cast(float, u);
}

__device__ inline void load_lds16(const void* g, void* l) {
  __builtin_amdgcn_global_load_lds(
      (const __attribute__((address_space(1))) unsigned int*)g,
      (__attribute__((address_space(3))) unsigned int*)l, 16, 0, 0);
}

// ---------------- 3-NN v8: r7 algorithm + __launch_bounds__(256,4) ----------------
// r7 root-cause: allocator capped VGPRs at <=64 (8 waves/SIMD target) and spilled
// ~55-60 live regs to scratch (WRITE_SIZE 52MB). LDS already caps occupancy at
// 5 blocks/CU, so min-4-waves/EU (VGPR cap 128) costs nothing and kills the spill.
__device__ inline void ins3u(unsigned long long k, unsigned long long& k0,
                             unsigned long long& k1, unsigned long long& k2) {
  if (k < k2) {
    if (k < k1) {
      k2 = k1;
      if (k < k0) { k1 = k0; k0 = k; } else k1 = k;
    } else k2 = k;
  }
}

#define QDECL(q)                                                            \
  float d0_##q = INFINITY, d1_##q = INFINITY, d2_##q = INFINITY;            \
  int i0_##q = 0, i1_##q = 0, i2_##q = 0;                                   \
  float qx_##q, qy_##q, qz_##q, q2_##q;

#define QLOAD(q)                                                            \
  {                                                                         \
    float ox = p1[nq + q], oy = p1[N + nq + q], oz = p1[2 * N + nq + q];    \
    q2_##q = ox * ox + oy * oy + oz * oz;                                   \
    qx_##q = -2.0f * ox; qy_##q = -2.0f * oy; qz_##q = -2.0f * oz;          \
  }

#define QINS(q)                                                             \
  {                                                                         \
    float d = fmaf(qx_##q, p.x,                                             \
                   fmaf(qy_##q, p.y, fmaf(qz_##q, p.z, p.w))) + q2_##q;     \
    bool lt0 = d < d0_##q, lt1 = d < d1_##q, lt2 = d < d2_##q;              \
    d2_##q = lt2 ? (lt1 ? d1_##q : d) : d2_##q;                             \
    i2_##q = lt2 ? (lt1 ? i1_##q : s) : i2_##q;                             \
    d1_##q = lt1 ? (lt0 ? d0_##q : d) : d1_##q;                             \
    i1_##q = lt1 ? (lt0 ? i0_##q : s) : i1_##q;                             \
    d0_##q = lt0 ? d : d0_##q;                                              \
    i0_##q = lt0 ? s : i0_##q;                                              \
  }

#define QPACK(q)                                                            \
  unsigned long long k0_##q =                                               \
      ((unsigned long long)__float_as_uint(d0_##q) << 32) | (unsigned)i0_##q; \
  unsigned long long k1_##q =                                               \
      ((unsigned long long)__float_as_uint(d1_##q) << 32) | (unsigned)i1_##q; \
  unsigned long long k2_##q =                                               \
      ((unsigned long long)__float_as_uint(d2_##q) << 32) | (unsigned)i2_##q;

#define QMSTEP(q, m)                                                        \
  {                                                                         \
    unsigned long long e0 = (unsigned long long)__shfl_xor((long long)k0_##q, m); \
    unsigned long long e1 = (unsigned long long)__shfl_xor((long long)k1_##q, m); \
    unsigned long long e2 = (unsigned long long)__shfl_xor((long long)k2_##q, m); \
    ins3u(e0, k0_##q, k1_##q, k2_##q);                                      \
    ins3u(e1, k0_##q, k1_##q, k2_##q);                                      \
    ins3u(e2, k0_##q, k1_##q, k2_##q);                                      \
  }

#define QOUT(q)                                                             \
  {                                                                         \
    float e0 = fmaxf(__uint_as_float((unsigned)(k0_##q >> 32)) - 1.0f, 0.0f); \
    float e1 = fmaxf(__uint_as_float((unsigned)(k1_##q >> 32)) - 1.0f, 0.0f); \
    float e2 = fmaxf(__uint_as_float((unsigned)(k2_##q >> 32)) - 1.0f, 0.0f); \
    float r0 = 1.0f / (e0 + 1e-8f);                                         \
    float r1 = 1.0f / (e1 + 1e-8f);                                         \
    float r2 = 1.0f / (e2 + 1e-8f);                                         \
    float rs = 1.0f / (r0 + r1 + r2);                                       \
    size_t o = ((size_t)b * N + nq + q) * 3;                                \
    idxbuf[o] = (int)(unsigned)k0_##q;                                      \
    idxbuf[o + 1] = (int)(unsigned)k1_##q;                                  \
    idxbuf[o + 2] = (int)(unsigned)k2_##q;                                  \
    wbuf[o] = r0 * rs; wbuf[o + 1] = r1 * rs; wbuf[o + 2] = r2 * rs;        \
  }

__global__ __launch_bounds__(256, 4) void nn3_kernel(const float* __restrict__ xyz1,
                                                     const float* __restrict__ xyz2,
                                                     int* __restrict__ idxbuf,
                                                     float* __restrict__ wbuf) {
  __shared__ float4 sp[S];  // {x,y,z,|p|^2 + 1}  32KB
  int b = blockIdx.x >> 7;            // grid = B * (N/64) = 1024
  int n0 = (blockIdx.x & 127) * 64;
  const float* p2 = xyz2 + (size_t)b * 3 * S;
  for (int i = threadIdx.x; i < S; i += 256) {
    float px = p2[i], py = p2[S + i], pz = p2[2 * S + i];
    sp[i] = make_float4(px, py, pz, px * px + py * py + pz * pz + 1.0f);
  }
  __syncthreads();
  int tid = threadIdx.x;
  int sub = tid & 15, grp = tid >> 4;  // 16 qgroups x 4 queries = 64 queries/block
  const float* p1 = xyz1 + (size_t)b * 3 * N;
  int nq = n0 + grp * 4;
  QDECL(0) QDECL(1) QDECL(2) QDECL(3)
  QLOAD(0) QLOAD(1) QLOAD(2) QLOAD(3)

  for (int t = 0; t < S / 16; ++t) {
    int s = t * 16 + sub;
    float4 p = sp[s];
    QINS(0) QINS(1) QINS(2) QINS(3)
  }

  QPACK(0) QPACK(1) QPACK(2) QPACK(3)
#pragma unroll
  for (int m = 1; m <= 8; m <<= 1) {
    QMSTEP(0, m) QMSTEP(1, m) QMSTEP(2, m) QMSTEP(3, m)
  }
  if (sub == 0) {
    QOUT(0) QOUT(1) QOUT(2) QOUT(3)
  }
}

// ---------------- weights f32 -> bf16 ----------------
__global__ __launch_bounds__(256) void convw_kernel(const float* __restrict__ w0,
                                                    const float* __restrict__ w1,
                                                    unsigned short* __restrict__ w0b,
                                                    unsigned short* __restrict__ w1b) {
  int i = blockIdx.x * 256 + threadIdx.x;
  if (i < C * CIN) w0b[i] = f2bf(w0[i]);
  else {
    int j = i - C * CIN;
    if (j < C * C) w1b[j] = f2bf(w1[j]);
  }
}

// ---------------- transpose+convert: src[b][256][cols] f32 -> dst[b][cols][drow] bf16 ----------------
__global__ __launch_bounds__(256) void tconv_kernel(const float* __restrict__ src,
                                                    unsigned short* __restrict__ dst,
                                                    int cols, int drow, int coff) {
  __shared__ float t[64][65];
  int n0 = blockIdx.x * 64, c0 = blockIdx.y * 64, b = blockIdx.z;
  int tid = threadIdx.x, r = tid >> 2, q = tid & 3;
  const float* sp = src + ((size_t)b * 256 + c0 + r) * cols + n0 + q * 16;
#pragma unroll
  for (int i = 0; i < 4; ++i) {
    float4 v = *(const float4*)(sp + i * 4);
    t[r][q * 16 + i * 4 + 0] = v.x;
    t[r][q * 16 + i * 4 + 1] = v.y;
    t[r][q * 16 + i * 4 + 2] = v.z;
    t[r][q * 16 + i * 4 + 3] = v.w;
  }
  __syncthreads();
  unsigned short* dp = dst + ((size_t)b * cols + n0 + r) * drow + coff + c0 + q * 16;
  ushort8v o0, o1;
#pragma unroll
  for (int i = 0; i < 8; ++i) o0[i] = f2bf(t[q * 16 + i][r]);
#pragma unroll
  for (int i = 0; i < 8; ++i) o1[i] = f2bf(t[q * 16 + 8 + i][r]);
  *(ushort8v*)dp = o0;
  *(ushort8v*)(dp + 8) = o1;
}

// ---------------- gather: Xb[b][n][256+c] = sum_j w_j * p2t[b][idx_j][c] ----------------
__global__ __launch_bounds__(256) void gather_kernel(const unsigned short* __restrict__ p2t,
                                                     const int* __restrict__ idxbuf,
                                                     const float* __restrict__ wbuf,
                                                     unsigned short* __restrict__ Xb) {
  __shared__ int si[192];
  __shared__ float sw[192];
  int b = blockIdx.x >> 7;  // grid = B * (N/64)
  int n0 = (blockIdx.x & 127) * 64;
  size_t base = ((size_t)b * N + n0) * 3;
  if (threadIdx.x < 192) {
    si[threadIdx.x] = idxbuf[base + threadIdx.x];
    sw[threadIdx.x] = wbuf[base + threadIdx.x];
  }
  __syncthreads();
  int nl = threadIdx.x >> 2, cb = threadIdx.x & 3;
  int j0 = si[nl * 3], j1 = si[nl * 3 + 1], j2 = si[nl * 3 + 2];
  float w0 = sw[nl * 3], w1 = sw[nl * 3 + 1], w2 = sw[nl * 3 + 2];
  const unsigned short* pb = p2t + (size_t)b * S * 256;
  const unsigned short* r0p = pb + (size_t)j0 * 256;
  const unsigned short* r1p = pb + (size_t)j1 * 256;
  const unsigned short* r2p = pb + (size_t)j2 * 256;
  unsigned short* xp = Xb + ((size_t)b * N + n0 + nl) * 512 + 256;
#pragma unroll
  for (int ch = 0; ch < 8; ++ch) {
    int co = (cb + ch * 4) * 8;
    ushort8v v0 = *(const ushort8v*)(r0p + co);
    ushort8v v1 = *(const ushort8v*)(r1p + co);
    ushort8v v2 = *(const ushort8v*)(r2p + co);
    ushort8v o;
#pragma unroll
    for (int i = 0; i < 8; ++i)
      o[i] = f2bf(w0 * bf2f(v0[i]) + w1 * bf2f(v1[i]) + w2 * bf2f(v2[i]));
    *(ushort8v*)(xp + co) = o;
  }
}

// ---------------- bf16 MFMA GEMM + per-block partial stats (NO atomics) ----------------
// Y[b][n][o] = bias[o] + sum_k W[o][k] X[b][n][k].
// Each wave writes its 64-channel partial sums over its 64 n-values to a unique
// slot of psum/psumsq [1024 blocks][2 wn][128 ch] — every slot written exactly
// once, no memset, no contention (r3 lesson: atomics were the regression).
__global__ __launch_bounds__(256) void gemm_kernel(const unsigned short* __restrict__ X,
                                                   const unsigned short* __restrict__ Wb,
                                                   const float* __restrict__ bias,
                                                   unsigned short* __restrict__ Y,
                                                   float* __restrict__ psum,
                                                   float* __restrict__ psumsq,
                                                   int Cin) {
  __shared__ unsigned short As[128 * 32];  // [o_row][k] 8KB, swizzled
  __shared__ unsigned short Bs[128 * 32];  // [n_row][k] 8KB, swizzled
  int n0 = blockIdx.x * 128, o0 = blockIdx.y * 128, b = blockIdx.z;
  int tid = threadIdx.x, lane = tid & 63, wid = tid >> 6;
  int wm = wid >> 1, wn = wid & 1;
  floatx4 acc[4][4];
#pragma unroll
  for (int m = 0; m < 4; ++m)
#pragma unroll
    for (int nt = 0; nt < 4; ++nt) acc[m][nt] = (floatx4)(0.0f);

  size_t rsA = (size_t)Cin * 2;  // row stride bytes
  int chunkSwz = ((lane & 3) ^ ((lane >> 3) & 3)) * 16;
  const char* Abase = (const char*)Wb + (size_t)(o0 + wid * 32 + (lane >> 2)) * rsA + chunkSwz;
  const char* Bbase = (const char*)X + ((size_t)b * N + n0 + wid * 32 + (lane >> 2)) * rsA + chunkSwz;
  size_t rstep16 = 16 * rsA;
  int kq = (((lane >> 4) ^ ((lane >> 1) & 3))) * 8;

  for (int k0 = 0; k0 < Cin; k0 += 32) {
    load_lds16(Abase + (size_t)k0 * 2, &As[(wid * 32) * 32]);
    load_lds16(Abase + (size_t)k0 * 2 + rstep16, &As[(wid * 32 + 16) * 32]);
    load_lds16(Bbase + (size_t)k0 * 2, &Bs[(wid * 32) * 32]);
    load_lds16(Bbase + (size_t)k0 * 2 + rstep16, &Bs[(wid * 32 + 16) * 32]);
    __syncthreads();
    bf16x8 af[4], bfv[4];
#pragma unroll
    for (int m = 0; m < 4; ++m)
      af[m] = *(const bf16x8*)&As[(wm * 64 + m * 16 + (lane & 15)) * 32 + kq];
#pragma unroll
    for (int nt = 0; nt < 4; ++nt)
      bfv[nt] = *(const bf16x8*)&Bs[(wn * 64 + nt * 16 + (lane & 15)) * 32 + kq];
#pragma unroll
    for (int m = 0; m < 4; ++m)
#pragma unroll
      for (int nt = 0; nt < 4; ++nt)
        acc[m][nt] = __builtin_amdgcn_mfma_f32_16x16x32_bf16(af[m], bfv[nt], acc[m][nt], 0, 0, 0);
    __syncthreads();
  }

  int col = lane & 15, rowq = lane >> 4;
  // partial-stats slot base: [((b*2+by)*64+bx)*2+wn][128]
  size_t pbase = (size_t)((((size_t)b * 2 + blockIdx.y) * 64 + blockIdx.x) * 2 + wn) * 128;
#pragma unroll
  for (int m = 0; m < 4; ++m) {
    int ob = o0 + wm * 64 + m * 16 + rowq * 4;
    float4 bs = *(const float4*)&bias[ob];
    float sj[4] = {0.f, 0.f, 0.f, 0.f}, qj[4] = {0.f, 0.f, 0.f, 0.f};
#pragma unroll
    for (int nt = 0; nt < 4; ++nt) {
      int n = n0 + wn * 64 + nt * 16 + col;
      float y0 = acc[m][nt][0] + bs.x;
      float y1 = acc[m][nt][1] + bs.y;
      float y2 = acc[m][nt][2] + bs.z;
      float y3 = acc[m][nt][3] + bs.w;
      ushort4v v;
      v[0] = f2bf(y0); v[1] = f2bf(y1); v[2] = f2bf(y2); v[3] = f2bf(y3);
      *(ushort4v*)&Y[((size_t)b * N + n) * 256 + ob] = v;
      sj[0] += y0; qj[0] = fmaf(y0, y0, qj[0]);
      sj[1] += y1; qj[1] = fmaf(y1, y1, qj[1]);
      sj[2] += y2; qj[2] = fmaf(y2, y2, qj[2]);
      sj[3] += y3; qj[3] = fmaf(y3, y3, qj[3]);
    }
#pragma unroll
    for (int j = 0; j < 4; ++j) {
#pragma unroll
      for (int d = 1; d <= 8; d <<= 1) {
        sj[j] += __shfl_xor(sj[j], d);
        qj[j] += __shfl_xor(qj[j], d);
      }
    }
    if (col == 0) {
      int choff = wm * 64 + m * 16 + rowq * 4;
#pragma unroll
      for (int j = 0; j < 4; ++j) {
        psum[pbase + choff + j] = sj[j];
        psumsq[pbase + choff + j] = qj[j];
      }
    }
  }
}

// ---------------- reduce partials -> BN scale/shift ----------------
__global__ void bnparam_kernel(const float* __restrict__ psum,
                               const float* __restrict__ psumsq,
                               const float* __restrict__ gamma,
                               const float* __restrict__ beta,
                               float* __restrict__ scale, float* __restrict__ shift) {
  int c = threadIdx.x;
  int by = c >> 7, choff = c & 127;
  float s = 0.f, q = 0.f;
  for (int bz = 0; bz < 8; ++bz) {
    for (int bx = 0; bx < 64; ++bx) {
#pragma unroll
      for (int wn = 0; wn < 2; ++wn) {
        size_t slot = (size_t)((((size_t)bz * 2 + by) * 64 + bx) * 2 + wn) * 128 + choff;
        s += psum[slot];
        q += psumsq[slot];
      }
    }
  }
  float m = s * (1.0f / CNT);
  float v = q * (1.0f / CNT) - m * m;
  float sc = gamma[c] * rsqrtf(v + 1e-5f);
  scale[c] = sc;
  shift[c] = beta[c] - m * sc;
}

// ---------------- BN+ReLU elementwise on [b][n][256] bf16 -> bf16 ----------------
__global__ __launch_bounds__(256) void bnrelu_kernel(const unsigned short* __restrict__ Y,
                                                     const float* __restrict__ scale,
                                                     const float* __restrict__ shift,
                                                     unsigned short* __restrict__ H) {
  size_t total = (size_t)B * N * 256 / 8;
  for (size_t i = (size_t)blockIdx.x * 256 + threadIdx.x; i < total;
       i += (size_t)gridDim.x * 256) {
    int ob = ((int)i & 31) * 8;
    float4 s0 = *(const float4*)&scale[ob];
    float4 s1 = *(const float4*)&scale[ob + 4];
    float4 h0 = *(const float4*)&shift[ob];
    float4 h1 = *(const float4*)&shift[ob + 4];
    ushort8v v = *(const ushort8v*)&Y[i * 8];
    ushort8v o;
    o[0] = f2bf(fmaxf(fmaf(bf2f(v[0]), s0.x, h0.x), 0.f));
    o[1] = f2bf(fmaxf(fmaf(bf2f(v[1]), s0.y, h0.y), 0.f));
    o[2] = f2bf(fmaxf(fmaf(bf2f(v[2]), s0.z, h0.z), 0.f));
    o[3] = f2bf(fmaxf(fmaf(bf2f(v[3]), s0.w, h0.w), 0.f));
    o[4] = f2bf(fmaxf(fmaf(bf2f(v[4]), s1.x, h1.x), 0.f));
    o[5] = f2bf(fmaxf(fmaf(bf2f(v[5]), s1.y, h1.y), 0.f));
    o[6] = f2bf(fmaxf(fmaf(bf2f(v[6]), s1.z, h1.z), 0.f));
    o[7] = f2bf(fmaxf(fmaf(bf2f(v[7]), s1.w, h1.w), 0.f));
    *(ushort8v*)&H[i * 8] = o;
  }
}

// ---------------- final: BN+ReLU + transpose [b][n][o] bf16 -> out [b][o][n] f32 ----------------
__global__ __launch_bounds__(256) void bnreluT_kernel(const unsigned short* __restrict__ Y,
                                                      const float* __restrict__ scale,
                                                      const float* __restrict__ shift,
                                                      float* __restrict__ out) {
  __shared__ float t[64][65];
  int n0 = blockIdx.x * 64, o0 = blockIdx.y * 64, b = blockIdx.z;
  int tid = threadIdx.x, r = tid >> 2, q = tid & 3;
  const unsigned short* yp = Y + ((size_t)b * N + n0 + r) * 256 + o0 + q * 16;
#pragma unroll
  for (int h = 0; h < 2; ++h) {
    ushort8v v = *(const ushort8v*)(yp + h * 8);
#pragma unroll
    for (int i = 0; i < 8; ++i) {
      int oc = q * 16 + h * 8 + i;
      float f = fmaxf(fmaf(bf2f(v[i]), scale[o0 + oc], shift[o0 + oc]), 0.f);
      t[oc][r] = f;
    }
  }
  __syncthreads();
  float* op = out + ((size_t)b * 256 + o0 + r) * N + n0 + q * 16;
#pragma unroll
  for (int i = 0; i < 4; ++i) {
    float4 v = make_float4(t[r][q * 16 + i * 4 + 0], t[r][q * 16 + i * 4 + 1],
                           t[r][q * 16 + i * 4 + 2], t[r][q * 16 + i * 4 + 3]);
    *(float4*)(op + i * 4) = v;
  }
}

extern "C" void kernel_launch(void* const* d_in, const int* in_sizes, int n_in,
                              void* d_out, int out_size, void* d_ws, size_t ws_size,
                              hipStream_t stream) {
  const float* xyz1 = (const float*)d_in[0];
  const float* xyz2 = (const float*)d_in[1];
  const float* points1 = (const float*)d_in[2];
  const float* points2 = (const float*)d_in[3];
  const float* w0 = (const float*)d_in[4];
  const float* b0 = (const float*)d_in[5];
  const float* g0 = (const float*)d_in[6];
  const float* be0 = (const float*)d_in[7];
  const float* w1 = (const float*)d_in[8];
  const float* b1 = (const float*)d_in[9];
  const float* g1 = (const float*)d_in[10];
  const float* be1 = (const float*)d_in[11];
  float* out = (float*)d_out;

  char* ws = (char*)d_ws;
  int* idxbuf = (int*)ws;              ws += (size_t)CNT * 3 * 4;      // 768KB
  float* wbuf = (float*)ws;            ws += (size_t)CNT * 3 * 4;      // 768KB
  float* scale0 = (float*)ws;          ws += 256 * 4;
  float* shift0 = (float*)ws;          ws += 256 * 4;
  float* scale1 = (float*)ws;          ws += 256 * 4;
  float* shift1 = (float*)ws;          ws += 256 * 4;
  float* psum = (float*)ws;            ws += (size_t)1024 * 2 * 128 * 4;  // 1MB
  float* psumsq = (float*)ws;          ws += (size_t)1024 * 2 * 128 * 4;  // 1MB
  unsigned short* w0b = (unsigned short*)ws;  ws += (size_t)C * CIN * 2;   // 256KB
  unsigned short* w1b = (unsigned short*)ws;  ws += (size_t)C * C * 2;     // 128KB
  unsigned short* p2t = (unsigned short*)ws;  ws += (size_t)B * S * 256 * 2;   // 8MB
  unsigned short* Xb = (unsigned short*)ws;   ws += (size_t)B * N * 512 * 2;   // 64MB
  unsigned short* Yb = (unsigned short*)ws;   ws += (size_t)B * N * 256 * 2;   // 32MB
  unsigned short* Hb = Xb;  // reuse Xb after GEMM0 consumed it

  convw_kernel<<<dim3((C * CIN + C * C) / 256), 256, 0, stream>>>(w0, w1, w0b, w1b);
  tconv_kernel<<<dim3(N / 64, 4, B), 256, 0, stream>>>(points1, Xb, N, 512, 0);
  tconv_kernel<<<dim3(S / 64, 4, B), 256, 0, stream>>>(points2, p2t, S, 256, 0);
  nn3_kernel<<<dim3(B * N / 64), 256, 0, stream>>>(xyz1, xyz2, idxbuf, wbuf);
  gather_kernel<<<dim3(B * N / 64), 256, 0, stream>>>(p2t, idxbuf, wbuf, Xb);
  gemm_kernel<<<dim3(N / 128, 2, B), 256, 0, stream>>>(Xb, w0b, b0, Yb, psum, psumsq, CIN);
  bnparam_kernel<<<1, 256, 0, stream>>>(psum, psumsq, g0, be0, scale0, shift0);
  bnrelu_kernel<<<dim3(2048), 256, 0, stream>>>(Yb, scale0, shift0, Hb);
  gemm_kernel<<<dim3(N / 128, 2, B), 256, 0, stream>>>(Hb, w1b, b1, Yb, psum, psumsq, C);
  bnparam_kernel<<<1, 256, 0, stream>>>(psum, psumsq, g1, be1, scale1, shift1);
  bnreluT_kernel<<<dim3(N / 64, 4, B), 256, 0, stream>>>(Yb, scale1, shift1, out);
}

// Round 9
// 246.911 us; speedup vs baseline: 3.1401x; 3.1401x over previous
//
#include <hip/hip_runtime.h>
#include <math.h>

#define B 8
#define N 8192
#define S 2048
#define C 256
#define CIN 512
#define CNT (B * N)  // 65536
#define NSLOT 1024   // (b*64 + bx)*2 + wn

typedef __attribute__((ext_vector_type(8))) short bf16x8;
typedef __attribute__((ext_vector_type(4))) float floatx4;
typedef __attribute__((ext_vector_type(8))) unsigned short ushort8v;
typedef __attribute__((ext_vector_type(4))) unsigned short ushort4v;

__device__ inline unsigned short f2bf(float f) {
  unsigned u = __builtin_bit_cast(unsigned, f);
  u += 0x7FFF + ((u >> 16) & 1);  // RNE
  return (unsigned short)(u >> 16);
}
__device__ inline float bf2f(unsigned short h) {
  unsigned u = ((unsigned)h) << 16;
  return __builtin_bit_cast(float, u);
}

__device__ inline void load_lds16(const void* g, void* l) {
  __builtin_amdgcn_global_load_lds(
      (const __attribute__((address_space(1))) unsigned int*)g,
      (__attribute__((address_space(3))) unsigned int*)l, 16, 0, 0);
}

// ---------------- 3-NN: Q=4 queries/thread, V=16 subs, named scalars, lb(256,4) ----------------
__device__ inline void ins3u(unsigned long long k, unsigned long long& k0,
                             unsigned long long& k1, unsigned long long& k2) {
  if (k < k2) {
    if (k < k1) {
      k2 = k1;
      if (k < k0) { k1 = k0; k0 = k; } else k1 = k;
    } else k2 = k;
  }
}

#define QDECL(q)                                                            \
  float d0_##q = INFINITY, d1_##q = INFINITY, d2_##q = INFINITY;            \
  int i0_##q = 0, i1_##q = 0, i2_##q = 0;                                   \
  float qx_##q, qy_##q, qz_##q, q2_##q;

#define QLOAD(q)                                                            \
  {                                                                         \
    float ox = p1[nq + q], oy = p1[N + nq + q], oz = p1[2 * N + nq + q];    \
    q2_##q = ox * ox + oy * oy + oz * oz;                                   \
    qx_##q = -2.0f * ox; qy_##q = -2.0f * oy; qz_##q = -2.0f * oz;          \
  }

#define QINS(q)                                                             \
  {                                                                         \
    float d = fmaf(qx_##q, p.x,                                             \
                   fmaf(qy_##q, p.y, fmaf(qz_##q, p.z, p.w))) + q2_##q;     \
    bool lt0 = d < d0_##q, lt1 = d < d1_##q, lt2 = d < d2_##q;              \
    d2_##q = lt2 ? (lt1 ? d1_##q : d) : d2_##q;                             \
    i2_##q = lt2 ? (lt1 ? i1_##q : s) : i2_##q;                             \
    d1_##q = lt1 ? (lt0 ? d0_##q : d) : d1_##q;                             \
    i1_##q = lt1 ? (lt0 ? i0_##q : s) : i1_##q;                             \
    d0_##q = lt0 ? d : d0_##q;                                              \
    i0_##q = lt0 ? s : i0_##q;                                              \
  }

#define QPACK(q)                                                            \
  unsigned long long k0_##q =                                               \
      ((unsigned long long)__float_as_uint(d0_##q) << 32) | (unsigned)i0_##q; \
  unsigned long long k1_##q =                                               \
      ((unsigned long long)__float_as_uint(d1_##q) << 32) | (unsigned)i1_##q; \
  unsigned long long k2_##q =                                               \
      ((unsigned long long)__float_as_uint(d2_##q) << 32) | (unsigned)i2_##q;

#define QMSTEP(q, m)                                                        \
  {                                                                         \
    unsigned long long e0 = (unsigned long long)__shfl_xor((long long)k0_##q, m); \
    unsigned long long e1 = (unsigned long long)__shfl_xor((long long)k1_##q, m); \
    unsigned long long e2 = (unsigned long long)__shfl_xor((long long)k2_##q, m); \
    ins3u(e0, k0_##q, k1_##q, k2_##q);                                      \
    ins3u(e1, k0_##q, k1_##q, k2_##q);                                      \
    ins3u(e2, k0_##q, k1_##q, k2_##q);                                      \
  }

#define QOUT(q)                                                             \
  {                                                                         \
    float e0 = fmaxf(__uint_as_float((unsigned)(k0_##q >> 32)) - 1.0f, 0.0f); \
    float e1 = fmaxf(__uint_as_float((unsigned)(k1_##q >> 32)) - 1.0f, 0.0f); \
    float e2 = fmaxf(__uint_as_float((unsigned)(k2_##q >> 32)) - 1.0f, 0.0f); \
    float r0 = 1.0f / (e0 + 1e-8f);                                         \
    float r1 = 1.0f / (e1 + 1e-8f);                                         \
    float r2 = 1.0f / (e2 + 1e-8f);                                         \
    float rs = 1.0f / (r0 + r1 + r2);                                       \
    size_t o = ((size_t)b * N + nq + q) * 3;                                \
    idxbuf[o] = (int)(unsigned)k0_##q;                                      \
    idxbuf[o + 1] = (int)(unsigned)k1_##q;                                  \
    idxbuf[o + 2] = (int)(unsigned)k2_##q;                                  \
    wbuf[o] = r0 * rs; wbuf[o + 1] = r1 * rs; wbuf[o + 2] = r2 * rs;        \
  }

__global__ __launch_bounds__(256, 4) void nn3_kernel(const float* __restrict__ xyz1,
                                                     const float* __restrict__ xyz2,
                                                     int* __restrict__ idxbuf,
                                                     float* __restrict__ wbuf) {
  __shared__ float4 sp[S];  // {x,y,z,|p|^2 + 1}  32KB
  int b = blockIdx.x >> 7;            // grid = B * (N/64) = 1024
  int n0 = (blockIdx.x & 127) * 64;
  const float* p2 = xyz2 + (size_t)b * 3 * S;
  for (int i = threadIdx.x; i < S; i += 256) {
    float px = p2[i], py = p2[S + i], pz = p2[2 * S + i];
    sp[i] = make_float4(px, py, pz, px * px + py * py + pz * pz + 1.0f);
  }
  __syncthreads();
  int tid = threadIdx.x;
  int sub = tid & 15, grp = tid >> 4;  // 16 qgroups x 4 queries = 64 queries/block
  const float* p1 = xyz1 + (size_t)b * 3 * N;
  int nq = n0 + grp * 4;
  QDECL(0) QDECL(1) QDECL(2) QDECL(3)
  QLOAD(0) QLOAD(1) QLOAD(2) QLOAD(3)

  for (int t = 0; t < S / 16; ++t) {
    int s = t * 16 + sub;
    float4 p = sp[s];
    QINS(0) QINS(1) QINS(2) QINS(3)
  }

  QPACK(0) QPACK(1) QPACK(2) QPACK(3)
#pragma unroll
  for (int m = 1; m <= 8; m <<= 1) {
    QMSTEP(0, m) QMSTEP(1, m) QMSTEP(2, m) QMSTEP(3, m)
  }
  if (sub == 0) {
    QOUT(0) QOUT(1) QOUT(2) QOUT(3)
  }
}

// ---------------- weights f32 -> bf16 ----------------
__global__ __launch_bounds__(256) void convw_kernel(const float* __restrict__ w0,
                                                    const float* __restrict__ w1,
                                                    unsigned short* __restrict__ w0b,
                                                    unsigned short* __restrict__ w1b) {
  int i = blockIdx.x * 256 + threadIdx.x;
  if (i < C * CIN) w0b[i] = f2bf(w0[i]);
  else {
    int j = i - C * CIN;
    if (j < C * C) w1b[j] = f2bf(w1[j]);
  }
}

// ---------------- transpose+convert: src[b][256][cols] f32 -> dst[b][cols][drow] bf16 ----------------
__global__ __launch_bounds__(256) void tconv_kernel(const float* __restrict__ src,
                                                    unsigned short* __restrict__ dst,
                                                    int cols, int drow, int coff) {
  __shared__ float t[64][65];
  int n0 = blockIdx.x * 64, c0 = blockIdx.y * 64, b = blockIdx.z;
  int tid = threadIdx.x, r = tid >> 2, q = tid & 3;
  const float* sp = src + ((size_t)b * 256 + c0 + r) * cols + n0 + q * 16;
#pragma unroll
  for (int i = 0; i < 4; ++i) {
    float4 v = *(const float4*)(sp + i * 4);
    t[r][q * 16 + i * 4 + 0] = v.x;
    t[r][q * 16 + i * 4 + 1] = v.y;
    t[r][q * 16 + i * 4 + 2] = v.z;
    t[r][q * 16 + i * 4 + 3] = v.w;
  }
  __syncthreads();
  unsigned short* dp = dst + ((size_t)b * cols + n0 + r) * drow + coff + c0 + q * 16;
  ushort8v o0, o1;
#pragma unroll
  for (int i = 0; i < 8; ++i) o0[i] = f2bf(t[q * 16 + i][r]);
#pragma unroll
  for (int i = 0; i < 8; ++i) o1[i] = f2bf(t[q * 16 + 8 + i][r]);
  *(ushort8v*)dp = o0;
  *(ushort8v*)(dp + 8) = o1;
}

// ---------------- gather: Xb[b][n][256+c] = sum_j w_j * p2t[b][idx_j][c] ----------------
__global__ __launch_bounds__(256) void gather_kernel(const unsigned short* __restrict__ p2t,
                                                     const int* __restrict__ idxbuf,
                                                     const float* __restrict__ wbuf,
                                                     unsigned short* __restrict__ Xb) {
  __shared__ int si[192];
  __shared__ float sw[192];
  int b = blockIdx.x >> 7;  // grid = B * (N/64)
  int n0 = (blockIdx.x & 127) * 64;
  size_t base = ((size_t)b * N + n0) * 3;
  if (threadIdx.x < 192) {
    si[threadIdx.x] = idxbuf[base + threadIdx.x];
    sw[threadIdx.x] = wbuf[base + threadIdx.x];
  }
  __syncthreads();
  int nl = threadIdx.x >> 2, cb = threadIdx.x & 3;
  int j0 = si[nl * 3], j1 = si[nl * 3 + 1], j2 = si[nl * 3 + 2];
  float w0 = sw[nl * 3], w1 = sw[nl * 3 + 1], w2 = sw[nl * 3 + 2];
  const unsigned short* pb = p2t + (size_t)b * S * 256;
  const unsigned short* r0p = pb + (size_t)j0 * 256;
  const unsigned short* r1p = pb + (size_t)j1 * 256;
  const unsigned short* r2p = pb + (size_t)j2 * 256;
  unsigned short* xp = Xb + ((size_t)b * N + n0 + nl) * 512 + 256;
#pragma unroll
  for (int ch = 0; ch < 8; ++ch) {
    int co = (cb + ch * 4) * 8;
    ushort8v v0 = *(const ushort8v*)(r0p + co);
    ushort8v v1 = *(const ushort8v*)(r1p + co);
    ushort8v v2 = *(const ushort8v*)(r2p + co);
    ushort8v o;
#pragma unroll
    for (int i = 0; i < 8; ++i)
      o[i] = f2bf(w0 * bf2f(v0[i]) + w1 * bf2f(v1[i]) + w2 * bf2f(v2[i]));
    *(ushort8v*)(xp + co) = o;
  }
}

// ---------------- bf16 MFMA GEMM + channel-major partial stats (no atomics) ----------------
// psum/psumsq layout: [c][slot], c = by*128 + choff, slot = (b*64+bx)*2+wn.
// Every (c,slot) written exactly once -> reducer reads coalesced per channel.
__global__ __launch_bounds__(256) void gemm_kernel(const unsigned short* __restrict__ X,
                                                   const unsigned short* __restrict__ Wb,
                                                   const float* __restrict__ bias,
                                                   unsigned short* __restrict__ Y,
                                                   float* __restrict__ psum,
                                                   float* __restrict__ psumsq,
                                                   int Cin) {
  __shared__ unsigned short As[128 * 32];  // [o_row][k] 8KB, swizzled
  __shared__ unsigned short Bs[128 * 32];  // [n_row][k] 8KB, swizzled
  int n0 = blockIdx.x * 128, o0 = blockIdx.y * 128, b = blockIdx.z;
  int tid = threadIdx.x, lane = tid & 63, wid = tid >> 6;
  int wm = wid >> 1, wn = wid & 1;
  floatx4 acc[4][4];
#pragma unroll
  for (int m = 0; m < 4; ++m)
#pragma unroll
    for (int nt = 0; nt < 4; ++nt) acc[m][nt] = (floatx4)(0.0f);

  size_t rsA = (size_t)Cin * 2;  // row stride bytes
  int chunkSwz = ((lane & 3) ^ ((lane >> 3) & 3)) * 16;
  const char* Abase = (const char*)Wb + (size_t)(o0 + wid * 32 + (lane >> 2)) * rsA + chunkSwz;
  const char* Bbase = (const char*)X + ((size_t)b * N + n0 + wid * 32 + (lane >> 2)) * rsA + chunkSwz;
  size_t rstep16 = 16 * rsA;
  int kq = (((lane >> 4) ^ ((lane >> 1) & 3))) * 8;

  for (int k0 = 0; k0 < Cin; k0 += 32) {
    load_lds16(Abase + (size_t)k0 * 2, &As[(wid * 32) * 32]);
    load_lds16(Abase + (size_t)k0 * 2 + rstep16, &As[(wid * 32 + 16) * 32]);
    load_lds16(Bbase + (size_t)k0 * 2, &Bs[(wid * 32) * 32]);
    load_lds16(Bbase + (size_t)k0 * 2 + rstep16, &Bs[(wid * 32 + 16) * 32]);
    __syncthreads();
    bf16x8 af[4], bfv[4];
#pragma unroll
    for (int m = 0; m < 4; ++m)
      af[m] = *(const bf16x8*)&As[(wm * 64 + m * 16 + (lane & 15)) * 32 + kq];
#pragma unroll
    for (int nt = 0; nt < 4; ++nt)
      bfv[nt] = *(const bf16x8*)&Bs[(wn * 64 + nt * 16 + (lane & 15)) * 32 + kq];
#pragma unroll
    for (int m = 0; m < 4; ++m)
#pragma unroll
      for (int nt = 0; nt < 4; ++nt)
        acc[m][nt] = __builtin_amdgcn_mfma_f32_16x16x32_bf16(af[m], bfv[nt], acc[m][nt], 0, 0, 0);
    __syncthreads();
  }

  int col = lane & 15, rowq = lane >> 4;
  int slot = ((b * 64 + blockIdx.x) * 2) + wn;
#pragma unroll
  for (int m = 0; m < 4; ++m) {
    int ob = o0 + wm * 64 + m * 16 + rowq * 4;
    float4 bs = *(const float4*)&bias[ob];
    float sj[4] = {0.f, 0.f, 0.f, 0.f}, qj[4] = {0.f, 0.f, 0.f, 0.f};
#pragma unroll
    for (int nt = 0; nt < 4; ++nt) {
      int n = n0 + wn * 64 + nt * 16 + col;
      float y0 = acc[m][nt][0] + bs.x;
      float y1 = acc[m][nt][1] + bs.y;
      float y2 = acc[m][nt][2] + bs.z;
      float y3 = acc[m][nt][3] + bs.w;
      ushort4v v;
      v[0] = f2bf(y0); v[1] = f2bf(y1); v[2] = f2bf(y2); v[3] = f2bf(y3);
      *(ushort4v*)&Y[((size_t)b * N + n) * 256 + ob] = v;
      sj[0] += y0; qj[0] = fmaf(y0, y0, qj[0]);
      sj[1] += y1; qj[1] = fmaf(y1, y1, qj[1]);
      sj[2] += y2; qj[2] = fmaf(y2, y2, qj[2]);
      sj[3] += y3; qj[3] = fmaf(y3, y3, qj[3]);
    }
#pragma unroll
    for (int j = 0; j < 4; ++j) {
#pragma unroll
      for (int d = 1; d <= 8; d <<= 1) {
        sj[j] += __shfl_xor(sj[j], d);
        qj[j] += __shfl_xor(qj[j], d);
      }
    }
    if (col == 0) {
      int c0 = blockIdx.y * 128 + wm * 64 + m * 16 + rowq * 4;
#pragma unroll
      for (int j = 0; j < 4; ++j) {
        psum[(size_t)(c0 + j) * NSLOT + slot] = sj[j];
        psumsq[(size_t)(c0 + j) * NSLOT + slot] = qj[j];
      }
    }
  }
}

// ---------------- parallel reduce partials -> BN scale/shift (256 blocks) ----------------
__global__ __launch_bounds__(256) void bnparam_kernel(const float* __restrict__ psum,
                                                      const float* __restrict__ psumsq,
                                                      const float* __restrict__ gamma,
                                                      const float* __restrict__ beta,
                                                      float* __restrict__ scale,
                                                      float* __restrict__ shift) {
  int c = blockIdx.x, tid = threadIdx.x;
  const float* ps = psum + (size_t)c * NSLOT;
  const float* pq = psumsq + (size_t)c * NSLOT;
  float s = 0.f, q = 0.f;
#pragma unroll
  for (int i = 0; i < NSLOT / 256; ++i) {
    s += ps[tid + i * 256];
    q += pq[tid + i * 256];
  }
#pragma unroll
  for (int d = 1; d <= 32; d <<= 1) {
    s += __shfl_xor(s, d);
    q += __shfl_xor(q, d);
  }
  __shared__ float ls[4], lq[4];
  int wid = tid >> 6;
  if ((tid & 63) == 0) { ls[wid] = s; lq[wid] = q; }
  __syncthreads();
  if (tid == 0) {
    s = ls[0] + ls[1] + ls[2] + ls[3];
    q = lq[0] + lq[1] + lq[2] + lq[3];
    float m = s * (1.0f / CNT);
    float v = q * (1.0f / CNT) - m * m;
    float sc = gamma[c] * rsqrtf(v + 1e-5f);
    scale[c] = sc;
    shift[c] = beta[c] - m * sc;
  }
}

// ---------------- BN+ReLU elementwise on [b][n][256] bf16 -> bf16 ----------------
__global__ __launch_bounds__(256) void bnrelu_kernel(const unsigned short* __restrict__ Y,
                                                     const float* __restrict__ scale,
                                                     const float* __restrict__ shift,
                                                     unsigned short* __restrict__ H) {
  size_t total = (size_t)B * N * 256 / 8;
  for (size_t i = (size_t)blockIdx.x * 256 + threadIdx.x; i < total;
       i += (size_t)gridDim.x * 256) {
    int ob = ((int)i & 31) * 8;
    float4 s0 = *(const float4*)&scale[ob];
    float4 s1 = *(const float4*)&scale[ob + 4];
    float4 h0 = *(const float4*)&shift[ob];
    float4 h1 = *(const float4*)&shift[ob + 4];
    ushort8v v = *(const ushort8v*)&Y[i * 8];
    ushort8v o;
    o[0] = f2bf(fmaxf(fmaf(bf2f(v[0]), s0.x, h0.x), 0.f));
    o[1] = f2bf(fmaxf(fmaf(bf2f(v[1]), s0.y, h0.y), 0.f));
    o[2] = f2bf(fmaxf(fmaf(bf2f(v[2]), s0.z, h0.z), 0.f));
    o[3] = f2bf(fmaxf(fmaf(bf2f(v[3]), s0.w, h0.w), 0.f));
    o[4] = f2bf(fmaxf(fmaf(bf2f(v[4]), s1.x, h1.x), 0.f));
    o[5] = f2bf(fmaxf(fmaf(bf2f(v[5]), s1.y, h1.y), 0.f));
    o[6] = f2bf(fmaxf(fmaf(bf2f(v[6]), s1.z, h1.z), 0.f));
    o[7] = f2bf(fmaxf(fmaf(bf2f(v[7]), s1.w, h1.w), 0.f));
    *(ushort8v*)&H[i * 8] = o;
  }
}

// ---------------- final: BN+ReLU + transpose [b][n][o] bf16 -> out [b][o][n] f32 ----------------
__global__ __launch_bounds__(256) void bnreluT_kernel(const unsigned short* __restrict__ Y,
                                                      const float* __restrict__ scale,
                                                      const float* __restrict__ shift,
                                                      float* __restrict__ out) {
  __shared__ float t[64][65];
  int n0 = blockIdx.x * 64, o0 = blockIdx.y * 64, b = blockIdx.z;
  int tid = threadIdx.x, r = tid >> 2, q = tid & 3;
  const unsigned short* yp = Y + ((size_t)b * N + n0 + r) * 256 + o0 + q * 16;
#pragma unroll
  for (int h = 0; h < 2; ++h) {
    ushort8v v = *(const ushort8v*)(yp + h * 8);
#pragma unroll
    for (int i = 0; i < 8; ++i) {
      int oc = q * 16 + h * 8 + i;
      float f = fmaxf(fmaf(bf2f(v[i]), scale[o0 + oc], shift[o0 + oc]), 0.f);
      t[oc][r] = f;
    }
  }
  __syncthreads();
  float* op = out + ((size_t)b * 256 + o0 + r) * N + n0 + q * 16;
#pragma unroll
  for (int i = 0; i < 4; ++i) {
    float4 v = make_float4(t[r][q * 16 + i * 4 + 0], t[r][q * 16 + i * 4 + 1],
                           t[r][q * 16 + i * 4 + 2], t[r][q * 16 + i * 4 + 3]);
    *(float4*)(op + i * 4) = v;
  }
}

extern "C" void kernel_launch(void* const* d_in, const int* in_sizes, int n_in,
                              void* d_out, int out_size, void* d_ws, size_t ws_size,
                              hipStream_t stream) {
  const float* xyz1 = (const float*)d_in[0];
  const float* xyz2 = (const float*)d_in[1];
  const float* points1 = (const float*)d_in[2];
  const float* points2 = (const float*)d_in[3];
  const float* w0 = (const float*)d_in[4];
  const float* b0 = (const float*)d_in[5];
  const float* g0 = (const float*)d_in[6];
  const float* be0 = (const float*)d_in[7];
  const float* w1 = (const float*)d_in[8];
  const float* b1 = (const float*)d_in[9];
  const float* g1 = (const float*)d_in[10];
  const float* be1 = (const float*)d_in[11];
  float* out = (float*)d_out;

  char* ws = (char*)d_ws;
  int* idxbuf = (int*)ws;              ws += (size_t)CNT * 3 * 4;      // 768KB
  float* wbuf = (float*)ws;            ws += (size_t)CNT * 3 * 4;      // 768KB
  float* scale0 = (float*)ws;          ws += 256 * 4;
  float* shift0 = (float*)ws;          ws += 256 * 4;
  float* scale1 = (float*)ws;          ws += 256 * 4;
  float* shift1 = (float*)ws;          ws += 256 * 4;
  float* psum = (float*)ws;            ws += (size_t)C * NSLOT * 4;    // 1MB
  float* psumsq = (float*)ws;          ws += (size_t)C * NSLOT * 4;    // 1MB
  unsigned short* w0b = (unsigned short*)ws;  ws += (size_t)C * CIN * 2;   // 256KB
  unsigned short* w1b = (unsigned short*)ws;  ws += (size_t)C * C * 2;     // 128KB
  unsigned short* p2t = (unsigned short*)ws;  ws += (size_t)B * S * 256 * 2;   // 8MB
  unsigned short* Xb = (unsigned short*)ws;   ws += (size_t)B * N * 512 * 2;   // 64MB
  unsigned short* Yb = (unsigned short*)ws;   ws += (size_t)B * N * 256 * 2;   // 32MB
  unsigned short* Hb = Xb;  // reuse Xb after GEMM0 consumed it

  convw_kernel<<<dim3((C * CIN + C * C) / 256), 256, 0, stream>>>(w0, w1, w0b, w1b);
  tconv_kernel<<<dim3(N / 64, 4, B), 256, 0, stream>>>(points1, Xb, N, 512, 0);
  tconv_kernel<<<dim3(S / 64, 4, B), 256, 0, stream>>>(points2, p2t, S, 256, 0);
  nn3_kernel<<<dim3(B * N / 64), 256, 0, stream>>>(xyz1, xyz2, idxbuf, wbuf);
  gather_kernel<<<dim3(B * N / 64), 256, 0, stream>>>(p2t, idxbuf, wbuf, Xb);
  gemm_kernel<<<dim3(N / 128, 2, B), 256, 0, stream>>>(Xb, w0b, b0, Yb, psum, psumsq, CIN);
  bnparam_kernel<<<dim3(C), 256, 0, stream>>>(psum, psumsq, g0, be0, scale0, shift0);
  bnrelu_kernel<<<dim3(2048), 256, 0, stream>>>(Yb, scale0, shift0, Hb);
  gemm_kernel<<<dim3(N / 128, 2, B), 256, 0, stream>>>(Hb, w1b, b1, Yb, psum, psumsq, C);
  bnparam_kernel<<<dim3(C), 256, 0, stream>>>(psum, psumsq, g1, be1, scale1, shift1);
  bnreluT_kernel<<<dim3(N / 64, 4, B), 256, 0, stream>>>(Yb, scale1, shift1, out);
}

// Round 10
// 242.858 us; speedup vs baseline: 3.1925x; 1.0167x over previous
//
#include <hip/hip_runtime.h>
#include <math.h>

#define B 8
#define N 8192
#define S 2048
#define C 256
#define CIN 512
#define CNT (B * N)  // 65536
#define NSLOT 1024   // (b*64 + bx)*2 + wn

typedef unsigned long long ull;
typedef __attribute__((ext_vector_type(8))) short bf16x8;
typedef __attribute__((ext_vector_type(4))) float floatx4;
typedef __attribute__((ext_vector_type(8))) unsigned short ushort8v;
typedef __attribute__((ext_vector_type(4))) unsigned short ushort4v;

__device__ inline unsigned short f2bf(float f) {
  unsigned u = __builtin_bit_cast(unsigned, f);
  u += 0x7FFF + ((u >> 16) & 1);  // RNE
  return (unsigned short)(u >> 16);
}
__device__ inline float bf2f(unsigned short h) {
  unsigned u = ((unsigned)h) << 16;
  return __builtin_bit_cast(float, u);
}

__device__ inline void load_lds16(const void* g, void* l) {
  __builtin_amdgcn_global_load_lds(
      (const __attribute__((address_space(1))) unsigned int*)g,
      (__attribute__((address_space(3))) unsigned int*)l, 16, 0, 0);
}

// ---------------- 3-NN v10 ----------------
// Scan: Q=4 queries/thread, V=16 subs/query, software-pipelined LDS read
// (pc/pn named float4 — hides ~120cyc ds_read latency under the 68-VALU body).
// Merge: NO register butterfly (r9's 50MB scratch spill came from 12 u64 keys
// + 24 d/i regs live at once). Keys go to LDS (reuse sp, 24KB); subs 0-3 merge
// 12 keys each + 2-step shfl butterfly; sub 0 writes output.
__device__ inline void ins3u(ull k, ull& k0, ull& k1, ull& k2) {
  if (k < k2) {
    if (k < k1) {
      k2 = k1;
      if (k < k0) { k1 = k0; k0 = k; } else k1 = k;
    } else k2 = k;
  }
}

__device__ inline void out3(ull k0, ull k1, ull k2, int* __restrict__ idxbuf,
                            float* __restrict__ wbuf, size_t o) {
  float e0 = fmaxf(__uint_as_float((unsigned)(k0 >> 32)) - 1.0f, 0.0f);
  float e1 = fmaxf(__uint_as_float((unsigned)(k1 >> 32)) - 1.0f, 0.0f);
  float e2 = fmaxf(__uint_as_float((unsigned)(k2 >> 32)) - 1.0f, 0.0f);
  float r0 = 1.0f / (e0 + 1e-8f);
  float r1 = 1.0f / (e1 + 1e-8f);
  float r2 = 1.0f / (e2 + 1e-8f);
  float rs = 1.0f / (r0 + r1 + r2);
  idxbuf[o] = (int)(unsigned)k0;
  idxbuf[o + 1] = (int)(unsigned)k1;
  idxbuf[o + 2] = (int)(unsigned)k2;
  wbuf[o] = r0 * rs; wbuf[o + 1] = r1 * rs; wbuf[o + 2] = r2 * rs;
}

#define QDECL(q)                                                            \
  float d0_##q = INFINITY, d1_##q = INFINITY, d2_##q = INFINITY;            \
  int i0_##q = 0, i1_##q = 0, i2_##q = 0;                                   \
  float qx_##q, qy_##q, qz_##q, q2_##q;

#define QLOAD(q)                                                            \
  {                                                                         \
    float ox = p1[nq + q], oy = p1[N + nq + q], oz = p1[2 * N + nq + q];    \
    q2_##q = ox * ox + oy * oy + oz * oz;                                   \
    qx_##q = -2.0f * ox; qy_##q = -2.0f * oy; qz_##q = -2.0f * oz;          \
  }

// insert (distance, s) for query q, using point pc (exact f32; ascending-s
// scan + strict < keeps the smaller index on ties == top_k semantics)
#define QINS(q)                                                             \
  {                                                                         \
    float d = fmaf(qx_##q, pc.x,                                            \
                   fmaf(qy_##q, pc.y, fmaf(qz_##q, pc.z, pc.w))) + q2_##q;  \
    bool lt0 = d < d0_##q, lt1 = d < d1_##q, lt2 = d < d2_##q;              \
    d2_##q = lt2 ? (lt1 ? d1_##q : d) : d2_##q;                             \
    i2_##q = lt2 ? (lt1 ? i1_##q : s) : i2_##q;                             \
    d1_##q = lt1 ? (lt0 ? d0_##q : d) : d1_##q;                             \
    i1_##q = lt1 ? (lt0 ? i0_##q : s) : i1_##q;                             \
    d0_##q = lt0 ? d : d0_##q;                                              \
    i0_##q = lt0 ? s : i0_##q;                                              \
  }

#define QSTORE(q)                                                           \
  {                                                                         \
    size_t kb = ((size_t)(grp * 4 + q) * 16 + sub) * 3;                     \
    keys[kb] = ((ull)__float_as_uint(d0_##q) << 32) | (unsigned)i0_##q;     \
    keys[kb + 1] = ((ull)__float_as_uint(d1_##q) << 32) | (unsigned)i1_##q; \
    keys[kb + 2] = ((ull)__float_as_uint(d2_##q) << 32) | (unsigned)i2_##q; \
  }

__global__ __launch_bounds__(256, 4) void nn3_kernel(const float* __restrict__ xyz1,
                                                     const float* __restrict__ xyz2,
                                                     int* __restrict__ idxbuf,
                                                     float* __restrict__ wbuf) {
  __shared__ float4 sp[S];  // {x,y,z,|p|^2 + 1}  32KB; reused as u64 key buffer
  int b = blockIdx.x >> 7;            // grid = B * (N/64) = 1024
  int n0 = (blockIdx.x & 127) * 64;
  const float* p2 = xyz2 + (size_t)b * 3 * S;
  for (int i = threadIdx.x; i < S; i += 256) {
    float px = p2[i], py = p2[S + i], pz = p2[2 * S + i];
    sp[i] = make_float4(px, py, pz, px * px + py * py + pz * pz + 1.0f);
  }
  __syncthreads();
  int tid = threadIdx.x;
  int sub = tid & 15, grp = tid >> 4;  // 16 qgroups x 4 queries = 64 queries/block
  const float* p1 = xyz1 + (size_t)b * 3 * N;
  int nq = n0 + grp * 4;
  QDECL(0) QDECL(1) QDECL(2) QDECL(3)
  QLOAD(0) QLOAD(1) QLOAD(2) QLOAD(3)

  // software-pipelined scan: next LDS read in flight while QINS block runs
  float4 pc = sp[sub];
  for (int t = 0; t < S / 16 - 1; ++t) {
    float4 pn = sp[(t + 1) * 16 + sub];
    int s = t * 16 + sub;
    QINS(0) QINS(1) QINS(2) QINS(3)
    pc = pn;
  }
  {
    int s = (S / 16 - 1) * 16 + sub;
    QINS(0) QINS(1) QINS(2) QINS(3)
  }

  // merge via LDS (scan state dies here; no 48-reg key butterfly)
  __syncthreads();
  ull* keys = (ull*)sp;  // [64 queries][16 subs][3]
  QSTORE(0) QSTORE(1) QSTORE(2) QSTORE(3)
  __syncthreads();
  if (sub < 4) {
#pragma unroll
    for (int q = 0; q < 4; ++q) {
      size_t qb = (size_t)(grp * 4 + q) * 48;
      ull m0 = ~0ull, m1 = ~0ull, m2 = ~0ull;
#pragma unroll
      for (int jj = 0; jj < 4; ++jj) {
        size_t o2 = qb + (size_t)(sub + 4 * jj) * 3;
        ins3u(keys[o2], m0, m1, m2);
        ins3u(keys[o2 + 1], m0, m1, m2);
        ins3u(keys[o2 + 2], m0, m1, m2);
      }
#pragma unroll
      for (int mm = 1; mm <= 2; mm <<= 1) {
        ull e0 = (ull)__shfl_xor((long long)m0, mm);
        ull e1 = (ull)__shfl_xor((long long)m1, mm);
        ull e2 = (ull)__shfl_xor((long long)m2, mm);
        ins3u(e0, m0, m1, m2);
        ins3u(e1, m0, m1, m2);
        ins3u(e2, m0, m1, m2);
      }
      if (sub == 0) out3(m0, m1, m2, idxbuf, wbuf, ((size_t)b * N + nq + q) * 3);
    }
  }
}

// ---------------- weights f32 -> bf16 ----------------
__global__ __launch_bounds__(256) void convw_kernel(const float* __restrict__ w0,
                                                    const float* __restrict__ w1,
                                                    unsigned short* __restrict__ w0b,
                                                    unsigned short* __restrict__ w1b) {
  int i = blockIdx.x * 256 + threadIdx.x;
  if (i < C * CIN) w0b[i] = f2bf(w0[i]);
  else {
    int j = i - C * CIN;
    if (j < C * C) w1b[j] = f2bf(w1[j]);
  }
}

// ---------------- transpose+convert: src[b][256][cols] f32 -> dst[b][cols][drow] bf16 ----------------
__global__ __launch_bounds__(256) void tconv_kernel(const float* __restrict__ src,
                                                    unsigned short* __restrict__ dst,
                                                    int cols, int drow, int coff) {
  __shared__ float t[64][65];
  int n0 = blockIdx.x * 64, c0 = blockIdx.y * 64, b = blockIdx.z;
  int tid = threadIdx.x, r = tid >> 2, q = tid & 3;
  const float* sp = src + ((size_t)b * 256 + c0 + r) * cols + n0 + q * 16;
#pragma unroll
  for (int i = 0; i < 4; ++i) {
    float4 v = *(const float4*)(sp + i * 4);
    t[r][q * 16 + i * 4 + 0] = v.x;
    t[r][q * 16 + i * 4 + 1] = v.y;
    t[r][q * 16 + i * 4 + 2] = v.z;
    t[r][q * 16 + i * 4 + 3] = v.w;
  }
  __syncthreads();
  unsigned short* dp = dst + ((size_t)b * cols + n0 + r) * drow + coff + c0 + q * 16;
  ushort8v o0, o1;
#pragma unroll
  for (int i = 0; i < 8; ++i) o0[i] = f2bf(t[q * 16 + i][r]);
#pragma unroll
  for (int i = 0; i < 8; ++i) o1[i] = f2bf(t[q * 16 + 8 + i][r]);
  *(ushort8v*)dp = o0;
  *(ushort8v*)(dp + 8) = o1;
}

// ---------------- gather: Xb[b][n][256+c] = sum_j w_j * p2t[b][idx_j][c] ----------------
__global__ __launch_bounds__(256) void gather_kernel(const unsigned short* __restrict__ p2t,
                                                     const int* __restrict__ idxbuf,
                                                     const float* __restrict__ wbuf,
                                                     unsigned short* __restrict__ Xb) {
  __shared__ int si[192];
  __shared__ float sw[192];
  int b = blockIdx.x >> 7;  // grid = B * (N/64)
  int n0 = (blockIdx.x & 127) * 64;
  size_t base = ((size_t)b * N + n0) * 3;
  if (threadIdx.x < 192) {
    si[threadIdx.x] = idxbuf[base + threadIdx.x];
    sw[threadIdx.x] = wbuf[base + threadIdx.x];
  }
  __syncthreads();
  int nl = threadIdx.x >> 2, cb = threadIdx.x & 3;
  int j0 = si[nl * 3], j1 = si[nl * 3 + 1], j2 = si[nl * 3 + 2];
  float w0 = sw[nl * 3], w1 = sw[nl * 3 + 1], w2 = sw[nl * 3 + 2];
  const unsigned short* pb = p2t + (size_t)b * S * 256;
  const unsigned short* r0p = pb + (size_t)j0 * 256;
  const unsigned short* r1p = pb + (size_t)j1 * 256;
  const unsigned short* r2p = pb + (size_t)j2 * 256;
  unsigned short* xp = Xb + ((size_t)b * N + n0 + nl) * 512 + 256;
#pragma unroll
  for (int ch = 0; ch < 8; ++ch) {
    int co = (cb + ch * 4) * 8;
    ushort8v v0 = *(const ushort8v*)(r0p + co);
    ushort8v v1 = *(const ushort8v*)(r1p + co);
    ushort8v v2 = *(const ushort8v*)(r2p + co);
    ushort8v o;
#pragma unroll
    for (int i = 0; i < 8; ++i)
      o[i] = f2bf(w0 * bf2f(v0[i]) + w1 * bf2f(v1[i]) + w2 * bf2f(v2[i]));
    *(ushort8v*)(xp + co) = o;
  }
}

// ---------------- bf16 MFMA GEMM + channel-major partial stats (no atomics) ----------------
__global__ __launch_bounds__(256) void gemm_kernel(const unsigned short* __restrict__ X,
                                                   const unsigned short* __restrict__ Wb,
                                                   const float* __restrict__ bias,
                                                   unsigned short* __restrict__ Y,
                                                   float* __restrict__ psum,
                                                   float* __restrict__ psumsq,
                                                   int Cin) {
  __shared__ unsigned short As[128 * 32];  // [o_row][k] 8KB, swizzled
  __shared__ unsigned short Bs[128 * 32];  // [n_row][k] 8KB, swizzled
  int n0 = blockIdx.x * 128, o0 = blockIdx.y * 128, b = blockIdx.z;
  int tid = threadIdx.x, lane = tid & 63, wid = tid >> 6;
  int wm = wid >> 1, wn = wid & 1;
  floatx4 acc[4][4];
#pragma unroll
  for (int m = 0; m < 4; ++m)
#pragma unroll
    for (int nt = 0; nt < 4; ++nt) acc[m][nt] = (floatx4)(0.0f);

  size_t rsA = (size_t)Cin * 2;  // row stride bytes
  int chunkSwz = ((lane & 3) ^ ((lane >> 3) & 3)) * 16;
  const char* Abase = (const char*)Wb + (size_t)(o0 + wid * 32 + (lane >> 2)) * rsA + chunkSwz;
  const char* Bbase = (const char*)X + ((size_t)b * N + n0 + wid * 32 + (lane >> 2)) * rsA + chunkSwz;
  size_t rstep16 = 16 * rsA;
  int kq = (((lane >> 4) ^ ((lane >> 1) & 3))) * 8;

  for (int k0 = 0; k0 < Cin; k0 += 32) {
    load_lds16(Abase + (size_t)k0 * 2, &As[(wid * 32) * 32]);
    load_lds16(Abase + (size_t)k0 * 2 + rstep16, &As[(wid * 32 + 16) * 32]);
    load_lds16(Bbase + (size_t)k0 * 2, &Bs[(wid * 32) * 32]);
    load_lds16(Bbase + (size_t)k0 * 2 + rstep16, &Bs[(wid * 32 + 16) * 32]);
    __syncthreads();
    bf16x8 af[4], bfv[4];
#pragma unroll
    for (int m = 0; m < 4; ++m)
      af[m] = *(const bf16x8*)&As[(wm * 64 + m * 16 + (lane & 15)) * 32 + kq];
#pragma unroll
    for (int nt = 0; nt < 4; ++nt)
      bfv[nt] = *(const bf16x8*)&Bs[(wn * 64 + nt * 16 + (lane & 15)) * 32 + kq];
#pragma unroll
    for (int m = 0; m < 4; ++m)
#pragma unroll
      for (int nt = 0; nt < 4; ++nt)
        acc[m][nt] = __builtin_amdgcn_mfma_f32_16x16x32_bf16(af[m], bfv[nt], acc[m][nt], 0, 0, 0);
    __syncthreads();
  }

  int col = lane & 15, rowq = lane >> 4;
  int slot = ((b * 64 + blockIdx.x) * 2) + wn;
#pragma unroll
  for (int m = 0; m < 4; ++m) {
    int ob = o0 + wm * 64 + m * 16 + rowq * 4;
    float4 bs = *(const float4*)&bias[ob];
    float sj[4] = {0.f, 0.f, 0.f, 0.f}, qj[4] = {0.f, 0.f, 0.f, 0.f};
#pragma unroll
    for (int nt = 0; nt < 4; ++nt) {
      int n = n0 + wn * 64 + nt * 16 + col;
      float y0 = acc[m][nt][0] + bs.x;
      float y1 = acc[m][nt][1] + bs.y;
      float y2 = acc[m][nt][2] + bs.z;
      float y3 = acc[m][nt][3] + bs.w;
      ushort4v v;
      v[0] = f2bf(y0); v[1] = f2bf(y1); v[2] = f2bf(y2); v[3] = f2bf(y3);
      *(ushort4v*)&Y[((size_t)b * N + n) * 256 + ob] = v;
      sj[0] += y0; qj[0] = fmaf(y0, y0, qj[0]);
      sj[1] += y1; qj[1] = fmaf(y1, y1, qj[1]);
      sj[2] += y2; qj[2] = fmaf(y2, y2, qj[2]);
      sj[3] += y3; qj[3] = fmaf(y3, y3, qj[3]);
    }
#pragma unroll
    for (int j = 0; j < 4; ++j) {
#pragma unroll
      for (int d = 1; d <= 8; d <<= 1) {
        sj[j] += __shfl_xor(sj[j], d);
        qj[j] += __shfl_xor(qj[j], d);
      }
    }
    if (col == 0) {
      int c0 = blockIdx.y * 128 + wm * 64 + m * 16 + rowq * 4;
#pragma unroll
      for (int j = 0; j < 4; ++j) {
        psum[(size_t)(c0 + j) * NSLOT + slot] = sj[j];
        psumsq[(size_t)(c0 + j) * NSLOT + slot] = qj[j];
      }
    }
  }
}

// ---------------- parallel reduce partials -> BN scale/shift (256 blocks) ----------------
__global__ __launch_bounds__(256) void bnparam_kernel(const float* __restrict__ psum,
                                                      const float* __restrict__ psumsq,
                                                      const float* __restrict__ gamma,
                                                      const float* __restrict__ beta,
                                                      float* __restrict__ scale,
                                                      float* __restrict__ shift) {
  int c = blockIdx.x, tid = threadIdx.x;
  const float* ps = psum + (size_t)c * NSLOT;
  const float* pq = psumsq + (size_t)c * NSLOT;
  float s = 0.f, q = 0.f;
#pragma unroll
  for (int i = 0; i < NSLOT / 256; ++i) {
    s += ps[tid + i * 256];
    q += pq[tid + i * 256];
  }
#pragma unroll
  for (int d = 1; d <= 32; d <<= 1) {
    s += __shfl_xor(s, d);
    q += __shfl_xor(q, d);
  }
  __shared__ float ls[4], lq[4];
  int wid = tid >> 6;
  if ((tid & 63) == 0) { ls[wid] = s; lq[wid] = q; }
  __syncthreads();
  if (tid == 0) {
    s = ls[0] + ls[1] + ls[2] + ls[3];
    q = lq[0] + lq[1] + lq[2] + lq[3];
    float m = s * (1.0f / CNT);
    float v = q * (1.0f / CNT) - m * m;
    float sc = gamma[c] * rsqrtf(v + 1e-5f);
    scale[c] = sc;
    shift[c] = beta[c] - m * sc;
  }
}

// ---------------- BN+ReLU elementwise on [b][n][256] bf16 -> bf16 ----------------
__global__ __launch_bounds__(256) void bnrelu_kernel(const unsigned short* __restrict__ Y,
                                                     const float* __restrict__ scale,
                                                     const float* __restrict__ shift,
                                                     unsigned short* __restrict__ H) {
  size_t total = (size_t)B * N * 256 / 8;
  for (size_t i = (size_t)blockIdx.x * 256 + threadIdx.x; i < total;
       i += (size_t)gridDim.x * 256) {
    int ob = ((int)i & 31) * 8;
    float4 s0 = *(const float4*)&scale[ob];
    float4 s1 = *(const float4*)&scale[ob + 4];
    float4 h0 = *(const float4*)&shift[ob];
    float4 h1 = *(const float4*)&shift[ob + 4];
    ushort8v v = *(const ushort8v*)&Y[i * 8];
    ushort8v o;
    o[0] = f2bf(fmaxf(fmaf(bf2f(v[0]), s0.x, h0.x), 0.f));
    o[1] = f2bf(fmaxf(fmaf(bf2f(v[1]), s0.y, h0.y), 0.f));
    o[2] = f2bf(fmaxf(fmaf(bf2f(v[2]), s0.z, h0.z), 0.f));
    o[3] = f2bf(fmaxf(fmaf(bf2f(v[3]), s0.w, h0.w), 0.f));
    o[4] = f2bf(fmaxf(fmaf(bf2f(v[4]), s1.x, h1.x), 0.f));
    o[5] = f2bf(fmaxf(fmaf(bf2f(v[5]), s1.y, h1.y), 0.f));
    o[6] = f2bf(fmaxf(fmaf(bf2f(v[6]), s1.z, h1.z), 0.f));
    o[7] = f2bf(fmaxf(fmaf(bf2f(v[7]), s1.w, h1.w), 0.f));
    *(ushort8v*)&H[i * 8] = o;
  }
}

// ---------------- final: BN+ReLU + transpose [b][n][o] bf16 -> out [b][o][n] f32 ----------------
__global__ __launch_bounds__(256) void bnreluT_kernel(const unsigned short* __restrict__ Y,
                                                      const float* __restrict__ scale,
                                                      const float* __restrict__ shift,
                                                      float* __restrict__ out) {
  __shared__ float t[64][65];
  int n0 = blockIdx.x * 64, o0 = blockIdx.y * 64, b = blockIdx.z;
  int tid = threadIdx.x, r = tid >> 2, q = tid & 3;
  const unsigned short* yp = Y + ((size_t)b * N + n0 + r) * 256 + o0 + q * 16;
#pragma unroll
  for (int h = 0; h < 2; ++h) {
    ushort8v v = *(const ushort8v*)(yp + h * 8);
#pragma unroll
    for (int i = 0; i < 8; ++i) {
      int oc = q * 16 + h * 8 + i;
      float f = fmaxf(fmaf(bf2f(v[i]), scale[o0 + oc], shift[o0 + oc]), 0.f);
      t[oc][r] = f;
    }
  }
  __syncthreads();
  float* op = out + ((size_t)b * 256 + o0 + r) * N + n0 + q * 16;
#pragma unroll
  for (int i = 0; i < 4; ++i) {
    float4 v = make_float4(t[r][q * 16 + i * 4 + 0], t[r][q * 16 + i * 4 + 1],
                           t[r][q * 16 + i * 4 + 2], t[r][q * 16 + i * 4 + 3]);
    *(float4*)(op + i * 4) = v;
  }
}

extern "C" void kernel_launch(void* const* d_in, const int* in_sizes, int n_in,
                              void* d_out, int out_size, void* d_ws, size_t ws_size,
                              hipStream_t stream) {
  const float* xyz1 = (const float*)d_in[0];
  const float* xyz2 = (const float*)d_in[1];
  const float* points1 = (const float*)d_in[2];
  const float* points2 = (const float*)d_in[3];
  const float* w0 = (const float*)d_in[4];
  const float* b0 = (const float*)d_in[5];
  const float* g0 = (const float*)d_in[6];
  const float* be0 = (const float*)d_in[7];
  const float* w1 = (const float*)d_in[8];
  const float* b1 = (const float*)d_in[9];
  const float* g1 = (const float*)d_in[10];
  const float* be1 = (const float*)d_in[11];
  float* out = (float*)d_out;

  char* ws = (char*)d_ws;
  int* idxbuf = (int*)ws;              ws += (size_t)CNT * 3 * 4;      // 768KB
  float* wbuf = (float*)ws;            ws += (size_t)CNT * 3 * 4;      // 768KB
  float* scale0 = (float*)ws;          ws += 256 * 4;
  float* shift0 = (float*)ws;          ws += 256 * 4;
  float* scale1 = (float*)ws;          ws += 256 * 4;
  float* shift1 = (float*)ws;          ws += 256 * 4;
  float* psum = (float*)ws;            ws += (size_t)C * NSLOT * 4;    // 1MB
  float* psumsq = (float*)ws;          ws += (size_t)C * NSLOT * 4;    // 1MB
  unsigned short* w0b = (unsigned short*)ws;  ws += (size_t)C * CIN * 2;   // 256KB
  unsigned short* w1b = (unsigned short*)ws;  ws += (size_t)C * C * 2;     // 128KB
  unsigned short* p2t = (unsigned short*)ws;  ws += (size_t)B * S * 256 * 2;   // 8MB
  unsigned short* Xb = (unsigned short*)ws;   ws += (size_t)B * N * 512 * 2;   // 64MB
  unsigned short* Yb = (unsigned short*)ws;   ws += (size_t)B * N * 256 * 2;   // 32MB
  unsigned short* Hb = Xb;  // reuse Xb after GEMM0 consumed it

  convw_kernel<<<dim3((C * CIN + C * C) / 256), 256, 0, stream>>>(w0, w1, w0b, w1b);
  tconv_kernel<<<dim3(N / 64, 4, B), 256, 0, stream>>>(points1, Xb, N, 512, 0);
  tconv_kernel<<<dim3(S / 64, 4, B), 256, 0, stream>>>(points2, p2t, S, 256, 0);
  nn3_kernel<<<dim3(B * N / 64), 256, 0, stream>>>(xyz1, xyz2, idxbuf, wbuf);
  gather_kernel<<<dim3(B * N / 64), 256, 0, stream>>>(p2t, idxbuf, wbuf, Xb);
  gemm_kernel<<<dim3(N / 128, 2, B), 256, 0, stream>>>(Xb, w0b, b0, Yb, psum, psumsq, CIN);
  bnparam_kernel<<<dim3(C), 256, 0, stream>>>(psum, psumsq, g0, be0, scale0, shift0);
  bnrelu_kernel<<<dim3(2048), 256, 0, stream>>>(Yb, scale0, shift0, Hb);
  gemm_kernel<<<dim3(N / 128, 2, B), 256, 0, stream>>>(Hb, w1b, b1, Yb, psum, psumsq, C);
  bnparam_kernel<<<dim3(C), 256, 0, stream>>>(psum, psumsq, g1, be1, scale1, shift1);
  bnreluT_kernel<<<dim3(N / 64, 4, B), 256, 0, stream>>>(Yb, scale1, shift1, out);
}

// Round 11
// 229.913 us; speedup vs baseline: 3.3722x; 1.0563x over previous
//
#include <hip/hip_runtime.h>
#include <math.h>

#define B 8
#define N 8192
#define S 2048
#define SCH 1024  // points per LDS chunk
#define C 256
#define CIN 512
#define CNT (B * N)  // 65536
#define NSLOT 1024   // (b*64 + bx)*2 + wn

typedef unsigned long long ull;
typedef __attribute__((ext_vector_type(8))) short bf16x8;
typedef __attribute__((ext_vector_type(4))) float floatx4;
typedef __attribute__((ext_vector_type(8))) unsigned short ushort8v;
typedef __attribute__((ext_vector_type(4))) unsigned short ushort4v;

__device__ inline unsigned short f2bf(float f) {
  unsigned u = __builtin_bit_cast(unsigned, f);
  u += 0x7FFF + ((u >> 16) & 1);  // RNE
  return (unsigned short)(u >> 16);
}
__device__ inline float bf2f(unsigned short h) {
  unsigned u = ((unsigned)h) << 16;
  return __builtin_bit_cast(float, u);
}

__device__ inline void load_lds16(const void* g, void* l) {
  __builtin_amdgcn_global_load_lds(
      (const __attribute__((address_space(1))) unsigned int*)g,
      (__attribute__((address_space(3))) unsigned int*)l, 16, 0, 0);
}

// ---------------- 3-NN v11 ----------------
// Q=2 queries/thread, V=16 subs/query, grid 2048 (8 blocks/CU), S in two
// 1024-pt LDS chunks (16KB). Distance slots via fmed3/fmin (3 VALU, no
// cndmask chains); per-pair +q2 dropped (selection-invariant, re-added at
// output). Merge via LDS u64 keys with sortable-uint transform (dkey may be
// negative). Exact f32 ordering == top_k semantics throughout.
__device__ inline void ins3u(ull k, ull& k0, ull& k1, ull& k2) {
  if (k < k2) {
    if (k < k1) {
      k2 = k1;
      if (k < k0) { k1 = k0; k0 = k; } else k1 = k;
    } else k2 = k;
  }
}

__device__ inline unsigned sortkey(float f) {
  unsigned u = __float_as_uint(f);
  return u ^ (((unsigned)((int)u >> 31)) | 0x80000000u);
}
__device__ inline float unsortkey(unsigned u) {
  unsigned m = ((int)u < 0) ? 0x80000000u : 0xFFFFFFFFu;
  return __uint_as_float(u ^ m);
}

__device__ inline void out3q(ull k0, ull k1, ull k2, float q2v,
                             int* __restrict__ idxbuf, float* __restrict__ wbuf,
                             size_t o) {
  float e0 = fmaxf(unsortkey((unsigned)(k0 >> 32)) + q2v, 0.0f);
  float e1 = fmaxf(unsortkey((unsigned)(k1 >> 32)) + q2v, 0.0f);
  float e2 = fmaxf(unsortkey((unsigned)(k2 >> 32)) + q2v, 0.0f);
  float r0 = 1.0f / (e0 + 1e-8f);
  float r1 = 1.0f / (e1 + 1e-8f);
  float r2 = 1.0f / (e2 + 1e-8f);
  float rs = 1.0f / (r0 + r1 + r2);
  idxbuf[o] = (int)(unsigned)k0;
  idxbuf[o + 1] = (int)(unsigned)k1;
  idxbuf[o + 2] = (int)(unsigned)k2;
  wbuf[o] = r0 * rs; wbuf[o + 1] = r1 * rs; wbuf[o + 2] = r2 * rs;
}

#define QDECL(q)                                                            \
  float d0_##q = INFINITY, d1_##q = INFINITY, d2_##q = INFINITY;            \
  int i0_##q = 0, i1_##q = 0, i2_##q = 0;                                   \
  float qx_##q, qy_##q, qz_##q, q2_##q;

#define QLOAD(q)                                                            \
  {                                                                         \
    float ox = p1[nq + q], oy = p1[N + nq + q], oz = p1[2 * N + nq + q];    \
    q2_##q = ox * ox + oy * oy + oz * oz;                                   \
    qx_##q = -2.0f * ox; qy_##q = -2.0f * oy; qz_##q = -2.0f * oz;          \
  }

// dkey = -2 q.p + |p|^2 (true dist^2 = dkey + q2, added at output).
// i-selects read OLD d-compares; d-updates med3/min ordered d2<-d1<-d0.
#define QINS(q)                                                             \
  {                                                                         \
    float d = fmaf(qx_##q, pc.x, fmaf(qy_##q, pc.y, fmaf(qz_##q, pc.z, pc.w))); \
    bool lt0 = d < d0_##q, lt1 = d < d1_##q, lt2 = d < d2_##q;              \
    i2_##q = lt2 ? (lt1 ? i1_##q : s) : i2_##q;                             \
    i1_##q = lt1 ? (lt0 ? i0_##q : s) : i1_##q;                             \
    i0_##q = lt0 ? s : i0_##q;                                              \
    d2_##q = __builtin_amdgcn_fmed3f(d, d1_##q, d2_##q);                    \
    d1_##q = __builtin_amdgcn_fmed3f(d, d0_##q, d1_##q);                    \
    d0_##q = fminf(d, d0_##q);                                              \
  }

#define QSTORE(q)                                                           \
  {                                                                         \
    size_t kb = ((size_t)(grp * 2 + q) * 16 + sub) * 3;                     \
    keys[kb] = ((ull)sortkey(d0_##q) << 32) | (unsigned)i0_##q;             \
    keys[kb + 1] = ((ull)sortkey(d1_##q) << 32) | (unsigned)i1_##q;         \
    keys[kb + 2] = ((ull)sortkey(d2_##q) << 32) | (unsigned)i2_##q;         \
  }

__global__ __launch_bounds__(256, 4) void nn3_kernel(const float* __restrict__ xyz1,
                                                     const float* __restrict__ xyz2,
                                                     int* __restrict__ idxbuf,
                                                     float* __restrict__ wbuf) {
  __shared__ float4 sp[SCH];  // 16KB chunk; reused as u64 key buffer (12KB)
  int b = blockIdx.x >> 8;            // grid = B * (N/32) = 2048
  int n0 = (blockIdx.x & 255) * 32;
  const float* p2 = xyz2 + (size_t)b * 3 * S;
  int tid = threadIdx.x;
  int sub = tid & 15, grp = tid >> 4;  // 16 grps x 2 queries = 32 queries/block
  const float* p1 = xyz1 + (size_t)b * 3 * N;
  int nq = n0 + grp * 2;
  QDECL(0) QDECL(1)
  QLOAD(0) QLOAD(1)

  for (int ch = 0; ch < 2; ++ch) {
    if (ch) __syncthreads();
    for (int i = tid; i < SCH; i += 256) {
      int g = ch * SCH + i;
      float px = p2[g], py = p2[S + g], pz = p2[2 * S + g];
      sp[i] = make_float4(px, py, pz, px * px + py * py + pz * pz);
    }
    __syncthreads();
    int sbase = ch * SCH;
    float4 pc = sp[sub];
    for (int t = 0; t < SCH / 16 - 1; ++t) {
      float4 pn = sp[(t + 1) * 16 + sub];
      int s = sbase + t * 16 + sub;
      QINS(0) QINS(1)
      pc = pn;
    }
    {
      int s = sbase + SCH - 16 + sub;
      QINS(0) QINS(1)
    }
  }

  // merge via LDS keys (scan state dies here)
  __syncthreads();
  ull* keys = (ull*)sp;  // [32 queries][16 subs][3]
  QSTORE(0) QSTORE(1)
  __syncthreads();
  if (sub < 4) {
#pragma unroll
    for (int q = 0; q < 2; ++q) {
      size_t qb = (size_t)(grp * 2 + q) * 48;
      ull m0 = ~0ull, m1 = ~0ull, m2 = ~0ull;
#pragma unroll
      for (int jj = 0; jj < 4; ++jj) {
        size_t o2 = qb + (size_t)(sub + 4 * jj) * 3;
        ins3u(keys[o2], m0, m1, m2);
        ins3u(keys[o2 + 1], m0, m1, m2);
        ins3u(keys[o2 + 2], m0, m1, m2);
      }
#pragma unroll
      for (int mm = 1; mm <= 2; mm <<= 1) {
        ull e0 = (ull)__shfl_xor((long long)m0, mm);
        ull e1 = (ull)__shfl_xor((long long)m1, mm);
        ull e2 = (ull)__shfl_xor((long long)m2, mm);
        ins3u(e0, m0, m1, m2);
        ins3u(e1, m0, m1, m2);
        ins3u(e2, m0, m1, m2);
      }
      if (sub == 0) {
        float q2v = q ? q2_1 : q2_0;
        out3q(m0, m1, m2, q2v, idxbuf, wbuf, ((size_t)b * N + nq + q) * 3);
      }
    }
  }
}

// ---------------- weights f32 -> bf16 ----------------
__global__ __launch_bounds__(256) void convw_kernel(const float* __restrict__ w0,
                                                    const float* __restrict__ w1,
                                                    unsigned short* __restrict__ w0b,
                                                    unsigned short* __restrict__ w1b) {
  int i = blockIdx.x * 256 + threadIdx.x;
  if (i < C * CIN) w0b[i] = f2bf(w0[i]);
  else {
    int j = i - C * CIN;
    if (j < C * C) w1b[j] = f2bf(w1[j]);
  }
}

// ---------------- transpose+convert: src[b][256][cols] f32 -> dst[b][cols][drow] bf16 ----------------
__global__ __launch_bounds__(256) void tconv_kernel(const float* __restrict__ src,
                                                    unsigned short* __restrict__ dst,
                                                    int cols, int drow, int coff) {
  __shared__ float t[64][65];
  int n0 = blockIdx.x * 64, c0 = blockIdx.y * 64, b = blockIdx.z;
  int tid = threadIdx.x, r = tid >> 2, q = tid & 3;
  const float* sp = src + ((size_t)b * 256 + c0 + r) * cols + n0 + q * 16;
#pragma unroll
  for (int i = 0; i < 4; ++i) {
    float4 v = *(const float4*)(sp + i * 4);
    t[r][q * 16 + i * 4 + 0] = v.x;
    t[r][q * 16 + i * 4 + 1] = v.y;
    t[r][q * 16 + i * 4 + 2] = v.z;
    t[r][q * 16 + i * 4 + 3] = v.w;
  }
  __syncthreads();
  unsigned short* dp = dst + ((size_t)b * cols + n0 + r) * drow + coff + c0 + q * 16;
  ushort8v o0, o1;
#pragma unroll
  for (int i = 0; i < 8; ++i) o0[i] = f2bf(t[q * 16 + i][r]);
#pragma unroll
  for (int i = 0; i < 8; ++i) o1[i] = f2bf(t[q * 16 + 8 + i][r]);
  *(ushort8v*)dp = o0;
  *(ushort8v*)(dp + 8) = o1;
}

// ---------------- gather: Xb[b][n][256+c] = sum_j w_j * p2t[b][idx_j][c] ----------------
__global__ __launch_bounds__(256) void gather_kernel(const unsigned short* __restrict__ p2t,
                                                     const int* __restrict__ idxbuf,
                                                     const float* __restrict__ wbuf,
                                                     unsigned short* __restrict__ Xb) {
  __shared__ int si[192];
  __shared__ float sw[192];
  int b = blockIdx.x >> 7;  // grid = B * (N/64)
  int n0 = (blockIdx.x & 127) * 64;
  size_t base = ((size_t)b * N + n0) * 3;
  if (threadIdx.x < 192) {
    si[threadIdx.x] = idxbuf[base + threadIdx.x];
    sw[threadIdx.x] = wbuf[base + threadIdx.x];
  }
  __syncthreads();
  int nl = threadIdx.x >> 2, cb = threadIdx.x & 3;
  int j0 = si[nl * 3], j1 = si[nl * 3 + 1], j2 = si[nl * 3 + 2];
  float w0 = sw[nl * 3], w1 = sw[nl * 3 + 1], w2 = sw[nl * 3 + 2];
  const unsigned short* pb = p2t + (size_t)b * S * 256;
  const unsigned short* r0p = pb + (size_t)j0 * 256;
  const unsigned short* r1p = pb + (size_t)j1 * 256;
  const unsigned short* r2p = pb + (size_t)j2 * 256;
  unsigned short* xp = Xb + ((size_t)b * N + n0 + nl) * 512 + 256;
#pragma unroll
  for (int ch = 0; ch < 8; ++ch) {
    int co = (cb + ch * 4) * 8;
    ushort8v v0 = *(const ushort8v*)(r0p + co);
    ushort8v v1 = *(const ushort8v*)(r1p + co);
    ushort8v v2 = *(const ushort8v*)(r2p + co);
    ushort8v o;
#pragma unroll
    for (int i = 0; i < 8; ++i)
      o[i] = f2bf(w0 * bf2f(v0[i]) + w1 * bf2f(v1[i]) + w2 * bf2f(v2[i]));
    *(ushort8v*)(xp + co) = o;
  }
}

// ---------------- bf16 MFMA GEMM + channel-major partial stats (no atomics) ----------------
__global__ __launch_bounds__(256) void gemm_kernel(const unsigned short* __restrict__ X,
                                                   const unsigned short* __restrict__ Wb,
                                                   const float* __restrict__ bias,
                                                   unsigned short* __restrict__ Y,
                                                   float* __restrict__ psum,
                                                   float* __restrict__ psumsq,
                                                   int Cin) {
  __shared__ unsigned short As[128 * 32];  // [o_row][k] 8KB, swizzled
  __shared__ unsigned short Bs[128 * 32];  // [n_row][k] 8KB, swizzled
  int n0 = blockIdx.x * 128, o0 = blockIdx.y * 128, b = blockIdx.z;
  int tid = threadIdx.x, lane = tid & 63, wid = tid >> 6;
  int wm = wid >> 1, wn = wid & 1;
  floatx4 acc[4][4];
#pragma unroll
  for (int m = 0; m < 4; ++m)
#pragma unroll
    for (int nt = 0; nt < 4; ++nt) acc[m][nt] = (floatx4)(0.0f);

  size_t rsA = (size_t)Cin * 2;  // row stride bytes
  int chunkSwz = ((lane & 3) ^ ((lane >> 3) & 3)) * 16;
  const char* Abase = (const char*)Wb + (size_t)(o0 + wid * 32 + (lane >> 2)) * rsA + chunkSwz;
  const char* Bbase = (const char*)X + ((size_t)b * N + n0 + wid * 32 + (lane >> 2)) * rsA + chunkSwz;
  size_t rstep16 = 16 * rsA;
  int kq = (((lane >> 4) ^ ((lane >> 1) & 3))) * 8;

  for (int k0 = 0; k0 < Cin; k0 += 32) {
    load_lds16(Abase + (size_t)k0 * 2, &As[(wid * 32) * 32]);
    load_lds16(Abase + (size_t)k0 * 2 + rstep16, &As[(wid * 32 + 16) * 32]);
    load_lds16(Bbase + (size_t)k0 * 2, &Bs[(wid * 32) * 32]);
    load_lds16(Bbase + (size_t)k0 * 2 + rstep16, &Bs[(wid * 32 + 16) * 32]);
    __syncthreads();
    bf16x8 af[4], bfv[4];
#pragma unroll
    for (int m = 0; m < 4; ++m)
      af[m] = *(const bf16x8*)&As[(wm * 64 + m * 16 + (lane & 15)) * 32 + kq];
#pragma unroll
    for (int nt = 0; nt < 4; ++nt)
      bfv[nt] = *(const bf16x8*)&Bs[(wn * 64 + nt * 16 + (lane & 15)) * 32 + kq];
#pragma unroll
    for (int m = 0; m < 4; ++m)
#pragma unroll
      for (int nt = 0; nt < 4; ++nt)
        acc[m][nt] = __builtin_amdgcn_mfma_f32_16x16x32_bf16(af[m], bfv[nt], acc[m][nt], 0, 0, 0);
    __syncthreads();
  }

  int col = lane & 15, rowq = lane >> 4;
  int slot = ((b * 64 + blockIdx.x) * 2) + wn;
#pragma unroll
  for (int m = 0; m < 4; ++m) {
    int ob = o0 + wm * 64 + m * 16 + rowq * 4;
    float4 bs = *(const float4*)&bias[ob];
    float sj[4] = {0.f, 0.f, 0.f, 0.f}, qj[4] = {0.f, 0.f, 0.f, 0.f};
#pragma unroll
    for (int nt = 0; nt < 4; ++nt) {
      int n = n0 + wn * 64 + nt * 16 + col;
      float y0 = acc[m][nt][0] + bs.x;
      float y1 = acc[m][nt][1] + bs.y;
      float y2 = acc[m][nt][2] + bs.z;
      float y3 = acc[m][nt][3] + bs.w;
      ushort4v v;
      v[0] = f2bf(y0); v[1] = f2bf(y1); v[2] = f2bf(y2); v[3] = f2bf(y3);
      *(ushort4v*)&Y[((size_t)b * N + n) * 256 + ob] = v;
      sj[0] += y0; qj[0] = fmaf(y0, y0, qj[0]);
      sj[1] += y1; qj[1] = fmaf(y1, y1, qj[1]);
      sj[2] += y2; qj[2] = fmaf(y2, y2, qj[2]);
      sj[3] += y3; qj[3] = fmaf(y3, y3, qj[3]);
    }
#pragma unroll
    for (int j = 0; j < 4; ++j) {
#pragma unroll
      for (int d = 1; d <= 8; d <<= 1) {
        sj[j] += __shfl_xor(sj[j], d);
        qj[j] += __shfl_xor(qj[j], d);
      }
    }
    if (col == 0) {
      int c0 = blockIdx.y * 128 + wm * 64 + m * 16 + rowq * 4;
#pragma unroll
      for (int j = 0; j < 4; ++j) {
        psum[(size_t)(c0 + j) * NSLOT + slot] = sj[j];
        psumsq[(size_t)(c0 + j) * NSLOT + slot] = qj[j];
      }
    }
  }
}

// ---------------- parallel reduce partials -> BN scale/shift (256 blocks) ----------------
__global__ __launch_bounds__(256) void bnparam_kernel(const float* __restrict__ psum,
                                                      const float* __restrict__ psumsq,
                                                      const float* __restrict__ gamma,
                                                      const float* __restrict__ beta,
                                                      float* __restrict__ scale,
                                                      float* __restrict__ shift) {
  int c = blockIdx.x, tid = threadIdx.x;
  const float* ps = psum + (size_t)c * NSLOT;
  const float* pq = psumsq + (size_t)c * NSLOT;
  float s = 0.f, q = 0.f;
#pragma unroll
  for (int i = 0; i < NSLOT / 256; ++i) {
    s += ps[tid + i * 256];
    q += pq[tid + i * 256];
  }
#pragma unroll
  for (int d = 1; d <= 32; d <<= 1) {
    s += __shfl_xor(s, d);
    q += __shfl_xor(q, d);
  }
  __shared__ float ls[4], lq[4];
  int wid = tid >> 6;
  if ((tid & 63) == 0) { ls[wid] = s; lq[wid] = q; }
  __syncthreads();
  if (tid == 0) {
    s = ls[0] + ls[1] + ls[2] + ls[3];
    q = lq[0] + lq[1] + lq[2] + lq[3];
    float m = s * (1.0f / CNT);
    float v = q * (1.0f / CNT) - m * m;
    float sc = gamma[c] * rsqrtf(v + 1e-5f);
    scale[c] = sc;
    shift[c] = beta[c] - m * sc;
  }
}

// ---------------- BN+ReLU elementwise on [b][n][256] bf16 -> bf16 ----------------
__global__ __launch_bounds__(256) void bnrelu_kernel(const unsigned short* __restrict__ Y,
                                                     const float* __restrict__ scale,
                                                     const float* __restrict__ shift,
                                                     unsigned short* __restrict__ H) {
  size_t total = (size_t)B * N * 256 / 8;
  for (size_t i = (size_t)blockIdx.x * 256 + threadIdx.x; i < total;
       i += (size_t)gridDim.x * 256) {
    int ob = ((int)i & 31) * 8;
    float4 s0 = *(const float4*)&scale[ob];
    float4 s1 = *(const float4*)&scale[ob + 4];
    float4 h0 = *(const float4*)&shift[ob];
    float4 h1 = *(const float4*)&shift[ob + 4];
    ushort8v v = *(const ushort8v*)&Y[i * 8];
    ushort8v o;
    o[0] = f2bf(fmaxf(fmaf(bf2f(v[0]), s0.x, h0.x), 0.f));
    o[1] = f2bf(fmaxf(fmaf(bf2f(v[1]), s0.y, h0.y), 0.f));
    o[2] = f2bf(fmaxf(fmaf(bf2f(v[2]), s0.z, h0.z), 0.f));
    o[3] = f2bf(fmaxf(fmaf(bf2f(v[3]), s0.w, h0.w), 0.f));
    o[4] = f2bf(fmaxf(fmaf(bf2f(v[4]), s1.x, h1.x), 0.f));
    o[5] = f2bf(fmaxf(fmaf(bf2f(v[5]), s1.y, h1.y), 0.f));
    o[6] = f2bf(fmaxf(fmaf(bf2f(v[6]), s1.z, h1.z), 0.f));
    o[7] = f2bf(fmaxf(fmaf(bf2f(v[7]), s1.w, h1.w), 0.f));
    *(ushort8v*)&H[i * 8] = o;
  }
}

// ---------------- final: BN+ReLU + transpose [b][n][o] bf16 -> out [b][o][n] f32 ----------------
__global__ __launch_bounds__(256) void bnreluT_kernel(const unsigned short* __restrict__ Y,
                                                      const float* __restrict__ scale,
                                                      const float* __restrict__ shift,
                                                      float* __restrict__ out) {
  __shared__ float t[64][65];
  int n0 = blockIdx.x * 64, o0 = blockIdx.y * 64, b = blockIdx.z;
  int tid = threadIdx.x, r = tid >> 2, q = tid & 3;
  const unsigned short* yp = Y + ((size_t)b * N + n0 + r) * 256 + o0 + q * 16;
#pragma unroll
  for (int h = 0; h < 2; ++h) {
    ushort8v v = *(const ushort8v*)(yp + h * 8);
#pragma unroll
    for (int i = 0; i < 8; ++i) {
      int oc = q * 16 + h * 8 + i;
      float f = fmaxf(fmaf(bf2f(v[i]), scale[o0 + oc], shift[o0 + oc]), 0.f);
      t[oc][r] = f;
    }
  }
  __syncthreads();
  float* op = out + ((size_t)b * 256 + o0 + r) * N + n0 + q * 16;
#pragma unroll
  for (int i = 0; i < 4; ++i) {
    float4 v = make_float4(t[r][q * 16 + i * 4 + 0], t[r][q * 16 + i * 4 + 1],
                           t[r][q * 16 + i * 4 + 2], t[r][q * 16 + i * 4 + 3]);
    *(float4*)(op + i * 4) = v;
  }
}

extern "C" void kernel_launch(void* const* d_in, const int* in_sizes, int n_in,
                              void* d_out, int out_size, void* d_ws, size_t ws_size,
                              hipStream_t stream) {
  const float* xyz1 = (const float*)d_in[0];
  const float* xyz2 = (const float*)d_in[1];
  const float* points1 = (const float*)d_in[2];
  const float* points2 = (const float*)d_in[3];
  const float* w0 = (const float*)d_in[4];
  const float* b0 = (const float*)d_in[5];
  const float* g0 = (const float*)d_in[6];
  const float* be0 = (const float*)d_in[7];
  const float* w1 = (const float*)d_in[8];
  const float* b1 = (const float*)d_in[9];
  const float* g1 = (const float*)d_in[10];
  const float* be1 = (const float*)d_in[11];
  float* out = (float*)d_out;

  char* ws = (char*)d_ws;
  int* idxbuf = (int*)ws;              ws += (size_t)CNT * 3 * 4;      // 768KB
  float* wbuf = (float*)ws;            ws += (size_t)CNT * 3 * 4;      // 768KB
  float* scale0 = (float*)ws;          ws += 256 * 4;
  float* shift0 = (float*)ws;          ws += 256 * 4;
  float* scale1 = (float*)ws;          ws += 256 * 4;
  float* shift1 = (float*)ws;          ws += 256 * 4;
  float* psum = (float*)ws;            ws += (size_t)C * NSLOT * 4;    // 1MB
  float* psumsq = (float*)ws;          ws += (size_t)C * NSLOT * 4;    // 1MB
  unsigned short* w0b = (unsigned short*)ws;  ws += (size_t)C * CIN * 2;   // 256KB
  unsigned short* w1b = (unsigned short*)ws;  ws += (size_t)C * C * 2;     // 128KB
  unsigned short* p2t = (unsigned short*)ws;  ws += (size_t)B * S * 256 * 2;   // 8MB
  unsigned short* Xb = (unsigned short*)ws;   ws += (size_t)B * N * 512 * 2;   // 64MB
  unsigned short* Yb = (unsigned short*)ws;   ws += (size_t)B * N * 256 * 2;   // 32MB
  unsigned short* Hb = Xb;  // reuse Xb after GEMM0 consumed it

  convw_kernel<<<dim3((C * CIN + C * C) / 256), 256, 0, stream>>>(w0, w1, w0b, w1b);
  tconv_kernel<<<dim3(N / 64, 4, B), 256, 0, stream>>>(points1, Xb, N, 512, 0);
  tconv_kernel<<<dim3(S / 64, 4, B), 256, 0, stream>>>(points2, p2t, S, 256, 0);
  nn3_kernel<<<dim3(B * N / 32), 256, 0, stream>>>(xyz1, xyz2, idxbuf, wbuf);
  gather_kernel<<<dim3(B * N / 64), 256, 0, stream>>>(p2t, idxbuf, wbuf, Xb);
  gemm_kernel<<<dim3(N / 128, 2, B), 256, 0, stream>>>(Xb, w0b, b0, Yb, psum, psumsq, CIN);
  bnparam_kernel<<<dim3(C), 256, 0, stream>>>(psum, psumsq, g0, be0, scale0, shift0);
  bnrelu_kernel<<<dim3(2048), 256, 0, stream>>>(Yb, scale0, shift0, Hb);
  gemm_kernel<<<dim3(N / 128, 2, B), 256, 0, stream>>>(Hb, w1b, b1, Yb, psum, psumsq, C);
  bnparam_kernel<<<dim3(C), 256, 0, stream>>>(psum, psumsq, g1, be1, scale1, shift1);
  bnreluT_kernel<<<dim3(N / 64, 4, B), 256, 0, stream>>>(Yb, scale1, shift1, out);
}

// Round 12
// 223.792 us; speedup vs baseline: 3.4644x; 1.0273x over previous
//
#include <hip/hip_runtime.h>
#include <math.h>

#define B 8
#define N 8192
#define S 2048
#define SCH 1024  // points per LDS chunk
#define C 256
#define CIN 512
#define CNT (B * N)  // 65536
#define NSLOT 1024   // (b*64 + bx)*2 + wn

typedef unsigned long long ull;
typedef __attribute__((ext_vector_type(8))) short bf16x8;
typedef __attribute__((ext_vector_type(4))) float floatx4;
typedef __attribute__((ext_vector_type(8))) unsigned short ushort8v;
typedef __attribute__((ext_vector_type(4))) unsigned short ushort4v;

__device__ inline unsigned short f2bf(float f) {
  unsigned u = __builtin_bit_cast(unsigned, f);
  u += 0x7FFF + ((u >> 16) & 1);  // RNE
  return (unsigned short)(u >> 16);
}
__device__ inline float bf2f(unsigned short h) {
  unsigned u = ((unsigned)h) << 16;
  return __builtin_bit_cast(float, u);
}

__device__ inline void load_lds16(const void* g, void* l) {
  __builtin_amdgcn_global_load_lds(
      (const __attribute__((address_space(1))) unsigned int*)g,
      (__attribute__((address_space(3))) unsigned int*)l, 16, 0, 0);
}

// ---------------- 3-NN v12: r11 + unroll x2 dual prefetch ----------------
__device__ inline void ins3u(ull k, ull& k0, ull& k1, ull& k2) {
  if (k < k2) {
    if (k < k1) {
      k2 = k1;
      if (k < k0) { k1 = k0; k0 = k; } else k1 = k;
    } else k2 = k;
  }
}

__device__ inline unsigned sortkey(float f) {
  unsigned u = __float_as_uint(f);
  return u ^ (((unsigned)((int)u >> 31)) | 0x80000000u);
}
__device__ inline float unsortkey(unsigned u) {
  unsigned m = ((int)u < 0) ? 0x80000000u : 0xFFFFFFFFu;
  return __uint_as_float(u ^ m);
}

__device__ inline void out3q(ull k0, ull k1, ull k2, float q2v,
                             int* __restrict__ idxbuf, float* __restrict__ wbuf,
                             size_t o) {
  float e0 = fmaxf(unsortkey((unsigned)(k0 >> 32)) + q2v, 0.0f);
  float e1 = fmaxf(unsortkey((unsigned)(k1 >> 32)) + q2v, 0.0f);
  float e2 = fmaxf(unsortkey((unsigned)(k2 >> 32)) + q2v, 0.0f);
  float r0 = 1.0f / (e0 + 1e-8f);
  float r1 = 1.0f / (e1 + 1e-8f);
  float r2 = 1.0f / (e2 + 1e-8f);
  float rs = 1.0f / (r0 + r1 + r2);
  idxbuf[o] = (int)(unsigned)k0;
  idxbuf[o + 1] = (int)(unsigned)k1;
  idxbuf[o + 2] = (int)(unsigned)k2;
  wbuf[o] = r0 * rs; wbuf[o + 1] = r1 * rs; wbuf[o + 2] = r2 * rs;
}

#define QDECL(q)                                                            \
  float d0_##q = INFINITY, d1_##q = INFINITY, d2_##q = INFINITY;            \
  int i0_##q = 0, i1_##q = 0, i2_##q = 0;                                   \
  float qx_##q, qy_##q, qz_##q, q2_##q;

#define QLOAD(q)                                                            \
  {                                                                         \
    float ox = p1[nq + q], oy = p1[N + nq + q], oz = p1[2 * N + nq + q];    \
    q2_##q = ox * ox + oy * oy + oz * oz;                                   \
    qx_##q = -2.0f * ox; qy_##q = -2.0f * oy; qz_##q = -2.0f * oz;          \
  }

// dkey = -2 q.p + |p|^2 (true dist^2 = dkey + q2, added at output).
// i-selects read OLD d-compares; d-updates med3/min ordered d2<-d1<-d0.
#define QINS(q)                                                             \
  {                                                                         \
    float d = fmaf(qx_##q, pc.x, fmaf(qy_##q, pc.y, fmaf(qz_##q, pc.z, pc.w))); \
    bool lt0 = d < d0_##q, lt1 = d < d1_##q, lt2 = d < d2_##q;              \
    i2_##q = lt2 ? (lt1 ? i1_##q : s) : i2_##q;                             \
    i1_##q = lt1 ? (lt0 ? i0_##q : s) : i1_##q;                             \
    i0_##q = lt0 ? s : i0_##q;                                              \
    d2_##q = __builtin_amdgcn_fmed3f(d, d1_##q, d2_##q);                    \
    d1_##q = __builtin_amdgcn_fmed3f(d, d0_##q, d1_##q);                    \
    d0_##q = fminf(d, d0_##q);                                              \
  }

#define QSTORE(q)                                                           \
  {                                                                         \
    size_t kb = ((size_t)(grp * 2 + q) * 16 + sub) * 3;                     \
    keys[kb] = ((ull)sortkey(d0_##q) << 32) | (unsigned)i0_##q;             \
    keys[kb + 1] = ((ull)sortkey(d1_##q) << 32) | (unsigned)i1_##q;         \
    keys[kb + 2] = ((ull)sortkey(d2_##q) << 32) | (unsigned)i2_##q;         \
  }

__global__ __launch_bounds__(256, 4) void nn3_kernel(const float* __restrict__ xyz1,
                                                     const float* __restrict__ xyz2,
                                                     int* __restrict__ idxbuf,
                                                     float* __restrict__ wbuf) {
  __shared__ float4 sp[SCH];  // 16KB chunk; reused as u64 key buffer (12KB)
  int b = blockIdx.x >> 8;            // grid = B * (N/32) = 2048
  int n0 = (blockIdx.x & 255) * 32;
  const float* p2 = xyz2 + (size_t)b * 3 * S;
  int tid = threadIdx.x;
  int sub = tid & 15, grp = tid >> 4;  // 16 grps x 2 queries = 32 queries/block
  const float* p1 = xyz1 + (size_t)b * 3 * N;
  int nq = n0 + grp * 2;
  QDECL(0) QDECL(1)
  QLOAD(0) QLOAD(1)

  for (int ch = 0; ch < 2; ++ch) {
    if (ch) __syncthreads();
    for (int i = tid; i < SCH; i += 256) {
      int g = ch * SCH + i;
      float px = p2[g], py = p2[S + g], pz = p2[2 * S + g];
      sp[i] = make_float4(px, py, pz, px * px + py * py + pz * pz);
    }
    __syncthreads();
    int sbase = ch * SCH;
    const float4* spp = sp + sub;
    // dual-prefetch pipeline: 2 points in flight, body-per-read doubled
    float4 pcA = spp[0];
    float4 pcB = spp[16];
    for (int t = 0; t < SCH / 16 - 2; t += 2) {
      float4 pnA = spp[(t + 2) * 16];
      float4 pnB = spp[(t + 3) * 16];
      {
        float4 pc = pcA;
        int s = sbase + t * 16 + sub;
        QINS(0) QINS(1)
      }
      {
        float4 pc = pcB;
        int s = sbase + (t + 1) * 16 + sub;
        QINS(0) QINS(1)
      }
      pcA = pnA;
      pcB = pnB;
    }
    {
      float4 pc = pcA;
      int s = sbase + (SCH / 16 - 2) * 16 + sub;
      QINS(0) QINS(1)
    }
    {
      float4 pc = pcB;
      int s = sbase + (SCH / 16 - 1) * 16 + sub;
      QINS(0) QINS(1)
    }
  }

  // merge via LDS keys (scan state dies here)
  __syncthreads();
  ull* keys = (ull*)sp;  // [32 queries][16 subs][3]
  QSTORE(0) QSTORE(1)
  __syncthreads();
  if (sub < 4) {
#pragma unroll
    for (int q = 0; q < 2; ++q) {
      size_t qb = (size_t)(grp * 2 + q) * 48;
      ull m0 = ~0ull, m1 = ~0ull, m2 = ~0ull;
#pragma unroll
      for (int jj = 0; jj < 4; ++jj) {
        size_t o2 = qb + (size_t)(sub + 4 * jj) * 3;
        ins3u(keys[o2], m0, m1, m2);
        ins3u(keys[o2 + 1], m0, m1, m2);
        ins3u(keys[o2 + 2], m0, m1, m2);
      }
#pragma unroll
      for (int mm = 1; mm <= 2; mm <<= 1) {
        ull e0 = (ull)__shfl_xor((long long)m0, mm);
        ull e1 = (ull)__shfl_xor((long long)m1, mm);
        ull e2 = (ull)__shfl_xor((long long)m2, mm);
        ins3u(e0, m0, m1, m2);
        ins3u(e1, m0, m1, m2);
        ins3u(e2, m0, m1, m2);
      }
      if (sub == 0) {
        float q2v = q ? q2_1 : q2_0;
        out3q(m0, m1, m2, q2v, idxbuf, wbuf, ((size_t)b * N + nq + q) * 3);
      }
    }
  }
}

// ---------------- fused prep: tconv(points1), tconv(points2), weight convert ----------------
__device__ inline void tconv_body(const float* __restrict__ src,
                                  unsigned short* __restrict__ dst,
                                  int cols, int drow, int bx, int by, int bz,
                                  float (*t)[65]) {
  int n0 = bx * 64, c0 = by * 64, b = bz;
  int tid = threadIdx.x, r = tid >> 2, q = tid & 3;
  const float* sp = src + ((size_t)b * 256 + c0 + r) * cols + n0 + q * 16;
#pragma unroll
  for (int i = 0; i < 4; ++i) {
    float4 v = *(const float4*)(sp + i * 4);
    t[r][q * 16 + i * 4 + 0] = v.x;
    t[r][q * 16 + i * 4 + 1] = v.y;
    t[r][q * 16 + i * 4 + 2] = v.z;
    t[r][q * 16 + i * 4 + 3] = v.w;
  }
  __syncthreads();
  unsigned short* dp = dst + ((size_t)b * cols + n0 + r) * drow + c0 + q * 16;
  ushort8v o0, o1;
#pragma unroll
  for (int i = 0; i < 8; ++i) o0[i] = f2bf(t[q * 16 + i][r]);
#pragma unroll
  for (int i = 0; i < 8; ++i) o1[i] = f2bf(t[q * 16 + 8 + i][r]);
  *(ushort8v*)dp = o0;
  *(ushort8v*)(dp + 8) = o1;
}

__global__ __launch_bounds__(256) void prep_kernel(const float* __restrict__ points1,
                                                   const float* __restrict__ points2,
                                                   const float* __restrict__ w0,
                                                   const float* __restrict__ w1,
                                                   unsigned short* __restrict__ Xb,
                                                   unsigned short* __restrict__ p2t,
                                                   unsigned short* __restrict__ w0b,
                                                   unsigned short* __restrict__ w1b) {
  __shared__ float t[64][65];
  int id = blockIdx.x;
  if (id < 4096) {  // points1 -> Xb[.][0:256], drow 512
    tconv_body(points1, Xb, N, 512, id & 127, (id >> 7) & 3, id >> 9, t);
  } else if (id < 5120) {  // points2 -> p2t, drow 256
    id -= 4096;
    tconv_body(points2, p2t, S, 256, id & 31, (id >> 5) & 3, id >> 7, t);
  } else {  // weights
    int i = (id - 5120) * 256 + threadIdx.x;
    if (i < C * CIN) w0b[i] = f2bf(w0[i]);
    else {
      int j = i - C * CIN;
      if (j < C * C) w1b[j] = f2bf(w1[j]);
    }
  }
}

// ---------------- gather: Xb[b][n][256+c] = sum_j w_j * p2t[b][idx_j][c] ----------------
__global__ __launch_bounds__(256) void gather_kernel(const unsigned short* __restrict__ p2t,
                                                     const int* __restrict__ idxbuf,
                                                     const float* __restrict__ wbuf,
                                                     unsigned short* __restrict__ Xb) {
  __shared__ int si[192];
  __shared__ float sw[192];
  int b = blockIdx.x >> 7;  // grid = B * (N/64)
  int n0 = (blockIdx.x & 127) * 64;
  size_t base = ((size_t)b * N + n0) * 3;
  if (threadIdx.x < 192) {
    si[threadIdx.x] = idxbuf[base + threadIdx.x];
    sw[threadIdx.x] = wbuf[base + threadIdx.x];
  }
  __syncthreads();
  int nl = threadIdx.x >> 2, cb = threadIdx.x & 3;
  int j0 = si[nl * 3], j1 = si[nl * 3 + 1], j2 = si[nl * 3 + 2];
  float w0 = sw[nl * 3], w1 = sw[nl * 3 + 1], w2 = sw[nl * 3 + 2];
  const unsigned short* pb = p2t + (size_t)b * S * 256;
  const unsigned short* r0p = pb + (size_t)j0 * 256;
  const unsigned short* r1p = pb + (size_t)j1 * 256;
  const unsigned short* r2p = pb + (size_t)j2 * 256;
  unsigned short* xp = Xb + ((size_t)b * N + n0 + nl) * 512 + 256;
#pragma unroll
  for (int ch = 0; ch < 8; ++ch) {
    int co = (cb + ch * 4) * 8;
    ushort8v v0 = *(const ushort8v*)(r0p + co);
    ushort8v v1 = *(const ushort8v*)(r1p + co);
    ushort8v v2 = *(const ushort8v*)(r2p + co);
    ushort8v o;
#pragma unroll
    for (int i = 0; i < 8; ++i)
      o[i] = f2bf(w0 * bf2f(v0[i]) + w1 * bf2f(v1[i]) + w2 * bf2f(v2[i]));
    *(ushort8v*)(xp + co) = o;
  }
}

// ---------------- bf16 MFMA GEMM + channel-major partial stats (no atomics) ----------------
__global__ __launch_bounds__(256) void gemm_kernel(const unsigned short* __restrict__ X,
                                                   const unsigned short* __restrict__ Wb,
                                                   const float* __restrict__ bias,
                                                   unsigned short* __restrict__ Y,
                                                   float* __restrict__ psum,
                                                   float* __restrict__ psumsq,
                                                   int Cin) {
  __shared__ unsigned short As[128 * 32];  // [o_row][k] 8KB, swizzled
  __shared__ unsigned short Bs[128 * 32];  // [n_row][k] 8KB, swizzled
  int n0 = blockIdx.x * 128, o0 = blockIdx.y * 128, b = blockIdx.z;
  int tid = threadIdx.x, lane = tid & 63, wid = tid >> 6;
  int wm = wid >> 1, wn = wid & 1;
  floatx4 acc[4][4];
#pragma unroll
  for (int m = 0; m < 4; ++m)
#pragma unroll
    for (int nt = 0; nt < 4; ++nt) acc[m][nt] = (floatx4)(0.0f);

  size_t rsA = (size_t)Cin * 2;  // row stride bytes
  int chunkSwz = ((lane & 3) ^ ((lane >> 3) & 3)) * 16;
  const char* Abase = (const char*)Wb + (size_t)(o0 + wid * 32 + (lane >> 2)) * rsA + chunkSwz;
  const char* Bbase = (const char*)X + ((size_t)b * N + n0 + wid * 32 + (lane >> 2)) * rsA + chunkSwz;
  size_t rstep16 = 16 * rsA;
  int kq = (((lane >> 4) ^ ((lane >> 1) & 3))) * 8;

  for (int k0 = 0; k0 < Cin; k0 += 32) {
    load_lds16(Abase + (size_t)k0 * 2, &As[(wid * 32) * 32]);
    load_lds16(Abase + (size_t)k0 * 2 + rstep16, &As[(wid * 32 + 16) * 32]);
    load_lds16(Bbase + (size_t)k0 * 2, &Bs[(wid * 32) * 32]);
    load_lds16(Bbase + (size_t)k0 * 2 + rstep16, &Bs[(wid * 32 + 16) * 32]);
    __syncthreads();
    bf16x8 af[4], bfv[4];
#pragma unroll
    for (int m = 0; m < 4; ++m)
      af[m] = *(const bf16x8*)&As[(wm * 64 + m * 16 + (lane & 15)) * 32 + kq];
#pragma unroll
    for (int nt = 0; nt < 4; ++nt)
      bfv[nt] = *(const bf16x8*)&Bs[(wn * 64 + nt * 16 + (lane & 15)) * 32 + kq];
#pragma unroll
    for (int m = 0; m < 4; ++m)
#pragma unroll
      for (int nt = 0; nt < 4; ++nt)
        acc[m][nt] = __builtin_amdgcn_mfma_f32_16x16x32_bf16(af[m], bfv[nt], acc[m][nt], 0, 0, 0);
    __syncthreads();
  }

  int col = lane & 15, rowq = lane >> 4;
  int slot = ((b * 64 + blockIdx.x) * 2) + wn;
#pragma unroll
  for (int m = 0; m < 4; ++m) {
    int ob = o0 + wm * 64 + m * 16 + rowq * 4;
    float4 bs = *(const float4*)&bias[ob];
    float sj[4] = {0.f, 0.f, 0.f, 0.f}, qj[4] = {0.f, 0.f, 0.f, 0.f};
#pragma unroll
    for (int nt = 0; nt < 4; ++nt) {
      int n = n0 + wn * 64 + nt * 16 + col;
      float y0 = acc[m][nt][0] + bs.x;
      float y1 = acc[m][nt][1] + bs.y;
      float y2 = acc[m][nt][2] + bs.z;
      float y3 = acc[m][nt][3] + bs.w;
      ushort4v v;
      v[0] = f2bf(y0); v[1] = f2bf(y1); v[2] = f2bf(y2); v[3] = f2bf(y3);
      *(ushort4v*)&Y[((size_t)b * N + n) * 256 + ob] = v;
      sj[0] += y0; qj[0] = fmaf(y0, y0, qj[0]);
      sj[1] += y1; qj[1] = fmaf(y1, y1, qj[1]);
      sj[2] += y2; qj[2] = fmaf(y2, y2, qj[2]);
      sj[3] += y3; qj[3] = fmaf(y3, y3, qj[3]);
    }
#pragma unroll
    for (int j = 0; j < 4; ++j) {
#pragma unroll
      for (int d = 1; d <= 8; d <<= 1) {
        sj[j] += __shfl_xor(sj[j], d);
        qj[j] += __shfl_xor(qj[j], d);
      }
    }
    if (col == 0) {
      int c0 = blockIdx.y * 128 + wm * 64 + m * 16 + rowq * 4;
#pragma unroll
      for (int j = 0; j < 4; ++j) {
        psum[(size_t)(c0 + j) * NSLOT + slot] = sj[j];
        psumsq[(size_t)(c0 + j) * NSLOT + slot] = qj[j];
      }
    }
  }
}

// ---------------- parallel reduce partials -> BN scale/shift (256 blocks) ----------------
__global__ __launch_bounds__(256) void bnparam_kernel(const float* __restrict__ psum,
                                                      const float* __restrict__ psumsq,
                                                      const float* __restrict__ gamma,
                                                      const float* __restrict__ beta,
                                                      float* __restrict__ scale,
                                                      float* __restrict__ shift) {
  int c = blockIdx.x, tid = threadIdx.x;
  const float* ps = psum + (size_t)c * NSLOT;
  const float* pq = psumsq + (size_t)c * NSLOT;
  float s = 0.f, q = 0.f;
#pragma unroll
  for (int i = 0; i < NSLOT / 256; ++i) {
    s += ps[tid + i * 256];
    q += pq[tid + i * 256];
  }
#pragma unroll
  for (int d = 1; d <= 32; d <<= 1) {
    s += __shfl_xor(s, d);
    q += __shfl_xor(q, d);
  }
  __shared__ float ls[4], lq[4];
  int wid = tid >> 6;
  if ((tid & 63) == 0) { ls[wid] = s; lq[wid] = q; }
  __syncthreads();
  if (tid == 0) {
    s = ls[0] + ls[1] + ls[2] + ls[3];
    q = lq[0] + lq[1] + lq[2] + lq[3];
    float m = s * (1.0f / CNT);
    float v = q * (1.0f / CNT) - m * m;
    float sc = gamma[c] * rsqrtf(v + 1e-5f);
    scale[c] = sc;
    shift[c] = beta[c] - m * sc;
  }
}

// ---------------- BN+ReLU elementwise on [b][n][256] bf16 -> bf16 ----------------
__global__ __launch_bounds__(256) void bnrelu_kernel(const unsigned short* __restrict__ Y,
                                                     const float* __restrict__ scale,
                                                     const float* __restrict__ shift,
                                                     unsigned short* __restrict__ H) {
  size_t total = (size_t)B * N * 256 / 8;
  for (size_t i = (size_t)blockIdx.x * 256 + threadIdx.x; i < total;
       i += (size_t)gridDim.x * 256) {
    int ob = ((int)i & 31) * 8;
    float4 s0 = *(const float4*)&scale[ob];
    float4 s1 = *(const float4*)&scale[ob + 4];
    float4 h0 = *(const float4*)&shift[ob];
    float4 h1 = *(const float4*)&shift[ob + 4];
    ushort8v v = *(const ushort8v*)&Y[i * 8];
    ushort8v o;
    o[0] = f2bf(fmaxf(fmaf(bf2f(v[0]), s0.x, h0.x), 0.f));
    o[1] = f2bf(fmaxf(fmaf(bf2f(v[1]), s0.y, h0.y), 0.f));
    o[2] = f2bf(fmaxf(fmaf(bf2f(v[2]), s0.z, h0.z), 0.f));
    o[3] = f2bf(fmaxf(fmaf(bf2f(v[3]), s0.w, h0.w), 0.f));
    o[4] = f2bf(fmaxf(fmaf(bf2f(v[4]), s1.x, h1.x), 0.f));
    o[5] = f2bf(fmaxf(fmaf(bf2f(v[5]), s1.y, h1.y), 0.f));
    o[6] = f2bf(fmaxf(fmaf(bf2f(v[6]), s1.z, h1.z), 0.f));
    o[7] = f2bf(fmaxf(fmaf(bf2f(v[7]), s1.w, h1.w), 0.f));
    *(ushort8v*)&H[i * 8] = o;
  }
}

// ---------------- final: BN+ReLU + transpose [b][n][o] bf16 -> out [b][o][n] f32 ----------------
__global__ __launch_bounds__(256) void bnreluT_kernel(const unsigned short* __restrict__ Y,
                                                      const float* __restrict__ scale,
                                                      const float* __restrict__ shift,
                                                      float* __restrict__ out) {
  __shared__ float t[64][65];
  int n0 = blockIdx.x * 64, o0 = blockIdx.y * 64, b = blockIdx.z;
  int tid = threadIdx.x, r = tid >> 2, q = tid & 3;
  const unsigned short* yp = Y + ((size_t)b * N + n0 + r) * 256 + o0 + q * 16;
#pragma unroll
  for (int h = 0; h < 2; ++h) {
    ushort8v v = *(const ushort8v*)(yp + h * 8);
#pragma unroll
    for (int i = 0; i < 8; ++i) {
      int oc = q * 16 + h * 8 + i;
      float f = fmaxf(fmaf(bf2f(v[i]), scale[o0 + oc], shift[o0 + oc]), 0.f);
      t[oc][r] = f;
    }
  }
  __syncthreads();
  float* op = out + ((size_t)b * 256 + o0 + r) * N + n0 + q * 16;
#pragma unroll
  for (int i = 0; i < 4; ++i) {
    float4 v = make_float4(t[r][q * 16 + i * 4 + 0], t[r][q * 16 + i * 4 + 1],
                           t[r][q * 16 + i * 4 + 2], t[r][q * 16 + i * 4 + 3]);
    *(float4*)(op + i * 4) = v;
  }
}

extern "C" void kernel_launch(void* const* d_in, const int* in_sizes, int n_in,
                              void* d_out, int out_size, void* d_ws, size_t ws_size,
                              hipStream_t stream) {
  const float* xyz1 = (const float*)d_in[0];
  const float* xyz2 = (const float*)d_in[1];
  const float* points1 = (const float*)d_in[2];
  const float* points2 = (const float*)d_in[3];
  const float* w0 = (const float*)d_in[4];
  const float* b0 = (const float*)d_in[5];
  const float* g0 = (const float*)d_in[6];
  const float* be0 = (const float*)d_in[7];
  const float* w1 = (const float*)d_in[8];
  const float* b1 = (const float*)d_in[9];
  const float* g1 = (const float*)d_in[10];
  const float* be1 = (const float*)d_in[11];
  float* out = (float*)d_out;

  char* ws = (char*)d_ws;
  int* idxbuf = (int*)ws;              ws += (size_t)CNT * 3 * 4;      // 768KB
  float* wbuf = (float*)ws;            ws += (size_t)CNT * 3 * 4;      // 768KB
  float* scale0 = (float*)ws;          ws += 256 * 4;
  float* shift0 = (float*)ws;          ws += 256 * 4;
  float* scale1 = (float*)ws;          ws += 256 * 4;
  float* shift1 = (float*)ws;          ws += 256 * 4;
  float* psum = (float*)ws;            ws += (size_t)C * NSLOT * 4;    // 1MB
  float* psumsq = (float*)ws;          ws += (size_t)C * NSLOT * 4;    // 1MB
  unsigned short* w0b = (unsigned short*)ws;  ws += (size_t)C * CIN * 2;   // 256KB
  unsigned short* w1b = (unsigned short*)ws;  ws += (size_t)C * C * 2;     // 128KB
  unsigned short* p2t = (unsigned short*)ws;  ws += (size_t)B * S * 256 * 2;   // 8MB
  unsigned short* Xb = (unsigned short*)ws;   ws += (size_t)B * N * 512 * 2;   // 64MB
  unsigned short* Yb = (unsigned short*)ws;   ws += (size_t)B * N * 256 * 2;   // 32MB
  unsigned short* Hb = Xb;  // reuse Xb after GEMM0 consumed it

  prep_kernel<<<dim3(4096 + 1024 + 768), 256, 0, stream>>>(points1, points2, w0, w1,
                                                           Xb, p2t, w0b, w1b);
  nn3_kernel<<<dim3(B * N / 32), 256, 0, stream>>>(xyz1, xyz2, idxbuf, wbuf);
  gather_kernel<<<dim3(B * N / 64), 256, 0, stream>>>(p2t, idxbuf, wbuf, Xb);
  gemm_kernel<<<dim3(N / 128, 2, B), 256, 0, stream>>>(Xb, w0b, b0, Yb, psum, psumsq, CIN);
  bnparam_kernel<<<dim3(C), 256, 0, stream>>>(psum, psumsq, g0, be0, scale0, shift0);
  bnrelu_kernel<<<dim3(2048), 256, 0, stream>>>(Yb, scale0, shift0, Hb);
  gemm_kernel<<<dim3(N / 128, 2, B), 256, 0, stream>>>(Hb, w1b, b1, Yb, psum, psumsq, C);
  bnparam_kernel<<<dim3(C), 256, 0, stream>>>(psum, psumsq, g1, be1, scale1, shift1);
  bnreluT_kernel<<<dim3(N / 64, 4, B), 256, 0, stream>>>(Yb, scale1, shift1, out);
}

// Round 13
// 212.196 us; speedup vs baseline: 3.6538x; 1.0546x over previous
//
#include <hip/hip_runtime.h>
#include <math.h>

#define B 8
#define N 8192
#define S 2048
#define SCH 1024  // points per LDS chunk
#define C 256
#define CIN 512
#define CNT (B * N)  // 65536
#define NSLOT 1024   // (b*64 + bx)*2 + wn

typedef unsigned long long ull;
typedef __attribute__((ext_vector_type(8))) short bf16x8;
typedef __attribute__((ext_vector_type(4))) float floatx4;
typedef __attribute__((ext_vector_type(8))) unsigned short ushort8v;
typedef __attribute__((ext_vector_type(4))) unsigned short ushort4v;

__device__ inline unsigned short f2bf(float f) {
  unsigned u = __builtin_bit_cast(unsigned, f);
  u += 0x7FFF + ((u >> 16) & 1);  // RNE
  return (unsigned short)(u >> 16);
}
__device__ inline float bf2f(unsigned short h) {
  unsigned u = ((unsigned)h) << 16;
  return __builtin_bit_cast(float, u);
}

__device__ inline void load_lds16(const void* g, void* l) {
  __builtin_amdgcn_global_load_lds(
      (const __attribute__((address_space(1))) unsigned int*)g,
      (__attribute__((address_space(3))) unsigned int*)l, 16, 0, 0);
}

// ---------------- 3-NN v13: r12 scan/merge + fused gather tail ----------------
// After the LDS-key merge, idx/weights go to a tiny LDS array (not global);
// all 256 threads then gather the 256 interp channels for the block's 32
// queries straight into Xb. Removes gather_kernel + idxbuf/wbuf round-trip;
// the tail's memory phase overlaps other blocks' VALU scan phase.
__device__ inline void ins3u(ull k, ull& k0, ull& k1, ull& k2) {
  if (k < k2) {
    if (k < k1) {
      k2 = k1;
      if (k < k0) { k1 = k0; k0 = k; } else k1 = k;
    } else k2 = k;
  }
}

__device__ inline unsigned sortkey(float f) {
  unsigned u = __float_as_uint(f);
  return u ^ (((unsigned)((int)u >> 31)) | 0x80000000u);
}
__device__ inline float unsortkey(unsigned u) {
  unsigned m = ((int)u < 0) ? 0x80000000u : 0xFFFFFFFFu;
  return __uint_as_float(u ^ m);
}

#define QDECL(q)                                                            \
  float d0_##q = INFINITY, d1_##q = INFINITY, d2_##q = INFINITY;            \
  int i0_##q = 0, i1_##q = 0, i2_##q = 0;                                   \
  float qx_##q, qy_##q, qz_##q, q2_##q;

#define QLOAD(q)                                                            \
  {                                                                         \
    float ox = p1[nq + q], oy = p1[N + nq + q], oz = p1[2 * N + nq + q];    \
    q2_##q = ox * ox + oy * oy + oz * oz;                                   \
    qx_##q = -2.0f * ox; qy_##q = -2.0f * oy; qz_##q = -2.0f * oz;          \
  }

// dkey = -2 q.p + |p|^2 (true dist^2 = dkey + q2, added at output).
// i-selects read OLD d-compares; d-updates med3/min ordered d2<-d1<-d0.
#define QINS(q)                                                             \
  {                                                                         \
    float d = fmaf(qx_##q, pc.x, fmaf(qy_##q, pc.y, fmaf(qz_##q, pc.z, pc.w))); \
    bool lt0 = d < d0_##q, lt1 = d < d1_##q, lt2 = d < d2_##q;              \
    i2_##q = lt2 ? (lt1 ? i1_##q : s) : i2_##q;                             \
    i1_##q = lt1 ? (lt0 ? i0_##q : s) : i1_##q;                             \
    i0_##q = lt0 ? s : i0_##q;                                              \
    d2_##q = __builtin_amdgcn_fmed3f(d, d1_##q, d2_##q);                    \
    d1_##q = __builtin_amdgcn_fmed3f(d, d0_##q, d1_##q);                    \
    d0_##q = fminf(d, d0_##q);                                              \
  }

#define QSTORE(q)                                                           \
  {                                                                         \
    size_t kb = ((size_t)(grp * 2 + q) * 16 + sub) * 3;                     \
    keys[kb] = ((ull)sortkey(d0_##q) << 32) | (unsigned)i0_##q;             \
    keys[kb + 1] = ((ull)sortkey(d1_##q) << 32) | (unsigned)i1_##q;         \
    keys[kb + 2] = ((ull)sortkey(d2_##q) << 32) | (unsigned)i2_##q;         \
  }

__global__ __launch_bounds__(256, 4) void nn3_kernel(const float* __restrict__ xyz1,
                                                     const float* __restrict__ xyz2,
                                                     const unsigned short* __restrict__ p2t,
                                                     unsigned short* __restrict__ Xb) {
  __shared__ float4 sp[SCH];  // 16KB chunk; reused as u64 key buffer (12KB)
  __shared__ int sidx[32][3];
  __shared__ float swt[32][3];
  int b = blockIdx.x >> 8;            // grid = B * (N/32) = 2048
  int n0 = (blockIdx.x & 255) * 32;
  const float* p2 = xyz2 + (size_t)b * 3 * S;
  int tid = threadIdx.x;
  int sub = tid & 15, grp = tid >> 4;  // 16 grps x 2 queries = 32 queries/block
  const float* p1 = xyz1 + (size_t)b * 3 * N;
  int nq = n0 + grp * 2;
  QDECL(0) QDECL(1)
  QLOAD(0) QLOAD(1)

  for (int ch = 0; ch < 2; ++ch) {
    if (ch) __syncthreads();
    for (int i = tid; i < SCH; i += 256) {
      int g = ch * SCH + i;
      float px = p2[g], py = p2[S + g], pz = p2[2 * S + g];
      sp[i] = make_float4(px, py, pz, px * px + py * py + pz * pz);
    }
    __syncthreads();
    int sbase = ch * SCH;
    const float4* spp = sp + sub;
    float4 pcA = spp[0];
    float4 pcB = spp[16];
    for (int t = 0; t < SCH / 16 - 2; t += 2) {
      float4 pnA = spp[(t + 2) * 16];
      float4 pnB = spp[(t + 3) * 16];
      {
        float4 pc = pcA;
        int s = sbase + t * 16 + sub;
        QINS(0) QINS(1)
      }
      {
        float4 pc = pcB;
        int s = sbase + (t + 1) * 16 + sub;
        QINS(0) QINS(1)
      }
      pcA = pnA;
      pcB = pnB;
    }
    {
      float4 pc = pcA;
      int s = sbase + (SCH / 16 - 2) * 16 + sub;
      QINS(0) QINS(1)
    }
    {
      float4 pc = pcB;
      int s = sbase + (SCH / 16 - 1) * 16 + sub;
      QINS(0) QINS(1)
    }
  }

  // merge via LDS keys (scan state dies here)
  __syncthreads();
  ull* keys = (ull*)sp;  // [32 queries][16 subs][3]
  QSTORE(0) QSTORE(1)
  __syncthreads();
  if (sub < 4) {
#pragma unroll
    for (int q = 0; q < 2; ++q) {
      size_t qb = (size_t)(grp * 2 + q) * 48;
      ull m0 = ~0ull, m1 = ~0ull, m2 = ~0ull;
#pragma unroll
      for (int jj = 0; jj < 4; ++jj) {
        size_t o2 = qb + (size_t)(sub + 4 * jj) * 3;
        ins3u(keys[o2], m0, m1, m2);
        ins3u(keys[o2 + 1], m0, m1, m2);
        ins3u(keys[o2 + 2], m0, m1, m2);
      }
#pragma unroll
      for (int mm = 1; mm <= 2; mm <<= 1) {
        ull e0 = (ull)__shfl_xor((long long)m0, mm);
        ull e1 = (ull)__shfl_xor((long long)m1, mm);
        ull e2 = (ull)__shfl_xor((long long)m2, mm);
        ins3u(e0, m0, m1, m2);
        ins3u(e1, m0, m1, m2);
        ins3u(e2, m0, m1, m2);
      }
      if (sub == 0) {
        float q2v = q ? q2_1 : q2_0;
        int qi = grp * 2 + q;
        float e0 = fmaxf(unsortkey((unsigned)(m0 >> 32)) + q2v, 0.0f);
        float e1 = fmaxf(unsortkey((unsigned)(m1 >> 32)) + q2v, 0.0f);
        float e2 = fmaxf(unsortkey((unsigned)(m2 >> 32)) + q2v, 0.0f);
        float r0 = 1.0f / (e0 + 1e-8f);
        float r1 = 1.0f / (e1 + 1e-8f);
        float r2 = 1.0f / (e2 + 1e-8f);
        float rs = 1.0f / (r0 + r1 + r2);
        sidx[qi][0] = (int)(unsigned)m0;
        sidx[qi][1] = (int)(unsigned)m1;
        sidx[qi][2] = (int)(unsigned)m2;
        swt[qi][0] = r0 * rs;
        swt[qi][1] = r1 * rs;
        swt[qi][2] = r2 * rs;
      }
    }
  }
  __syncthreads();

  // fused gather tail: 8 threads per query, 4 x 16B chunks each
  int qi = tid >> 3, cc = tid & 7;
  int j0 = sidx[qi][0], j1 = sidx[qi][1], j2 = sidx[qi][2];
  float w0v = swt[qi][0], w1v = swt[qi][1], w2v = swt[qi][2];
  const unsigned short* pb = p2t + (size_t)b * S * 256;
  const unsigned short* r0p = pb + (size_t)j0 * 256;
  const unsigned short* r1p = pb + (size_t)j1 * 256;
  const unsigned short* r2p = pb + (size_t)j2 * 256;
  unsigned short* xp = Xb + ((size_t)b * N + n0 + qi) * 512 + 256;
#pragma unroll
  for (int h = 0; h < 4; ++h) {
    int co = (cc + h * 8) * 8;
    ushort8v v0 = *(const ushort8v*)(r0p + co);
    ushort8v v1 = *(const ushort8v*)(r1p + co);
    ushort8v v2 = *(const ushort8v*)(r2p + co);
    ushort8v o;
#pragma unroll
    for (int i = 0; i < 8; ++i)
      o[i] = f2bf(w0v * bf2f(v0[i]) + w1v * bf2f(v1[i]) + w2v * bf2f(v2[i]));
    *(ushort8v*)(xp + co) = o;
  }
}

// ---------------- fused prep: tconv(points1), tconv(points2), weight convert ----------------
__device__ inline void tconv_body(const float* __restrict__ src,
                                  unsigned short* __restrict__ dst,
                                  int cols, int drow, int bx, int by, int bz,
                                  float (*t)[65]) {
  int n0 = bx * 64, c0 = by * 64, b = bz;
  int tid = threadIdx.x, r = tid >> 2, q = tid & 3;
  const float* sp = src + ((size_t)b * 256 + c0 + r) * cols + n0 + q * 16;
#pragma unroll
  for (int i = 0; i < 4; ++i) {
    float4 v = *(const float4*)(sp + i * 4);
    t[r][q * 16 + i * 4 + 0] = v.x;
    t[r][q * 16 + i * 4 + 1] = v.y;
    t[r][q * 16 + i * 4 + 2] = v.z;
    t[r][q * 16 + i * 4 + 3] = v.w;
  }
  __syncthreads();
  unsigned short* dp = dst + ((size_t)b * cols + n0 + r) * drow + c0 + q * 16;
  ushort8v o0, o1;
#pragma unroll
  for (int i = 0; i < 8; ++i) o0[i] = f2bf(t[q * 16 + i][r]);
#pragma unroll
  for (int i = 0; i < 8; ++i) o1[i] = f2bf(t[q * 16 + 8 + i][r]);
  *(ushort8v*)dp = o0;
  *(ushort8v*)(dp + 8) = o1;
}

__global__ __launch_bounds__(256) void prep_kernel(const float* __restrict__ points1,
                                                   const float* __restrict__ points2,
                                                   const float* __restrict__ w0,
                                                   const float* __restrict__ w1,
                                                   unsigned short* __restrict__ Xb,
                                                   unsigned short* __restrict__ p2t,
                                                   unsigned short* __restrict__ w0b,
                                                   unsigned short* __restrict__ w1b) {
  __shared__ float t[64][65];
  int id = blockIdx.x;
  if (id < 4096) {  // points1 -> Xb[.][0:256], drow 512
    tconv_body(points1, Xb, N, 512, id & 127, (id >> 7) & 3, id >> 9, t);
  } else if (id < 5120) {  // points2 -> p2t, drow 256
    id -= 4096;
    tconv_body(points2, p2t, S, 256, id & 31, (id >> 5) & 3, id >> 7, t);
  } else {  // weights
    int i = (id - 5120) * 256 + threadIdx.x;
    if (i < C * CIN) w0b[i] = f2bf(w0[i]);
    else {
      int j = i - C * CIN;
      if (j < C * C) w1b[j] = f2bf(w1[j]);
    }
  }
}

// ---------------- bf16 MFMA GEMM + channel-major partial stats (no atomics) ----------------
__global__ __launch_bounds__(256) void gemm_kernel(const unsigned short* __restrict__ X,
                                                   const unsigned short* __restrict__ Wb,
                                                   const float* __restrict__ bias,
                                                   unsigned short* __restrict__ Y,
                                                   float* __restrict__ psum,
                                                   float* __restrict__ psumsq,
                                                   int Cin) {
  __shared__ unsigned short As[128 * 32];  // [o_row][k] 8KB, swizzled
  __shared__ unsigned short Bs[128 * 32];  // [n_row][k] 8KB, swizzled
  int n0 = blockIdx.x * 128, o0 = blockIdx.y * 128, b = blockIdx.z;
  int tid = threadIdx.x, lane = tid & 63, wid = tid >> 6;
  int wm = wid >> 1, wn = wid & 1;
  floatx4 acc[4][4];
#pragma unroll
  for (int m = 0; m < 4; ++m)
#pragma unroll
    for (int nt = 0; nt < 4; ++nt) acc[m][nt] = (floatx4)(0.0f);

  size_t rsA = (size_t)Cin * 2;  // row stride bytes
  int chunkSwz = ((lane & 3) ^ ((lane >> 3) & 3)) * 16;
  const char* Abase = (const char*)Wb + (size_t)(o0 + wid * 32 + (lane >> 2)) * rsA + chunkSwz;
  const char* Bbase = (const char*)X + ((size_t)b * N + n0 + wid * 32 + (lane >> 2)) * rsA + chunkSwz;
  size_t rstep16 = 16 * rsA;
  int kq = (((lane >> 4) ^ ((lane >> 1) & 3))) * 8;

  for (int k0 = 0; k0 < Cin; k0 += 32) {
    load_lds16(Abase + (size_t)k0 * 2, &As[(wid * 32) * 32]);
    load_lds16(Abase + (size_t)k0 * 2 + rstep16, &As[(wid * 32 + 16) * 32]);
    load_lds16(Bbase + (size_t)k0 * 2, &Bs[(wid * 32) * 32]);
    load_lds16(Bbase + (size_t)k0 * 2 + rstep16, &Bs[(wid * 32 + 16) * 32]);
    __syncthreads();
    bf16x8 af[4], bfv[4];
#pragma unroll
    for (int m = 0; m < 4; ++m)
      af[m] = *(const bf16x8*)&As[(wm * 64 + m * 16 + (lane & 15)) * 32 + kq];
#pragma unroll
    for (int nt = 0; nt < 4; ++nt)
      bfv[nt] = *(const bf16x8*)&Bs[(wn * 64 + nt * 16 + (lane & 15)) * 32 + kq];
#pragma unroll
    for (int m = 0; m < 4; ++m)
#pragma unroll
      for (int nt = 0; nt < 4; ++nt)
        acc[m][nt] = __builtin_amdgcn_mfma_f32_16x16x32_bf16(af[m], bfv[nt], acc[m][nt], 0, 0, 0);
    __syncthreads();
  }

  int col = lane & 15, rowq = lane >> 4;
  int slot = ((b * 64 + blockIdx.x) * 2) + wn;
#pragma unroll
  for (int m = 0; m < 4; ++m) {
    int ob = o0 + wm * 64 + m * 16 + rowq * 4;
    float4 bs = *(const float4*)&bias[ob];
    float sj[4] = {0.f, 0.f, 0.f, 0.f}, qj[4] = {0.f, 0.f, 0.f, 0.f};
#pragma unroll
    for (int nt = 0; nt < 4; ++nt) {
      int n = n0 + wn * 64 + nt * 16 + col;
      float y0 = acc[m][nt][0] + bs.x;
      float y1 = acc[m][nt][1] + bs.y;
      float y2 = acc[m][nt][2] + bs.z;
      float y3 = acc[m][nt][3] + bs.w;
      ushort4v v;
      v[0] = f2bf(y0); v[1] = f2bf(y1); v[2] = f2bf(y2); v[3] = f2bf(y3);
      *(ushort4v*)&Y[((size_t)b * N + n) * 256 + ob] = v;
      sj[0] += y0; qj[0] = fmaf(y0, y0, qj[0]);
      sj[1] += y1; qj[1] = fmaf(y1, y1, qj[1]);
      sj[2] += y2; qj[2] = fmaf(y2, y2, qj[2]);
      sj[3] += y3; qj[3] = fmaf(y3, y3, qj[3]);
    }
#pragma unroll
    for (int j = 0; j < 4; ++j) {
#pragma unroll
      for (int d = 1; d <= 8; d <<= 1) {
        sj[j] += __shfl_xor(sj[j], d);
        qj[j] += __shfl_xor(qj[j], d);
      }
    }
    if (col == 0) {
      int c0 = blockIdx.y * 128 + wm * 64 + m * 16 + rowq * 4;
#pragma unroll
      for (int j = 0; j < 4; ++j) {
        psum[(size_t)(c0 + j) * NSLOT + slot] = sj[j];
        psumsq[(size_t)(c0 + j) * NSLOT + slot] = qj[j];
      }
    }
  }
}

// ---------------- parallel reduce partials -> BN scale/shift (256 blocks) ----------------
__global__ __launch_bounds__(256) void bnparam_kernel(const float* __restrict__ psum,
                                                      const float* __restrict__ psumsq,
                                                      const float* __restrict__ gamma,
                                                      const float* __restrict__ beta,
                                                      float* __restrict__ scale,
                                                      float* __restrict__ shift) {
  int c = blockIdx.x, tid = threadIdx.x;
  const float* ps = psum + (size_t)c * NSLOT;
  const float* pq = psumsq + (size_t)c * NSLOT;
  float s = 0.f, q = 0.f;
#pragma unroll
  for (int i = 0; i < NSLOT / 256; ++i) {
    s += ps[tid + i * 256];
    q += pq[tid + i * 256];
  }
#pragma unroll
  for (int d = 1; d <= 32; d <<= 1) {
    s += __shfl_xor(s, d);
    q += __shfl_xor(q, d);
  }
  __shared__ float ls[4], lq[4];
  int wid = tid >> 6;
  if ((tid & 63) == 0) { ls[wid] = s; lq[wid] = q; }
  __syncthreads();
  if (tid == 0) {
    s = ls[0] + ls[1] + ls[2] + ls[3];
    q = lq[0] + lq[1] + lq[2] + lq[3];
    float m = s * (1.0f / CNT);
    float v = q * (1.0f / CNT) - m * m;
    float sc = gamma[c] * rsqrtf(v + 1e-5f);
    scale[c] = sc;
    shift[c] = beta[c] - m * sc;
  }
}

// ---------------- BN+ReLU elementwise on [b][n][256] bf16 -> bf16 ----------------
__global__ __launch_bounds__(256) void bnrelu_kernel(const unsigned short* __restrict__ Y,
                                                     const float* __restrict__ scale,
                                                     const float* __restrict__ shift,
                                                     unsigned short* __restrict__ H) {
  size_t total = (size_t)B * N * 256 / 8;
  for (size_t i = (size_t)blockIdx.x * 256 + threadIdx.x; i < total;
       i += (size_t)gridDim.x * 256) {
    int ob = ((int)i & 31) * 8;
    float4 s0 = *(const float4*)&scale[ob];
    float4 s1 = *(const float4*)&scale[ob + 4];
    float4 h0 = *(const float4*)&shift[ob];
    float4 h1 = *(const float4*)&shift[ob + 4];
    ushort8v v = *(const ushort8v*)&Y[i * 8];
    ushort8v o;
    o[0] = f2bf(fmaxf(fmaf(bf2f(v[0]), s0.x, h0.x), 0.f));
    o[1] = f2bf(fmaxf(fmaf(bf2f(v[1]), s0.y, h0.y), 0.f));
    o[2] = f2bf(fmaxf(fmaf(bf2f(v[2]), s0.z, h0.z), 0.f));
    o[3] = f2bf(fmaxf(fmaf(bf2f(v[3]), s0.w, h0.w), 0.f));
    o[4] = f2bf(fmaxf(fmaf(bf2f(v[4]), s1.x, h1.x), 0.f));
    o[5] = f2bf(fmaxf(fmaf(bf2f(v[5]), s1.y, h1.y), 0.f));
    o[6] = f2bf(fmaxf(fmaf(bf2f(v[6]), s1.z, h1.z), 0.f));
    o[7] = f2bf(fmaxf(fmaf(bf2f(v[7]), s1.w, h1.w), 0.f));
    *(ushort8v*)&H[i * 8] = o;
  }
}

// ---------------- final: BN+ReLU + transpose [b][n][o] bf16 -> out [b][o][n] f32 ----------------
__global__ __launch_bounds__(256) void bnreluT_kernel(const unsigned short* __restrict__ Y,
                                                      const float* __restrict__ scale,
                                                      const float* __restrict__ shift,
                                                      float* __restrict__ out) {
  __shared__ float t[64][65];
  int n0 = blockIdx.x * 64, o0 = blockIdx.y * 64, b = blockIdx.z;
  int tid = threadIdx.x, r = tid >> 2, q = tid & 3;
  const unsigned short* yp = Y + ((size_t)b * N + n0 + r) * 256 + o0 + q * 16;
#pragma unroll
  for (int h = 0; h < 2; ++h) {
    ushort8v v = *(const ushort8v*)(yp + h * 8);
#pragma unroll
    for (int i = 0; i < 8; ++i) {
      int oc = q * 16 + h * 8 + i;
      float f = fmaxf(fmaf(bf2f(v[i]), scale[o0 + oc], shift[o0 + oc]), 0.f);
      t[oc][r] = f;
    }
  }
  __syncthreads();
  float* op = out + ((size_t)b * 256 + o0 + r) * N + n0 + q * 16;
#pragma unroll
  for (int i = 0; i < 4; ++i) {
    float4 v = make_float4(t[r][q * 16 + i * 4 + 0], t[r][q * 16 + i * 4 + 1],
                           t[r][q * 16 + i * 4 + 2], t[r][q * 16 + i * 4 + 3]);
    *(float4*)(op + i * 4) = v;
  }
}

extern "C" void kernel_launch(void* const* d_in, const int* in_sizes, int n_in,
                              void* d_out, int out_size, void* d_ws, size_t ws_size,
                              hipStream_t stream) {
  const float* xyz1 = (const float*)d_in[0];
  const float* xyz2 = (const float*)d_in[1];
  const float* points1 = (const float*)d_in[2];
  const float* points2 = (const float*)d_in[3];
  const float* w0 = (const float*)d_in[4];
  const float* b0 = (const float*)d_in[5];
  const float* g0 = (const float*)d_in[6];
  const float* be0 = (const float*)d_in[7];
  const float* w1 = (const float*)d_in[8];
  const float* b1 = (const float*)d_in[9];
  const float* g1 = (const float*)d_in[10];
  const float* be1 = (const float*)d_in[11];
  float* out = (float*)d_out;

  char* ws = (char*)d_ws;
  float* scale0 = (float*)ws;          ws += 256 * 4;
  float* shift0 = (float*)ws;          ws += 256 * 4;
  float* scale1 = (float*)ws;          ws += 256 * 4;
  float* shift1 = (float*)ws;          ws += 256 * 4;
  float* psum = (float*)ws;            ws += (size_t)C * NSLOT * 4;    // 1MB
  float* psumsq = (float*)ws;          ws += (size_t)C * NSLOT * 4;    // 1MB
  unsigned short* w0b = (unsigned short*)ws;  ws += (size_t)C * CIN * 2;   // 256KB
  unsigned short* w1b = (unsigned short*)ws;  ws += (size_t)C * C * 2;     // 128KB
  unsigned short* p2t = (unsigned short*)ws;  ws += (size_t)B * S * 256 * 2;   // 8MB
  unsigned short* Xb = (unsigned short*)ws;   ws += (size_t)B * N * 512 * 2;   // 64MB
  unsigned short* Yb = (unsigned short*)ws;   ws += (size_t)B * N * 256 * 2;   // 32MB
  unsigned short* Hb = Xb;  // reuse Xb after GEMM0 consumed it

  prep_kernel<<<dim3(4096 + 1024 + 768), 256, 0, stream>>>(points1, points2, w0, w1,
                                                           Xb, p2t, w0b, w1b);
  nn3_kernel<<<dim3(B * N / 32), 256, 0, stream>>>(xyz1, xyz2, p2t, Xb);
  gemm_kernel<<<dim3(N / 128, 2, B), 256, 0, stream>>>(Xb, w0b, b0, Yb, psum, psumsq, CIN);
  bnparam_kernel<<<dim3(C), 256, 0, stream>>>(psum, psumsq, g0, be0, scale0, shift0);
  bnrelu_kernel<<<dim3(2048), 256, 0, stream>>>(Yb, scale0, shift0, Hb);
  gemm_kernel<<<dim3(N / 128, 2, B), 256, 0, stream>>>(Hb, w1b, b1, Yb, psum, psumsq, C);
  bnparam_kernel<<<dim3(C), 256, 0, stream>>>(psum, psumsq, g1, be1, scale1, shift1);
  bnreluT_kernel<<<dim3(N / 64, 4, B), 256, 0, stream>>>(Yb, scale1, shift1, out);
}

// Round 14
// 208.170 us; speedup vs baseline: 3.7244x; 1.0193x over previous
//
#include <hip/hip_runtime.h>
#include <math.h>

#define B 8
#define N 8192
#define S 2048
#define SCH 1024  // points per LDS chunk
#define C 256
#define CIN 512
#define CNT (B * N)  // 65536
#define NSLOT 1024   // (b*64 + bx)*2 + wn

typedef unsigned long long ull;
typedef __attribute__((ext_vector_type(8))) short bf16x8;
typedef __attribute__((ext_vector_type(4))) float floatx4;
typedef __attribute__((ext_vector_type(8))) unsigned short ushort8v;
typedef __attribute__((ext_vector_type(4))) unsigned short ushort4v;

__device__ inline unsigned short f2bf(float f) {
  unsigned u = __builtin_bit_cast(unsigned, f);
  u += 0x7FFF + ((u >> 16) & 1);  // RNE
  return (unsigned short)(u >> 16);
}
__device__ inline float bf2f(unsigned short h) {
  unsigned u = ((unsigned)h) << 16;
  return __builtin_bit_cast(float, u);
}

__device__ inline void load_lds16(const void* g, void* l) {
  __builtin_amdgcn_global_load_lds(
      (const __attribute__((address_space(1))) unsigned int*)g,
      (__attribute__((address_space(3))) unsigned int*)l, 16, 0, 0);
}

// ---------------- 3-NN v13: scan/merge + fused gather tail (unchanged) ----------------
__device__ inline void ins3u(ull k, ull& k0, ull& k1, ull& k2) {
  if (k < k2) {
    if (k < k1) {
      k2 = k1;
      if (k < k0) { k1 = k0; k0 = k; } else k1 = k;
    } else k2 = k;
  }
}

__device__ inline unsigned sortkey(float f) {
  unsigned u = __float_as_uint(f);
  return u ^ (((unsigned)((int)u >> 31)) | 0x80000000u);
}
__device__ inline float unsortkey(unsigned u) {
  unsigned m = ((int)u < 0) ? 0x80000000u : 0xFFFFFFFFu;
  return __uint_as_float(u ^ m);
}

#define QDECL(q)                                                            \
  float d0_##q = INFINITY, d1_##q = INFINITY, d2_##q = INFINITY;            \
  int i0_##q = 0, i1_##q = 0, i2_##q = 0;                                   \
  float qx_##q, qy_##q, qz_##q, q2_##q;

#define QLOAD(q)                                                            \
  {                                                                         \
    float ox = p1[nq + q], oy = p1[N + nq + q], oz = p1[2 * N + nq + q];    \
    q2_##q = ox * ox + oy * oy + oz * oz;                                   \
    qx_##q = -2.0f * ox; qy_##q = -2.0f * oy; qz_##q = -2.0f * oz;          \
  }

#define QINS(q)                                                             \
  {                                                                         \
    float d = fmaf(qx_##q, pc.x, fmaf(qy_##q, pc.y, fmaf(qz_##q, pc.z, pc.w))); \
    bool lt0 = d < d0_##q, lt1 = d < d1_##q, lt2 = d < d2_##q;              \
    i2_##q = lt2 ? (lt1 ? i1_##q : s) : i2_##q;                             \
    i1_##q = lt1 ? (lt0 ? i0_##q : s) : i1_##q;                             \
    i0_##q = lt0 ? s : i0_##q;                                              \
    d2_##q = __builtin_amdgcn_fmed3f(d, d1_##q, d2_##q);                    \
    d1_##q = __builtin_amdgcn_fmed3f(d, d0_##q, d1_##q);                    \
    d0_##q = fminf(d, d0_##q);                                              \
  }

#define QSTORE(q)                                                           \
  {                                                                         \
    size_t kb = ((size_t)(grp * 2 + q) * 16 + sub) * 3;                     \
    keys[kb] = ((ull)sortkey(d0_##q) << 32) | (unsigned)i0_##q;             \
    keys[kb + 1] = ((ull)sortkey(d1_##q) << 32) | (unsigned)i1_##q;         \
    keys[kb + 2] = ((ull)sortkey(d2_##q) << 32) | (unsigned)i2_##q;         \
  }

__global__ __launch_bounds__(256, 4) void nn3_kernel(const float* __restrict__ xyz1,
                                                     const float* __restrict__ xyz2,
                                                     const unsigned short* __restrict__ p2t,
                                                     unsigned short* __restrict__ Xb) {
  __shared__ float4 sp[SCH];  // 16KB chunk; reused as u64 key buffer (12KB)
  __shared__ int sidx[32][3];
  __shared__ float swt[32][3];
  int b = blockIdx.x >> 8;            // grid = B * (N/32) = 2048
  int n0 = (blockIdx.x & 255) * 32;
  const float* p2 = xyz2 + (size_t)b * 3 * S;
  int tid = threadIdx.x;
  int sub = tid & 15, grp = tid >> 4;  // 16 grps x 2 queries = 32 queries/block
  const float* p1 = xyz1 + (size_t)b * 3 * N;
  int nq = n0 + grp * 2;
  QDECL(0) QDECL(1)
  QLOAD(0) QLOAD(1)

  for (int ch = 0; ch < 2; ++ch) {
    if (ch) __syncthreads();
    for (int i = tid; i < SCH; i += 256) {
      int g = ch * SCH + i;
      float px = p2[g], py = p2[S + g], pz = p2[2 * S + g];
      sp[i] = make_float4(px, py, pz, px * px + py * py + pz * pz);
    }
    __syncthreads();
    int sbase = ch * SCH;
    const float4* spp = sp + sub;
    float4 pcA = spp[0];
    float4 pcB = spp[16];
    for (int t = 0; t < SCH / 16 - 2; t += 2) {
      float4 pnA = spp[(t + 2) * 16];
      float4 pnB = spp[(t + 3) * 16];
      {
        float4 pc = pcA;
        int s = sbase + t * 16 + sub;
        QINS(0) QINS(1)
      }
      {
        float4 pc = pcB;
        int s = sbase + (t + 1) * 16 + sub;
        QINS(0) QINS(1)
      }
      pcA = pnA;
      pcB = pnB;
    }
    {
      float4 pc = pcA;
      int s = sbase + (SCH / 16 - 2) * 16 + sub;
      QINS(0) QINS(1)
    }
    {
      float4 pc = pcB;
      int s = sbase + (SCH / 16 - 1) * 16 + sub;
      QINS(0) QINS(1)
    }
  }

  // merge via LDS keys (scan state dies here)
  __syncthreads();
  ull* keys = (ull*)sp;  // [32 queries][16 subs][3]
  QSTORE(0) QSTORE(1)
  __syncthreads();
  if (sub < 4) {
#pragma unroll
    for (int q = 0; q < 2; ++q) {
      size_t qb = (size_t)(grp * 2 + q) * 48;
      ull m0 = ~0ull, m1 = ~0ull, m2 = ~0ull;
#pragma unroll
      for (int jj = 0; jj < 4; ++jj) {
        size_t o2 = qb + (size_t)(sub + 4 * jj) * 3;
        ins3u(keys[o2], m0, m1, m2);
        ins3u(keys[o2 + 1], m0, m1, m2);
        ins3u(keys[o2 + 2], m0, m1, m2);
      }
#pragma unroll
      for (int mm = 1; mm <= 2; mm <<= 1) {
        ull e0 = (ull)__shfl_xor((long long)m0, mm);
        ull e1 = (ull)__shfl_xor((long long)m1, mm);
        ull e2 = (ull)__shfl_xor((long long)m2, mm);
        ins3u(e0, m0, m1, m2);
        ins3u(e1, m0, m1, m2);
        ins3u(e2, m0, m1, m2);
      }
      if (sub == 0) {
        float q2v = q ? q2_1 : q2_0;
        int qi = grp * 2 + q;
        float e0 = fmaxf(unsortkey((unsigned)(m0 >> 32)) + q2v, 0.0f);
        float e1 = fmaxf(unsortkey((unsigned)(m1 >> 32)) + q2v, 0.0f);
        float e2 = fmaxf(unsortkey((unsigned)(m2 >> 32)) + q2v, 0.0f);
        float r0 = 1.0f / (e0 + 1e-8f);
        float r1 = 1.0f / (e1 + 1e-8f);
        float r2 = 1.0f / (e2 + 1e-8f);
        float rs = 1.0f / (r0 + r1 + r2);
        sidx[qi][0] = (int)(unsigned)m0;
        sidx[qi][1] = (int)(unsigned)m1;
        sidx[qi][2] = (int)(unsigned)m2;
        swt[qi][0] = r0 * rs;
        swt[qi][1] = r1 * rs;
        swt[qi][2] = r2 * rs;
      }
    }
  }
  __syncthreads();

  // fused gather tail: 8 threads per query, 4 x 16B chunks each
  int qi = tid >> 3, cc = tid & 7;
  int j0 = sidx[qi][0], j1 = sidx[qi][1], j2 = sidx[qi][2];
  float w0v = swt[qi][0], w1v = swt[qi][1], w2v = swt[qi][2];
  const unsigned short* pb = p2t + (size_t)b * S * 256;
  const unsigned short* r0p = pb + (size_t)j0 * 256;
  const unsigned short* r1p = pb + (size_t)j1 * 256;
  const unsigned short* r2p = pb + (size_t)j2 * 256;
  unsigned short* xp = Xb + ((size_t)b * N + n0 + qi) * 512 + 256;
#pragma unroll
  for (int h = 0; h < 4; ++h) {
    int co = (cc + h * 8) * 8;
    ushort8v v0 = *(const ushort8v*)(r0p + co);
    ushort8v v1 = *(const ushort8v*)(r1p + co);
    ushort8v v2 = *(const ushort8v*)(r2p + co);
    ushort8v o;
#pragma unroll
    for (int i = 0; i < 8; ++i)
      o[i] = f2bf(w0v * bf2f(v0[i]) + w1v * bf2f(v1[i]) + w2v * bf2f(v2[i]));
    *(ushort8v*)(xp + co) = o;
  }
}

// ---------------- fused prep: tconv(points1), tconv(points2), weight convert ----------------
__device__ inline void tconv_body(const float* __restrict__ src,
                                  unsigned short* __restrict__ dst,
                                  int cols, int drow, int bx, int by, int bz,
                                  float (*t)[65]) {
  int n0 = bx * 64, c0 = by * 64, b = bz;
  int tid = threadIdx.x, r = tid >> 2, q = tid & 3;
  const float* sp = src + ((size_t)b * 256 + c0 + r) * cols + n0 + q * 16;
#pragma unroll
  for (int i = 0; i < 4; ++i) {
    float4 v = *(const float4*)(sp + i * 4);
    t[r][q * 16 + i * 4 + 0] = v.x;
    t[r][q * 16 + i * 4 + 1] = v.y;
    t[r][q * 16 + i * 4 + 2] = v.z;
    t[r][q * 16 + i * 4 + 3] = v.w;
  }
  __syncthreads();
  unsigned short* dp = dst + ((size_t)b * cols + n0 + r) * drow + c0 + q * 16;
  ushort8v o0, o1;
#pragma unroll
  for (int i = 0; i < 8; ++i) o0[i] = f2bf(t[q * 16 + i][r]);
#pragma unroll
  for (int i = 0; i < 8; ++i) o1[i] = f2bf(t[q * 16 + 8 + i][r]);
  *(ushort8v*)dp = o0;
  *(ushort8v*)(dp + 8) = o1;
}

__global__ __launch_bounds__(256) void prep_kernel(const float* __restrict__ points1,
                                                   const float* __restrict__ points2,
                                                   const float* __restrict__ w0,
                                                   const float* __restrict__ w1,
                                                   unsigned short* __restrict__ Xb,
                                                   unsigned short* __restrict__ p2t,
                                                   unsigned short* __restrict__ w0b,
                                                   unsigned short* __restrict__ w1b) {
  __shared__ float t[64][65];
  int id = blockIdx.x;
  if (id < 4096) {  // points1 -> Xb[.][0:256], drow 512
    tconv_body(points1, Xb, N, 512, id & 127, (id >> 7) & 3, id >> 9, t);
  } else if (id < 5120) {  // points2 -> p2t, drow 256
    id -= 4096;
    tconv_body(points2, p2t, S, 256, id & 31, (id >> 5) & 3, id >> 7, t);
  } else {  // weights
    int i = (id - 5120) * 256 + threadIdx.x;
    if (i < C * CIN) w0b[i] = f2bf(w0[i]);
    else {
      int j = i - C * CIN;
      if (j < C * C) w1b[j] = f2bf(w1[j]);
    }
  }
}

// ---------------- bf16 MFMA GEMM, BK=64 + channel-major partial stats ----------------
// BK 32->64 halves the per-K-step vmcnt(0)+barrier drains (the §5 ~20% stall)
// amortized over only 16/8 steps at K=512/256. LDS rows are 128B; swizzle:
// stage source chunk (lane&7)^((lane>>3)&7), read chunk ((lane>>4)+kk*4)^(lane&7)
// -> LDS[r][c]=global[r][c^(r&7)] both sides, reads 2-way on banks (free).
__global__ __launch_bounds__(256) void gemm_kernel(const unsigned short* __restrict__ X,
                                                   const unsigned short* __restrict__ Wb,
                                                   const float* __restrict__ bias,
                                                   unsigned short* __restrict__ Y,
                                                   float* __restrict__ psum,
                                                   float* __restrict__ psumsq,
                                                   int Cin) {
  __shared__ unsigned short As[128 * 64];  // [o_row][k] 16KB, swizzled
  __shared__ unsigned short Bs[128 * 64];  // [n_row][k] 16KB, swizzled
  int n0 = blockIdx.x * 128, o0 = blockIdx.y * 128, b = blockIdx.z;
  int tid = threadIdx.x, lane = tid & 63, wid = tid >> 6;
  int wm = wid >> 1, wn = wid & 1;
  floatx4 acc[4][4];
#pragma unroll
  for (int m = 0; m < 4; ++m)
#pragma unroll
    for (int nt = 0; nt < 4; ++nt) acc[m][nt] = (floatx4)(0.0f);

  size_t rsA = (size_t)Cin * 2;  // row stride bytes
  int chunkSwz = ((lane & 7) ^ ((lane >> 3) & 7)) * 16;
  const char* Abase = (const char*)Wb + (size_t)(o0 + wid * 32 + (lane >> 3)) * rsA + chunkSwz;
  const char* Bbase = (const char*)X + ((size_t)b * N + n0 + wid * 32 + (lane >> 3)) * rsA + chunkSwz;
  size_t rstep8 = 8 * rsA;
  int fr = lane & 15;
  int cbase = lane >> 4;   // 0..3
  int rswz = lane & 7;     // row&7 for this lane's fragment reads

  for (int k0 = 0; k0 < Cin; k0 += 64) {
#pragma unroll
    for (int l = 0; l < 4; ++l) {
      load_lds16(Abase + (size_t)k0 * 2 + (size_t)l * rstep8, &As[(wid * 32 + l * 8) * 64]);
      load_lds16(Bbase + (size_t)k0 * 2 + (size_t)l * rstep8, &Bs[(wid * 32 + l * 8) * 64]);
    }
    __syncthreads();
#pragma unroll
    for (int kk = 0; kk < 2; ++kk) {
      int chunk = (cbase + kk * 4) ^ rswz;
      bf16x8 af[4], bfv[4];
#pragma unroll
      for (int m = 0; m < 4; ++m)
        af[m] = *(const bf16x8*)&As[(wm * 64 + m * 16 + fr) * 64 + chunk * 8];
#pragma unroll
      for (int nt = 0; nt < 4; ++nt)
        bfv[nt] = *(const bf16x8*)&Bs[(wn * 64 + nt * 16 + fr) * 64 + chunk * 8];
#pragma unroll
      for (int m = 0; m < 4; ++m)
#pragma unroll
        for (int nt = 0; nt < 4; ++nt)
          acc[m][nt] = __builtin_amdgcn_mfma_f32_16x16x32_bf16(af[m], bfv[nt], acc[m][nt], 0, 0, 0);
    }
    __syncthreads();
  }

  int col = lane & 15, rowq = lane >> 4;
  int slot = ((b * 64 + blockIdx.x) * 2) + wn;
#pragma unroll
  for (int m = 0; m < 4; ++m) {
    int ob = o0 + wm * 64 + m * 16 + rowq * 4;
    float4 bs = *(const float4*)&bias[ob];
    float sj[4] = {0.f, 0.f, 0.f, 0.f}, qj[4] = {0.f, 0.f, 0.f, 0.f};
#pragma unroll
    for (int nt = 0; nt < 4; ++nt) {
      int n = n0 + wn * 64 + nt * 16 + col;
      float y0 = acc[m][nt][0] + bs.x;
      float y1 = acc[m][nt][1] + bs.y;
      float y2 = acc[m][nt][2] + bs.z;
      float y3 = acc[m][nt][3] + bs.w;
      ushort4v v;
      v[0] = f2bf(y0); v[1] = f2bf(y1); v[2] = f2bf(y2); v[3] = f2bf(y3);
      *(ushort4v*)&Y[((size_t)b * N + n) * 256 + ob] = v;
      sj[0] += y0; qj[0] = fmaf(y0, y0, qj[0]);
      sj[1] += y1; qj[1] = fmaf(y1, y1, qj[1]);
      sj[2] += y2; qj[2] = fmaf(y2, y2, qj[2]);
      sj[3] += y3; qj[3] = fmaf(y3, y3, qj[3]);
    }
#pragma unroll
    for (int j = 0; j < 4; ++j) {
#pragma unroll
      for (int d = 1; d <= 8; d <<= 1) {
        sj[j] += __shfl_xor(sj[j], d);
        qj[j] += __shfl_xor(qj[j], d);
      }
    }
    if (col == 0) {
      int c0 = blockIdx.y * 128 + wm * 64 + m * 16 + rowq * 4;
#pragma unroll
      for (int j = 0; j < 4; ++j) {
        psum[(size_t)(c0 + j) * NSLOT + slot] = sj[j];
        psumsq[(size_t)(c0 + j) * NSLOT + slot] = qj[j];
      }
    }
  }
}

// ---------------- parallel reduce partials -> BN scale/shift (256 blocks) ----------------
__global__ __launch_bounds__(256) void bnparam_kernel(const float* __restrict__ psum,
                                                      const float* __restrict__ psumsq,
                                                      const float* __restrict__ gamma,
                                                      const float* __restrict__ beta,
                                                      float* __restrict__ scale,
                                                      float* __restrict__ shift) {
  int c = blockIdx.x, tid = threadIdx.x;
  const float* ps = psum + (size_t)c * NSLOT;
  const float* pq = psumsq + (size_t)c * NSLOT;
  float s = 0.f, q = 0.f;
#pragma unroll
  for (int i = 0; i < NSLOT / 256; ++i) {
    s += ps[tid + i * 256];
    q += pq[tid + i * 256];
  }
#pragma unroll
  for (int d = 1; d <= 32; d <<= 1) {
    s += __shfl_xor(s, d);
    q += __shfl_xor(q, d);
  }
  __shared__ float ls[4], lq[4];
  int wid = tid >> 6;
  if ((tid & 63) == 0) { ls[wid] = s; lq[wid] = q; }
  __syncthreads();
  if (tid == 0) {
    s = ls[0] + ls[1] + ls[2] + ls[3];
    q = lq[0] + lq[1] + lq[2] + lq[3];
    float m = s * (1.0f / CNT);
    float v = q * (1.0f / CNT) - m * m;
    float sc = gamma[c] * rsqrtf(v + 1e-5f);
    scale[c] = sc;
    shift[c] = beta[c] - m * sc;
  }
}

// ---------------- BN+ReLU elementwise on [b][n][256] bf16 -> bf16 ----------------
__global__ __launch_bounds__(256) void bnrelu_kernel(const unsigned short* __restrict__ Y,
                                                     const float* __restrict__ scale,
                                                     const float* __restrict__ shift,
                                                     unsigned short* __restrict__ H) {
  size_t total = (size_t)B * N * 256 / 8;
  for (size_t i = (size_t)blockIdx.x * 256 + threadIdx.x; i < total;
       i += (size_t)gridDim.x * 256) {
    int ob = ((int)i & 31) * 8;
    float4 s0 = *(const float4*)&scale[ob];
    float4 s1 = *(const float4*)&scale[ob + 4];
    float4 h0 = *(const float4*)&shift[ob];
    float4 h1 = *(const float4*)&shift[ob + 4];
    ushort8v v = *(const ushort8v*)&Y[i * 8];
    ushort8v o;
    o[0] = f2bf(fmaxf(fmaf(bf2f(v[0]), s0.x, h0.x), 0.f));
    o[1] = f2bf(fmaxf(fmaf(bf2f(v[1]), s0.y, h0.y), 0.f));
    o[2] = f2bf(fmaxf(fmaf(bf2f(v[2]), s0.z, h0.z), 0.f));
    o[3] = f2bf(fmaxf(fmaf(bf2f(v[3]), s0.w, h0.w), 0.f));
    o[4] = f2bf(fmaxf(fmaf(bf2f(v[4]), s1.x, h1.x), 0.f));
    o[5] = f2bf(fmaxf(fmaf(bf2f(v[5]), s1.y, h1.y), 0.f));
    o[6] = f2bf(fmaxf(fmaf(bf2f(v[6]), s1.z, h1.z), 0.f));
    o[7] = f2bf(fmaxf(fmaf(bf2f(v[7]), s1.w, h1.w), 0.f));
    *(ushort8v*)&H[i * 8] = o;
  }
}

// ---------------- final: BN+ReLU + transpose [b][n][o] bf16 -> out [b][o][n] f32 ----------------
__global__ __launch_bounds__(256) void bnreluT_kernel(const unsigned short* __restrict__ Y,
                                                      const float* __restrict__ scale,
                                                      const float* __restrict__ shift,
                                                      float* __restrict__ out) {
  __shared__ float t[64][65];
  int n0 = blockIdx.x * 64, o0 = blockIdx.y * 64, b = blockIdx.z;
  int tid = threadIdx.x, r = tid >> 2, q = tid & 3;
  const unsigned short* yp = Y + ((size_t)b * N + n0 + r) * 256 + o0 + q * 16;
#pragma unroll
  for (int h = 0; h < 2; ++h) {
    ushort8v v = *(const ushort8v*)(yp + h * 8);
#pragma unroll
    for (int i = 0; i < 8; ++i) {
      int oc = q * 16 + h * 8 + i;
      float f = fmaxf(fmaf(bf2f(v[i]), scale[o0 + oc], shift[o0 + oc]), 0.f);
      t[oc][r] = f;
    }
  }
  __syncthreads();
  float* op = out + ((size_t)b * 256 + o0 + r) * N + n0 + q * 16;
#pragma unroll
  for (int i = 0; i < 4; ++i) {
    float4 v = make_float4(t[r][q * 16 + i * 4 + 0], t[r][q * 16 + i * 4 + 1],
                           t[r][q * 16 + i * 4 + 2], t[r][q * 16 + i * 4 + 3]);
    *(float4*)(op + i * 4) = v;
  }
}

extern "C" void kernel_launch(void* const* d_in, const int* in_sizes, int n_in,
                              void* d_out, int out_size, void* d_ws, size_t ws_size,
                              hipStream_t stream) {
  const float* xyz1 = (const float*)d_in[0];
  const float* xyz2 = (const float*)d_in[1];
  const float* points1 = (const float*)d_in[2];
  const float* points2 = (const float*)d_in[3];
  const float* w0 = (const float*)d_in[4];
  const float* b0 = (const float*)d_in[5];
  const float* g0 = (const float*)d_in[6];
  const float* be0 = (const float*)d_in[7];
  const float* w1 = (const float*)d_in[8];
  const float* b1 = (const float*)d_in[9];
  const float* g1 = (const float*)d_in[10];
  const float* be1 = (const float*)d_in[11];
  float* out = (float*)d_out;

  char* ws = (char*)d_ws;
  float* scale0 = (float*)ws;          ws += 256 * 4;
  float* shift0 = (float*)ws;          ws += 256 * 4;
  float* scale1 = (float*)ws;          ws += 256 * 4;
  float* shift1 = (float*)ws;          ws += 256 * 4;
  float* psum = (float*)ws;            ws += (size_t)C * NSLOT * 4;    // 1MB
  float* psumsq = (float*)ws;          ws += (size_t)C * NSLOT * 4;    // 1MB
  unsigned short* w0b = (unsigned short*)ws;  ws += (size_t)C * CIN * 2;   // 256KB
  unsigned short* w1b = (unsigned short*)ws;  ws += (size_t)C * C * 2;     // 128KB
  unsigned short* p2t = (unsigned short*)ws;  ws += (size_t)B * S * 256 * 2;   // 8MB
  unsigned short* Xb = (unsigned short*)ws;   ws += (size_t)B * N * 512 * 2;   // 64MB
  unsigned short* Yb = (unsigned short*)ws;   ws += (size_t)B * N * 256 * 2;   // 32MB
  unsigned short* Hb = Xb;  // reuse Xb after GEMM0 consumed it

  prep_kernel<<<dim3(4096 + 1024 + 768), 256, 0, stream>>>(points1, points2, w0, w1,
                                                           Xb, p2t, w0b, w1b);
  nn3_kernel<<<dim3(B * N / 32), 256, 0, stream>>>(xyz1, xyz2, p2t, Xb);
  gemm_kernel<<<dim3(N / 128, 2, B), 256, 0, stream>>>(Xb, w0b, b0, Yb, psum, psumsq, CIN);
  bnparam_kernel<<<dim3(C), 256, 0, stream>>>(psum, psumsq, g0, be0, scale0, shift0);
  bnrelu_kernel<<<dim3(2048), 256, 0, stream>>>(Yb, scale0, shift0, Hb);
  gemm_kernel<<<dim3(N / 128, 2, B), 256, 0, stream>>>(Hb, w1b, b1, Yb, psum, psumsq, C);
  bnparam_kernel<<<dim3(C), 256, 0, stream>>>(psum, psumsq, g1, be1, scale1, shift1);
  bnreluT_kernel<<<dim3(N / 64, 4, B), 256, 0, stream>>>(Yb, scale1, shift1, out);
}

// Round 15
// 193.581 us; speedup vs baseline: 4.0051x; 1.0754x over previous
//
#include <hip/hip_runtime.h>
#include <math.h>

#define B 8
#define N 8192
#define S 2048
#define SCH 1024  // points per LDS chunk
#define C 256
#define CIN 512
#define CNT (B * N)  // 65536
#define NSLOT 1024   // (b*64 + bx)*2 + wn

typedef unsigned long long ull;
typedef __attribute__((ext_vector_type(8))) short bf16x8;
typedef __attribute__((ext_vector_type(4))) float floatx4;
typedef __attribute__((ext_vector_type(8))) unsigned short ushort8v;
typedef __attribute__((ext_vector_type(4))) unsigned short ushort4v;

__device__ inline unsigned short f2bf(float f) {
  unsigned u = __builtin_bit_cast(unsigned, f);
  u += 0x7FFF + ((u >> 16) & 1);  // RNE
  return (unsigned short)(u >> 16);
}
__device__ inline float bf2f(unsigned short h) {
  unsigned u = ((unsigned)h) << 16;
  return __builtin_bit_cast(float, u);
}

__device__ inline void load_lds16(const void* g, void* l) {
  __builtin_amdgcn_global_load_lds(
      (const __attribute__((address_space(1))) unsigned int*)g,
      (__attribute__((address_space(3))) unsigned int*)l, 16, 0, 0);
}

// ---------------- 3-NN v15: two-phase (d-only scan + threshold recovery) ----------------
// Phase 1: d-only top-3 (6 VALU/pair, no index cndmask chains). Phase 2:
// rescan with per-query 3rd-best threshold (4 VALU/pair); matches (expected
// exactly 3) pushed to an LDS candidate list. Selection sorts candidates by
// exact (sortkey(d), s) u64 — d is recomputed bit-identically, so this equals
// top_k's value-then-index order, ties included.
__device__ inline void ins3u(ull k, ull& k0, ull& k1, ull& k2) {
  if (k < k2) {
    if (k < k1) {
      k2 = k1;
      if (k < k0) { k1 = k0; k0 = k; } else k1 = k;
    } else k2 = k;
  }
}

// branchless float top-3 insert (r5-verified med3 identity; reads OLD slots)
__device__ inline void insf(float k, float& m0, float& m1, float& m2) {
  float n1 = __builtin_amdgcn_fmed3f(k, m0, m1);
  float n2 = __builtin_amdgcn_fmed3f(k, m1, m2);
  m0 = fminf(k, m0);
  m1 = n1;
  m2 = n2;
}

__device__ inline unsigned sortkey(float f) {
  unsigned u = __float_as_uint(f);
  return u ^ (((unsigned)((int)u >> 31)) | 0x80000000u);
}
__device__ inline float unsortkey(unsigned u) {
  unsigned m = ((int)u < 0) ? 0x80000000u : 0xFFFFFFFFu;
  return __uint_as_float(u ^ m);
}

#define QDECL(q)                                                            \
  float d0_##q = INFINITY, d1_##q = INFINITY, d2_##q = INFINITY;            \
  float qx_##q, qy_##q, qz_##q, q2_##q;

#define QLOAD(q)                                                            \
  {                                                                         \
    float ox = p1[nq + q], oy = p1[N + nq + q], oz = p1[2 * N + nq + q];    \
    q2_##q = ox * ox + oy * oy + oz * oz;                                   \
    qx_##q = -2.0f * ox; qy_##q = -2.0f * oy; qz_##q = -2.0f * oz;          \
  }

// dkey = -2 q.p + |p|^2 (true dist^2 = dkey + q2, re-added at output)
#define QINSD(q)                                                            \
  {                                                                         \
    float d = fmaf(qx_##q, pc.x, fmaf(qy_##q, pc.y, fmaf(qz_##q, pc.z, pc.w))); \
    float n1 = __builtin_amdgcn_fmed3f(d, d0_##q, d1_##q);                  \
    float n2 = __builtin_amdgcn_fmed3f(d, d1_##q, d2_##q);                  \
    d0_##q = fminf(d, d0_##q);                                              \
    d1_##q = n1;                                                            \
    d2_##q = n2;                                                            \
  }

__global__ __launch_bounds__(256, 4) void nn3_kernel(const float* __restrict__ xyz1,
                                                     const float* __restrict__ xyz2,
                                                     const unsigned short* __restrict__ p2t,
                                                     unsigned short* __restrict__ Xb) {
  __shared__ float4 sp[SCH];  // 16KB staging; phase-1 merge array aliases it
  __shared__ float t2q[32];
  __shared__ int ccnt[32];
  __shared__ float cand_d[32][8];
  __shared__ int cand_s[32][8];
  __shared__ int sidx[32][3];
  __shared__ float swt[32][3];
  int b = blockIdx.x >> 8;            // grid = B * (N/32) = 2048
  int n0 = (blockIdx.x & 255) * 32;
  const float* p2 = xyz2 + (size_t)b * 3 * S;
  int tid = threadIdx.x;
  int sub = tid & 15, grp = tid >> 4;  // 16 grps x 2 queries = 32 queries/block
  const float* p1 = xyz1 + (size_t)b * 3 * N;
  int nq = n0 + grp * 2;
  QDECL(0) QDECL(1)
  QLOAD(0) QLOAD(1)

  // ---- phase 1: d-only scan over 2 chunks ----
  for (int ch = 0; ch < 2; ++ch) {
    if (ch) __syncthreads();
    for (int i = tid; i < SCH; i += 256) {
      int g = ch * SCH + i;
      float px = p2[g], py = p2[S + g], pz = p2[2 * S + g];
      sp[i] = make_float4(px, py, pz, px * px + py * py + pz * pz);
    }
    __syncthreads();
    const float4* spp = sp + sub;
    float4 pc = spp[0];
    for (int t = 0; t < SCH / 16 - 1; ++t) {
      float4 pn = spp[(t + 1) * 16];
      QINSD(0) QINSD(1)
      pc = pn;
    }
    QINSD(0) QINSD(1)
  }

  // ---- merge per-sub top-3 distances -> per-query 3rd-best threshold ----
  __syncthreads();                 // phase-1 sp reads done; safe to alias
  float* tm = (float*)sp;          // [32 queries][16 subs][3] floats (6KB)
  tm[((grp * 2 + 0) * 16 + sub) * 3 + 0] = d0_0;
  tm[((grp * 2 + 0) * 16 + sub) * 3 + 1] = d1_0;
  tm[((grp * 2 + 0) * 16 + sub) * 3 + 2] = d2_0;
  tm[((grp * 2 + 1) * 16 + sub) * 3 + 0] = d0_1;
  tm[((grp * 2 + 1) * 16 + sub) * 3 + 1] = d1_1;
  tm[((grp * 2 + 1) * 16 + sub) * 3 + 2] = d2_1;
  if (tid < 32) ccnt[tid] = 0;
  __syncthreads();
  if (sub < 4) {
#pragma unroll
    for (int q = 0; q < 2; ++q) {
      int qi = grp * 2 + q;
      float m0 = INFINITY, m1 = INFINITY, m2 = INFINITY;
#pragma unroll
      for (int jj = 0; jj < 4; ++jj) {
        int ss = sub + 4 * jj;
        insf(tm[(qi * 16 + ss) * 3 + 0], m0, m1, m2);
        insf(tm[(qi * 16 + ss) * 3 + 1], m0, m1, m2);
        insf(tm[(qi * 16 + ss) * 3 + 2], m0, m1, m2);
      }
#pragma unroll
      for (int mm = 1; mm <= 2; mm <<= 1) {
        float e0 = __shfl_xor(m0, mm);
        float e1 = __shfl_xor(m1, mm);
        float e2 = __shfl_xor(m2, mm);
        insf(e0, m0, m1, m2);
        insf(e1, m0, m1, m2);
        insf(e2, m0, m1, m2);
      }
      if (sub == 0) t2q[qi] = m2;
    }
  }
  __syncthreads();
  float t2_0 = t2q[grp * 2], t2_1 = t2q[grp * 2 + 1];

  // ---- phase 2: rescan with threshold, collect candidates ----
  for (int ch = 0; ch < 2; ++ch) {
    if (ch) __syncthreads();
    for (int i = tid; i < SCH; i += 256) {
      int g = ch * SCH + i;
      float px = p2[g], py = p2[S + g], pz = p2[2 * S + g];
      sp[i] = make_float4(px, py, pz, px * px + py * py + pz * pz);
    }
    __syncthreads();
    const float4* spp = sp + sub;
    for (int t = 0; t < SCH / 16; ++t) {
      float4 pc = spp[t * 16];
      int s = ch * SCH + t * 16 + sub;
      {
        float d = fmaf(qx_0, pc.x, fmaf(qy_0, pc.y, fmaf(qz_0, pc.z, pc.w)));
        if (d <= t2_0) {
          int sl = atomicAdd(&ccnt[grp * 2], 1);
          if (sl < 8) { cand_d[grp * 2][sl] = d; cand_s[grp * 2][sl] = s; }
        }
      }
      {
        float d = fmaf(qx_1, pc.x, fmaf(qy_1, pc.y, fmaf(qz_1, pc.z, pc.w)));
        if (d <= t2_1) {
          int sl = atomicAdd(&ccnt[grp * 2 + 1], 1);
          if (sl < 8) { cand_d[grp * 2 + 1][sl] = d; cand_s[grp * 2 + 1][sl] = s; }
        }
      }
    }
  }
  __syncthreads();

  // ---- select 3 smallest (d, s) lexicographic + weights ----
  if (sub == 0) {
#pragma unroll
    for (int q = 0; q < 2; ++q) {
      int qi = grp * 2 + q;
      int n = min(ccnt[qi], 8);
      ull k0 = ~0ull, k1 = ~0ull, k2 = ~0ull;
      for (int i = 0; i < n; ++i) {
        ull k = ((ull)sortkey(cand_d[qi][i]) << 32) | (unsigned)cand_s[qi][i];
        ins3u(k, k0, k1, k2);
      }
      float q2v = q ? q2_1 : q2_0;
      float e0 = fmaxf(unsortkey((unsigned)(k0 >> 32)) + q2v, 0.0f);
      float e1 = fmaxf(unsortkey((unsigned)(k1 >> 32)) + q2v, 0.0f);
      float e2 = fmaxf(unsortkey((unsigned)(k2 >> 32)) + q2v, 0.0f);
      float r0 = 1.0f / (e0 + 1e-8f);
      float r1 = 1.0f / (e1 + 1e-8f);
      float r2 = 1.0f / (e2 + 1e-8f);
      float rs = 1.0f / (r0 + r1 + r2);
      sidx[qi][0] = (int)(unsigned)k0;
      sidx[qi][1] = (int)(unsigned)k1;
      sidx[qi][2] = (int)(unsigned)k2;
      swt[qi][0] = r0 * rs;
      swt[qi][1] = r1 * rs;
      swt[qi][2] = r2 * rs;
    }
  }
  __syncthreads();

  // ---- fused gather tail: 8 threads per query, 4 x 16B chunks each ----
  int qi = tid >> 3, cc = tid & 7;
  int j0 = sidx[qi][0], j1 = sidx[qi][1], j2 = sidx[qi][2];
  float w0v = swt[qi][0], w1v = swt[qi][1], w2v = swt[qi][2];
  const unsigned short* pb = p2t + (size_t)b * S * 256;
  const unsigned short* r0p = pb + (size_t)j0 * 256;
  const unsigned short* r1p = pb + (size_t)j1 * 256;
  const unsigned short* r2p = pb + (size_t)j2 * 256;
  unsigned short* xp = Xb + ((size_t)b * N + n0 + qi) * 512 + 256;
#pragma unroll
  for (int h = 0; h < 4; ++h) {
    int co = (cc + h * 8) * 8;
    ushort8v v0 = *(const ushort8v*)(r0p + co);
    ushort8v v1 = *(const ushort8v*)(r1p + co);
    ushort8v v2 = *(const ushort8v*)(r2p + co);
    ushort8v o;
#pragma unroll
    for (int i = 0; i < 8; ++i)
      o[i] = f2bf(w0v * bf2f(v0[i]) + w1v * bf2f(v1[i]) + w2v * bf2f(v2[i]));
    *(ushort8v*)(xp + co) = o;
  }
}

// ---------------- fused prep: tconv(points1), tconv(points2), weight convert ----------------
__device__ inline void tconv_body(const float* __restrict__ src,
                                  unsigned short* __restrict__ dst,
                                  int cols, int drow, int bx, int by, int bz,
                                  float (*t)[65]) {
  int n0 = bx * 64, c0 = by * 64, b = bz;
  int tid = threadIdx.x, r = tid >> 2, q = tid & 3;
  const float* sp = src + ((size_t)b * 256 + c0 + r) * cols + n0 + q * 16;
#pragma unroll
  for (int i = 0; i < 4; ++i) {
    float4 v = *(const float4*)(sp + i * 4);
    t[r][q * 16 + i * 4 + 0] = v.x;
    t[r][q * 16 + i * 4 + 1] = v.y;
    t[r][q * 16 + i * 4 + 2] = v.z;
    t[r][q * 16 + i * 4 + 3] = v.w;
  }
  __syncthreads();
  unsigned short* dp = dst + ((size_t)b * cols + n0 + r) * drow + c0 + q * 16;
  ushort8v o0, o1;
#pragma unroll
  for (int i = 0; i < 8; ++i) o0[i] = f2bf(t[q * 16 + i][r]);
#pragma unroll
  for (int i = 0; i < 8; ++i) o1[i] = f2bf(t[q * 16 + 8 + i][r]);
  *(ushort8v*)dp = o0;
  *(ushort8v*)(dp + 8) = o1;
}

__global__ __launch_bounds__(256) void prep_kernel(const float* __restrict__ points1,
                                                   const float* __restrict__ points2,
                                                   const float* __restrict__ w0,
                                                   const float* __restrict__ w1,
                                                   unsigned short* __restrict__ Xb,
                                                   unsigned short* __restrict__ p2t,
                                                   unsigned short* __restrict__ w0b,
                                                   unsigned short* __restrict__ w1b) {
  __shared__ float t[64][65];
  int id = blockIdx.x;
  if (id < 4096) {  // points1 -> Xb[.][0:256], drow 512
    tconv_body(points1, Xb, N, 512, id & 127, (id >> 7) & 3, id >> 9, t);
  } else if (id < 5120) {  // points2 -> p2t, drow 256
    id -= 4096;
    tconv_body(points2, p2t, S, 256, id & 31, (id >> 5) & 3, id >> 7, t);
  } else {  // weights
    int i = (id - 5120) * 256 + threadIdx.x;
    if (i < C * CIN) w0b[i] = f2bf(w0[i]);
    else {
      int j = i - C * CIN;
      if (j < C * C) w1b[j] = f2bf(w1[j]);
    }
  }
}

// ---------------- bf16 MFMA GEMM, BK=64 + channel-major partial stats ----------------
__global__ __launch_bounds__(256) void gemm_kernel(const unsigned short* __restrict__ X,
                                                   const unsigned short* __restrict__ Wb,
                                                   const float* __restrict__ bias,
                                                   unsigned short* __restrict__ Y,
                                                   float* __restrict__ psum,
                                                   float* __restrict__ psumsq,
                                                   int Cin) {
  __shared__ unsigned short As[128 * 64];  // [o_row][k] 16KB, swizzled
  __shared__ unsigned short Bs[128 * 64];  // [n_row][k] 16KB, swizzled
  int n0 = blockIdx.x * 128, o0 = blockIdx.y * 128, b = blockIdx.z;
  int tid = threadIdx.x, lane = tid & 63, wid = tid >> 6;
  int wm = wid >> 1, wn = wid & 1;
  floatx4 acc[4][4];
#pragma unroll
  for (int m = 0; m < 4; ++m)
#pragma unroll
    for (int nt = 0; nt < 4; ++nt) acc[m][nt] = (floatx4)(0.0f);

  size_t rsA = (size_t)Cin * 2;  // row stride bytes
  int chunkSwz = ((lane & 7) ^ ((lane >> 3) & 7)) * 16;
  const char* Abase = (const char*)Wb + (size_t)(o0 + wid * 32 + (lane >> 3)) * rsA + chunkSwz;
  const char* Bbase = (const char*)X + ((size_t)b * N + n0 + wid * 32 + (lane >> 3)) * rsA + chunkSwz;
  size_t rstep8 = 8 * rsA;
  int fr = lane & 15;
  int cbase = lane >> 4;   // 0..3
  int rswz = lane & 7;     // row&7 for this lane's fragment reads

  for (int k0 = 0; k0 < Cin; k0 += 64) {
#pragma unroll
    for (int l = 0; l < 4; ++l) {
      load_lds16(Abase + (size_t)k0 * 2 + (size_t)l * rstep8, &As[(wid * 32 + l * 8) * 64]);
      load_lds16(Bbase + (size_t)k0 * 2 + (size_t)l * rstep8, &Bs[(wid * 32 + l * 8) * 64]);
    }
    __syncthreads();
#pragma unroll
    for (int kk = 0; kk < 2; ++kk) {
      int chunk = (cbase + kk * 4) ^ rswz;
      bf16x8 af[4], bfv[4];
#pragma unroll
      for (int m = 0; m < 4; ++m)
        af[m] = *(const bf16x8*)&As[(wm * 64 + m * 16 + fr) * 64 + chunk * 8];
#pragma unroll
      for (int nt = 0; nt < 4; ++nt)
        bfv[nt] = *(const bf16x8*)&Bs[(wn * 64 + nt * 16 + fr) * 64 + chunk * 8];
#pragma unroll
      for (int m = 0; m < 4; ++m)
#pragma unroll
        for (int nt = 0; nt < 4; ++nt)
          acc[m][nt] = __builtin_amdgcn_mfma_f32_16x16x32_bf16(af[m], bfv[nt], acc[m][nt], 0, 0, 0);
    }
    __syncthreads();
  }

  int col = lane & 15, rowq = lane >> 4;
  int slot = ((b * 64 + blockIdx.x) * 2) + wn;
#pragma unroll
  for (int m = 0; m < 4; ++m) {
    int ob = o0 + wm * 64 + m * 16 + rowq * 4;
    float4 bs = *(const float4*)&bias[ob];
    float sj[4] = {0.f, 0.f, 0.f, 0.f}, qj[4] = {0.f, 0.f, 0.f, 0.f};
#pragma unroll
    for (int nt = 0; nt < 4; ++nt) {
      int n = n0 + wn * 64 + nt * 16 + col;
      float y0 = acc[m][nt][0] + bs.x;
      float y1 = acc[m][nt][1] + bs.y;
      float y2 = acc[m][nt][2] + bs.z;
      float y3 = acc[m][nt][3] + bs.w;
      ushort4v v;
      v[0] = f2bf(y0); v[1] = f2bf(y1); v[2] = f2bf(y2); v[3] = f2bf(y3);
      *(ushort4v*)&Y[((size_t)b * N + n) * 256 + ob] = v;
      sj[0] += y0; qj[0] = fmaf(y0, y0, qj[0]);
      sj[1] += y1; qj[1] = fmaf(y1, y1, qj[1]);
      sj[2] += y2; qj[2] = fmaf(y2, y2, qj[2]);
      sj[3] += y3; qj[3] = fmaf(y3, y3, qj[3]);
    }
#pragma unroll
    for (int j = 0; j < 4; ++j) {
#pragma unroll
      for (int d = 1; d <= 8; d <<= 1) {
        sj[j] += __shfl_xor(sj[j], d);
        qj[j] += __shfl_xor(qj[j], d);
      }
    }
    if (col == 0) {
      int c0 = blockIdx.y * 128 + wm * 64 + m * 16 + rowq * 4;
#pragma unroll
      for (int j = 0; j < 4; ++j) {
        psum[(size_t)(c0 + j) * NSLOT + slot] = sj[j];
        psumsq[(size_t)(c0 + j) * NSLOT + slot] = qj[j];
      }
    }
  }
}

// ---------------- parallel reduce partials -> BN scale/shift (256 blocks) ----------------
__global__ __launch_bounds__(256) void bnparam_kernel(const float* __restrict__ psum,
                                                      const float* __restrict__ psumsq,
                                                      const float* __restrict__ gamma,
                                                      const float* __restrict__ beta,
                                                      float* __restrict__ scale,
                                                      float* __restrict__ shift) {
  int c = blockIdx.x, tid = threadIdx.x;
  const float* ps = psum + (size_t)c * NSLOT;
  const float* pq = psumsq + (size_t)c * NSLOT;
  float s = 0.f, q = 0.f;
#pragma unroll
  for (int i = 0; i < NSLOT / 256; ++i) {
    s += ps[tid + i * 256];
    q += pq[tid + i * 256];
  }
#pragma unroll
  for (int d = 1; d <= 32; d <<= 1) {
    s += __shfl_xor(s, d);
    q += __shfl_xor(q, d);
  }
  __shared__ float ls[4], lq[4];
  int wid = tid >> 6;
  if ((tid & 63) == 0) { ls[wid] = s; lq[wid] = q; }
  __syncthreads();
  if (tid == 0) {
    s = ls[0] + ls[1] + ls[2] + ls[3];
    q = lq[0] + lq[1] + lq[2] + lq[3];
    float m = s * (1.0f / CNT);
    float v = q * (1.0f / CNT) - m * m;
    float sc = gamma[c] * rsqrtf(v + 1e-5f);
    scale[c] = sc;
    shift[c] = beta[c] - m * sc;
  }
}

// ---------------- BN+ReLU elementwise on [b][n][256] bf16 -> bf16 ----------------
__global__ __launch_bounds__(256) void bnrelu_kernel(const unsigned short* __restrict__ Y,
                                                     const float* __restrict__ scale,
                                                     const float* __restrict__ shift,
                                                     unsigned short* __restrict__ H) {
  size_t total = (size_t)B * N * 256 / 8;
  for (size_t i = (size_t)blockIdx.x * 256 + threadIdx.x; i < total;
       i += (size_t)gridDim.x * 256) {
    int ob = ((int)i & 31) * 8;
    float4 s0 = *(const float4*)&scale[ob];
    float4 s1 = *(const float4*)&scale[ob + 4];
    float4 h0 = *(const float4*)&shift[ob];
    float4 h1 = *(const float4*)&shift[ob + 4];
    ushort8v v = *(const ushort8v*)&Y[i * 8];
    ushort8v o;
    o[0] = f2bf(fmaxf(fmaf(bf2f(v[0]), s0.x, h0.x), 0.f));
    o[1] = f2bf(fmaxf(fmaf(bf2f(v[1]), s0.y, h0.y), 0.f));
    o[2] = f2bf(fmaxf(fmaf(bf2f(v[2]), s0.z, h0.z), 0.f));
    o[3] = f2bf(fmaxf(fmaf(bf2f(v[3]), s0.w, h0.w), 0.f));
    o[4] = f2bf(fmaxf(fmaf(bf2f(v[4]), s1.x, h1.x), 0.f));
    o[5] = f2bf(fmaxf(fmaf(bf2f(v[5]), s1.y, h1.y), 0.f));
    o[6] = f2bf(fmaxf(fmaf(bf2f(v[6]), s1.z, h1.z), 0.f));
    o[7] = f2bf(fmaxf(fmaf(bf2f(v[7]), s1.w, h1.w), 0.f));
    *(ushort8v*)&H[i * 8] = o;
  }
}

// ---------------- final: BN+ReLU + transpose [b][n][o] bf16 -> out [b][o][n] f32 ----------------
__global__ __launch_bounds__(256) void bnreluT_kernel(const unsigned short* __restrict__ Y,
                                                      const float* __restrict__ scale,
                                                      const float* __restrict__ shift,
                                                      float* __restrict__ out) {
  __shared__ float t[64][65];
  int n0 = blockIdx.x * 64, o0 = blockIdx.y * 64, b = blockIdx.z;
  int tid = threadIdx.x, r = tid >> 2, q = tid & 3;
  const unsigned short* yp = Y + ((size_t)b * N + n0 + r) * 256 + o0 + q * 16;
#pragma unroll
  for (int h = 0; h < 2; ++h) {
    ushort8v v = *(const ushort8v*)(yp + h * 8);
#pragma unroll
    for (int i = 0; i < 8; ++i) {
      int oc = q * 16 + h * 8 + i;
      float f = fmaxf(fmaf(bf2f(v[i]), scale[o0 + oc], shift[o0 + oc]), 0.f);
      t[oc][r] = f;
    }
  }
  __syncthreads();
  float* op = out + ((size_t)b * 256 + o0 + r) * N + n0 + q * 16;
#pragma unroll
  for (int i = 0; i < 4; ++i) {
    float4 v = make_float4(t[r][q * 16 + i * 4 + 0], t[r][q * 16 + i * 4 + 1],
                           t[r][q * 16 + i * 4 + 2], t[r][q * 16 + i * 4 + 3]);
    *(float4*)(op + i * 4) = v;
  }
}

extern "C" void kernel_launch(void* const* d_in, const int* in_sizes, int n_in,
                              void* d_out, int out_size, void* d_ws, size_t ws_size,
                              hipStream_t stream) {
  const float* xyz1 = (const float*)d_in[0];
  const float* xyz2 = (const float*)d_in[1];
  const float* points1 = (const float*)d_in[2];
  const float* points2 = (const float*)d_in[3];
  const float* w0 = (const float*)d_in[4];
  const float* b0 = (const float*)d_in[5];
  const float* g0 = (const float*)d_in[6];
  const float* be0 = (const float*)d_in[7];
  const float* w1 = (const float*)d_in[8];
  const float* b1 = (const float*)d_in[9];
  const float* g1 = (const float*)d_in[10];
  const float* be1 = (const float*)d_in[11];
  float* out = (float*)d_out;

  char* ws = (char*)d_ws;
  float* scale0 = (float*)ws;          ws += 256 * 4;
  float* shift0 = (float*)ws;          ws += 256 * 4;
  float* scale1 = (float*)ws;          ws += 256 * 4;
  float* shift1 = (float*)ws;          ws += 256 * 4;
  float* psum = (float*)ws;            ws += (size_t)C * NSLOT * 4;    // 1MB
  float* psumsq = (float*)ws;          ws += (size_t)C * NSLOT * 4;    // 1MB
  unsigned short* w0b = (unsigned short*)ws;  ws += (size_t)C * CIN * 2;   // 256KB
  unsigned short* w1b = (unsigned short*)ws;  ws += (size_t)C * C * 2;     // 128KB
  unsigned short* p2t = (unsigned short*)ws;  ws += (size_t)B * S * 256 * 2;   // 8MB
  unsigned short* Xb = (unsigned short*)ws;   ws += (size_t)B * N * 512 * 2;   // 64MB
  unsigned short* Yb = (unsigned short*)ws;   ws += (size_t)B * N * 256 * 2;   // 32MB
  unsigned short* Hb = Xb;  // reuse Xb after GEMM0 consumed it

  prep_kernel<<<dim3(4096 + 1024 + 768), 256, 0, stream>>>(points1, points2, w0, w1,
                                                           Xb, p2t, w0b, w1b);
  nn3_kernel<<<dim3(B * N / 32), 256, 0, stream>>>(xyz1, xyz2, p2t, Xb);
  gemm_kernel<<<dim3(N / 128, 2, B), 256, 0, stream>>>(Xb, w0b, b0, Yb, psum, psumsq, CIN);
  bnparam_kernel<<<dim3(C), 256, 0, stream>>>(psum, psumsq, g0, be0, scale0, shift0);
  bnrelu_kernel<<<dim3(2048), 256, 0, stream>>>(Yb, scale0, shift0, Hb);
  gemm_kernel<<<dim3(N / 128, 2, B), 256, 0, stream>>>(Hb, w1b, b1, Yb, psum, psumsq, C);
  bnparam_kernel<<<dim3(C), 256, 0, stream>>>(psum, psumsq, g1, be1, scale1, shift1);
  bnreluT_kernel<<<dim3(N / 64, 4, B), 256, 0, stream>>>(Yb, scale1, shift1, out);
}

// Round 16
// 187.372 us; speedup vs baseline: 4.1378x; 1.0331x over previous
//
#include <hip/hip_runtime.h>
#include <math.h>

#define B 8
#define N 8192
#define S 2048
#define SCH 1024  // points per LDS chunk
#define C 256
#define CIN 512
#define CNT (B * N)  // 65536
#define NSLOT 1024   // (b*64 + bx)*2 + wn

typedef unsigned long long ull;
typedef __attribute__((ext_vector_type(8))) short bf16x8;
typedef __attribute__((ext_vector_type(4))) float floatx4;
typedef __attribute__((ext_vector_type(8))) unsigned short ushort8v;
typedef __attribute__((ext_vector_type(4))) unsigned short ushort4v;

__device__ inline unsigned short f2bf(float f) {
  unsigned u = __builtin_bit_cast(unsigned, f);
  u += 0x7FFF + ((u >> 16) & 1);  // RNE
  return (unsigned short)(u >> 16);
}
__device__ inline float bf2f(unsigned short h) {
  unsigned u = ((unsigned)h) << 16;
  return __builtin_bit_cast(float, u);
}

__device__ inline void load_lds16(const void* g, void* l) {
  __builtin_amdgcn_global_load_lds(
      (const __attribute__((address_space(1))) unsigned int*)g,
      (__attribute__((address_space(3))) unsigned int*)l, 16, 0, 0);
}

// ---------------- 3-NN v15: two-phase (d-only scan + threshold recovery) ----------------
__device__ inline void ins3u(ull k, ull& k0, ull& k1, ull& k2) {
  if (k < k2) {
    if (k < k1) {
      k2 = k1;
      if (k < k0) { k1 = k0; k0 = k; } else k1 = k;
    } else k2 = k;
  }
}

__device__ inline void insf(float k, float& m0, float& m1, float& m2) {
  float n1 = __builtin_amdgcn_fmed3f(k, m0, m1);
  float n2 = __builtin_amdgcn_fmed3f(k, m1, m2);
  m0 = fminf(k, m0);
  m1 = n1;
  m2 = n2;
}

__device__ inline unsigned sortkey(float f) {
  unsigned u = __float_as_uint(f);
  return u ^ (((unsigned)((int)u >> 31)) | 0x80000000u);
}
__device__ inline float unsortkey(unsigned u) {
  unsigned m = ((int)u < 0) ? 0x80000000u : 0xFFFFFFFFu;
  return __uint_as_float(u ^ m);
}

#define QDECL(q)                                                            \
  float d0_##q = INFINITY, d1_##q = INFINITY, d2_##q = INFINITY;            \
  float qx_##q, qy_##q, qz_##q, q2_##q;

#define QLOAD(q)                                                            \
  {                                                                         \
    float ox = p1[nq + q], oy = p1[N + nq + q], oz = p1[2 * N + nq + q];    \
    q2_##q = ox * ox + oy * oy + oz * oz;                                   \
    qx_##q = -2.0f * ox; qy_##q = -2.0f * oy; qz_##q = -2.0f * oz;          \
  }

#define QINSD(q)                                                            \
  {                                                                         \
    float d = fmaf(qx_##q, pc.x, fmaf(qy_##q, pc.y, fmaf(qz_##q, pc.z, pc.w))); \
    float n1 = __builtin_amdgcn_fmed3f(d, d0_##q, d1_##q);                  \
    float n2 = __builtin_amdgcn_fmed3f(d, d1_##q, d2_##q);                  \
    d0_##q = fminf(d, d0_##q);                                              \
    d1_##q = n1;                                                            \
    d2_##q = n2;                                                            \
  }

__global__ __launch_bounds__(256, 4) void nn3_kernel(const float* __restrict__ xyz1,
                                                     const float* __restrict__ xyz2,
                                                     const unsigned short* __restrict__ p2t,
                                                     unsigned short* __restrict__ Xb) {
  __shared__ float4 sp[SCH];  // 16KB staging; phase-1 merge array aliases it
  __shared__ float t2q[32];
  __shared__ int ccnt[32];
  __shared__ float cand_d[32][8];
  __shared__ int cand_s[32][8];
  __shared__ int sidx[32][3];
  __shared__ float swt[32][3];
  int b = blockIdx.x >> 8;            // grid = B * (N/32) = 2048
  int n0 = (blockIdx.x & 255) * 32;
  const float* p2 = xyz2 + (size_t)b * 3 * S;
  int tid = threadIdx.x;
  int sub = tid & 15, grp = tid >> 4;  // 16 grps x 2 queries = 32 queries/block
  const float* p1 = xyz1 + (size_t)b * 3 * N;
  int nq = n0 + grp * 2;
  QDECL(0) QDECL(1)
  QLOAD(0) QLOAD(1)

  // ---- phase 1: d-only scan over 2 chunks ----
  for (int ch = 0; ch < 2; ++ch) {
    if (ch) __syncthreads();
    for (int i = tid; i < SCH; i += 256) {
      int g = ch * SCH + i;
      float px = p2[g], py = p2[S + g], pz = p2[2 * S + g];
      sp[i] = make_float4(px, py, pz, px * px + py * py + pz * pz);
    }
    __syncthreads();
    const float4* spp = sp + sub;
    float4 pc = spp[0];
    for (int t = 0; t < SCH / 16 - 1; ++t) {
      float4 pn = spp[(t + 1) * 16];
      QINSD(0) QINSD(1)
      pc = pn;
    }
    QINSD(0) QINSD(1)
  }

  // ---- merge per-sub top-3 distances -> per-query 3rd-best threshold ----
  __syncthreads();
  float* tm = (float*)sp;  // [32 queries][16 subs][3] floats (6KB)
  tm[((grp * 2 + 0) * 16 + sub) * 3 + 0] = d0_0;
  tm[((grp * 2 + 0) * 16 + sub) * 3 + 1] = d1_0;
  tm[((grp * 2 + 0) * 16 + sub) * 3 + 2] = d2_0;
  tm[((grp * 2 + 1) * 16 + sub) * 3 + 0] = d0_1;
  tm[((grp * 2 + 1) * 16 + sub) * 3 + 1] = d1_1;
  tm[((grp * 2 + 1) * 16 + sub) * 3 + 2] = d2_1;
  if (tid < 32) ccnt[tid] = 0;
  __syncthreads();
  if (sub < 4) {
#pragma unroll
    for (int q = 0; q < 2; ++q) {
      int qi = grp * 2 + q;
      float m0 = INFINITY, m1 = INFINITY, m2 = INFINITY;
#pragma unroll
      for (int jj = 0; jj < 4; ++jj) {
        int ss = sub + 4 * jj;
        insf(tm[(qi * 16 + ss) * 3 + 0], m0, m1, m2);
        insf(tm[(qi * 16 + ss) * 3 + 1], m0, m1, m2);
        insf(tm[(qi * 16 + ss) * 3 + 2], m0, m1, m2);
      }
#pragma unroll
      for (int mm = 1; mm <= 2; mm <<= 1) {
        float e0 = __shfl_xor(m0, mm);
        float e1 = __shfl_xor(m1, mm);
        float e2 = __shfl_xor(m2, mm);
        insf(e0, m0, m1, m2);
        insf(e1, m0, m1, m2);
        insf(e2, m0, m1, m2);
      }
      if (sub == 0) t2q[qi] = m2;
    }
  }
  __syncthreads();
  float t2_0 = t2q[grp * 2], t2_1 = t2q[grp * 2 + 1];

  // ---- phase 2: rescan with threshold, collect candidates ----
  for (int ch = 0; ch < 2; ++ch) {
    if (ch) __syncthreads();
    for (int i = tid; i < SCH; i += 256) {
      int g = ch * SCH + i;
      float px = p2[g], py = p2[S + g], pz = p2[2 * S + g];
      sp[i] = make_float4(px, py, pz, px * px + py * py + pz * pz);
    }
    __syncthreads();
    const float4* spp = sp + sub;
    for (int t = 0; t < SCH / 16; ++t) {
      float4 pc = spp[t * 16];
      int s = ch * SCH + t * 16 + sub;
      {
        float d = fmaf(qx_0, pc.x, fmaf(qy_0, pc.y, fmaf(qz_0, pc.z, pc.w)));
        if (d <= t2_0) {
          int sl = atomicAdd(&ccnt[grp * 2], 1);
          if (sl < 8) { cand_d[grp * 2][sl] = d; cand_s[grp * 2][sl] = s; }
        }
      }
      {
        float d = fmaf(qx_1, pc.x, fmaf(qy_1, pc.y, fmaf(qz_1, pc.z, pc.w)));
        if (d <= t2_1) {
          int sl = atomicAdd(&ccnt[grp * 2 + 1], 1);
          if (sl < 8) { cand_d[grp * 2 + 1][sl] = d; cand_s[grp * 2 + 1][sl] = s; }
        }
      }
    }
  }
  __syncthreads();

  // ---- select 3 smallest (d, s) lexicographic + weights ----
  if (sub == 0) {
#pragma unroll
    for (int q = 0; q < 2; ++q) {
      int qi = grp * 2 + q;
      int n = min(ccnt[qi], 8);
      ull k0 = ~0ull, k1 = ~0ull, k2 = ~0ull;
      for (int i = 0; i < n; ++i) {
        ull k = ((ull)sortkey(cand_d[qi][i]) << 32) | (unsigned)cand_s[qi][i];
        ins3u(k, k0, k1, k2);
      }
      float q2v = q ? q2_1 : q2_0;
      float e0 = fmaxf(unsortkey((unsigned)(k0 >> 32)) + q2v, 0.0f);
      float e1 = fmaxf(unsortkey((unsigned)(k1 >> 32)) + q2v, 0.0f);
      float e2 = fmaxf(unsortkey((unsigned)(k2 >> 32)) + q2v, 0.0f);
      float r0 = 1.0f / (e0 + 1e-8f);
      float r1 = 1.0f / (e1 + 1e-8f);
      float r2 = 1.0f / (e2 + 1e-8f);
      float rs = 1.0f / (r0 + r1 + r2);
      sidx[qi][0] = (int)(unsigned)k0;
      sidx[qi][1] = (int)(unsigned)k1;
      sidx[qi][2] = (int)(unsigned)k2;
      swt[qi][0] = r0 * rs;
      swt[qi][1] = r1 * rs;
      swt[qi][2] = r2 * rs;
    }
  }
  __syncthreads();

  // ---- fused gather tail: 8 threads per query, 4 x 16B chunks each ----
  int qi = tid >> 3, cc = tid & 7;
  int j0 = sidx[qi][0], j1 = sidx[qi][1], j2 = sidx[qi][2];
  float w0v = swt[qi][0], w1v = swt[qi][1], w2v = swt[qi][2];
  const unsigned short* pb = p2t + (size_t)b * S * 256;
  const unsigned short* r0p = pb + (size_t)j0 * 256;
  const unsigned short* r1p = pb + (size_t)j1 * 256;
  const unsigned short* r2p = pb + (size_t)j2 * 256;
  unsigned short* xp = Xb + ((size_t)b * N + n0 + qi) * 512 + 256;
#pragma unroll
  for (int h = 0; h < 4; ++h) {
    int co = (cc + h * 8) * 8;
    ushort8v v0 = *(const ushort8v*)(r0p + co);
    ushort8v v1 = *(const ushort8v*)(r1p + co);
    ushort8v v2 = *(const ushort8v*)(r2p + co);
    ushort8v o;
#pragma unroll
    for (int i = 0; i < 8; ++i)
      o[i] = f2bf(w0v * bf2f(v0[i]) + w1v * bf2f(v1[i]) + w2v * bf2f(v2[i]));
    *(ushort8v*)(xp + co) = o;
  }
}

// ---------------- fused prep: tconv(points1), tconv(points2), weight convert ----------------
__device__ inline void tconv_body(const float* __restrict__ src,
                                  unsigned short* __restrict__ dst,
                                  int cols, int drow, int bx, int by, int bz,
                                  float (*t)[65]) {
  int n0 = bx * 64, c0 = by * 64, b = bz;
  int tid = threadIdx.x, r = tid >> 2, q = tid & 3;
  const float* sp = src + ((size_t)b * 256 + c0 + r) * cols + n0 + q * 16;
#pragma unroll
  for (int i = 0; i < 4; ++i) {
    float4 v = *(const float4*)(sp + i * 4);
    t[r][q * 16 + i * 4 + 0] = v.x;
    t[r][q * 16 + i * 4 + 1] = v.y;
    t[r][q * 16 + i * 4 + 2] = v.z;
    t[r][q * 16 + i * 4 + 3] = v.w;
  }
  __syncthreads();
  unsigned short* dp = dst + ((size_t)b * cols + n0 + r) * drow + c0 + q * 16;
  ushort8v o0, o1;
#pragma unroll
  for (int i = 0; i < 8; ++i) o0[i] = f2bf(t[q * 16 + i][r]);
#pragma unroll
  for (int i = 0; i < 8; ++i) o1[i] = f2bf(t[q * 16 + 8 + i][r]);
  *(ushort8v*)dp = o0;
  *(ushort8v*)(dp + 8) = o1;
}

__global__ __launch_bounds__(256) void prep_kernel(const float* __restrict__ points1,
                                                   const float* __restrict__ points2,
                                                   const float* __restrict__ w0,
                                                   const float* __restrict__ w1,
                                                   unsigned short* __restrict__ Xb,
                                                   unsigned short* __restrict__ p2t,
                                                   unsigned short* __restrict__ w0b,
                                                   unsigned short* __restrict__ w1b) {
  __shared__ float t[64][65];
  int id = blockIdx.x;
  if (id < 4096) {  // points1 -> Xb[.][0:256], drow 512
    tconv_body(points1, Xb, N, 512, id & 127, (id >> 7) & 3, id >> 9, t);
  } else if (id < 5120) {  // points2 -> p2t, drow 256
    id -= 4096;
    tconv_body(points2, p2t, S, 256, id & 31, (id >> 5) & 3, id >> 7, t);
  } else {  // weights
    int i = (id - 5120) * 256 + threadIdx.x;
    if (i < C * CIN) w0b[i] = f2bf(w0[i]);
    else {
      int j = i - C * CIN;
      if (j < C * C) w1b[j] = f2bf(w1[j]);
    }
  }
}

// ---------------- bf16 MFMA GEMM, BK=64 + channel-major partial stats ----------------
__global__ __launch_bounds__(256) void gemm_kernel(const unsigned short* __restrict__ X,
                                                   const unsigned short* __restrict__ Wb,
                                                   const float* __restrict__ bias,
                                                   unsigned short* __restrict__ Y,
                                                   float* __restrict__ psum,
                                                   float* __restrict__ psumsq,
                                                   int Cin) {
  __shared__ unsigned short As[128 * 64];  // [o_row][k] 16KB, swizzled
  __shared__ unsigned short Bs[128 * 64];  // [n_row][k] 16KB, swizzled
  int n0 = blockIdx.x * 128, o0 = blockIdx.y * 128, b = blockIdx.z;
  int tid = threadIdx.x, lane = tid & 63, wid = tid >> 6;
  int wm = wid >> 1, wn = wid & 1;
  floatx4 acc[4][4];
#pragma unroll
  for (int m = 0; m < 4; ++m)
#pragma unroll
    for (int nt = 0; nt < 4; ++nt) acc[m][nt] = (floatx4)(0.0f);

  size_t rsA = (size_t)Cin * 2;  // row stride bytes
  int chunkSwz = ((lane & 7) ^ ((lane >> 3) & 7)) * 16;
  const char* Abase = (const char*)Wb + (size_t)(o0 + wid * 32 + (lane >> 3)) * rsA + chunkSwz;
  const char* Bbase = (const char*)X + ((size_t)b * N + n0 + wid * 32 + (lane >> 3)) * rsA + chunkSwz;
  size_t rstep8 = 8 * rsA;
  int fr = lane & 15;
  int cbase = lane >> 4;   // 0..3
  int rswz = lane & 7;     // row&7 for this lane's fragment reads

  for (int k0 = 0; k0 < Cin; k0 += 64) {
#pragma unroll
    for (int l = 0; l < 4; ++l) {
      load_lds16(Abase + (size_t)k0 * 2 + (size_t)l * rstep8, &As[(wid * 32 + l * 8) * 64]);
      load_lds16(Bbase + (size_t)k0 * 2 + (size_t)l * rstep8, &Bs[(wid * 32 + l * 8) * 64]);
    }
    __syncthreads();
#pragma unroll
    for (int kk = 0; kk < 2; ++kk) {
      int chunk = (cbase + kk * 4) ^ rswz;
      bf16x8 af[4], bfv[4];
#pragma unroll
      for (int m = 0; m < 4; ++m)
        af[m] = *(const bf16x8*)&As[(wm * 64 + m * 16 + fr) * 64 + chunk * 8];
#pragma unroll
      for (int nt = 0; nt < 4; ++nt)
        bfv[nt] = *(const bf16x8*)&Bs[(wn * 64 + nt * 16 + fr) * 64 + chunk * 8];
#pragma unroll
      for (int m = 0; m < 4; ++m)
#pragma unroll
        for (int nt = 0; nt < 4; ++nt)
          acc[m][nt] = __builtin_amdgcn_mfma_f32_16x16x32_bf16(af[m], bfv[nt], acc[m][nt], 0, 0, 0);
    }
    __syncthreads();
  }

  int col = lane & 15, rowq = lane >> 4;
  int slot = ((b * 64 + blockIdx.x) * 2) + wn;
#pragma unroll
  for (int m = 0; m < 4; ++m) {
    int ob = o0 + wm * 64 + m * 16 + rowq * 4;
    float4 bs = *(const float4*)&bias[ob];
    float sj[4] = {0.f, 0.f, 0.f, 0.f}, qj[4] = {0.f, 0.f, 0.f, 0.f};
#pragma unroll
    for (int nt = 0; nt < 4; ++nt) {
      int n = n0 + wn * 64 + nt * 16 + col;
      float y0 = acc[m][nt][0] + bs.x;
      float y1 = acc[m][nt][1] + bs.y;
      float y2 = acc[m][nt][2] + bs.z;
      float y3 = acc[m][nt][3] + bs.w;
      ushort4v v;
      v[0] = f2bf(y0); v[1] = f2bf(y1); v[2] = f2bf(y2); v[3] = f2bf(y3);
      *(ushort4v*)&Y[((size_t)b * N + n) * 256 + ob] = v;
      sj[0] += y0; qj[0] = fmaf(y0, y0, qj[0]);
      sj[1] += y1; qj[1] = fmaf(y1, y1, qj[1]);
      sj[2] += y2; qj[2] = fmaf(y2, y2, qj[2]);
      sj[3] += y3; qj[3] = fmaf(y3, y3, qj[3]);
    }
#pragma unroll
    for (int j = 0; j < 4; ++j) {
#pragma unroll
      for (int d = 1; d <= 8; d <<= 1) {
        sj[j] += __shfl_xor(sj[j], d);
        qj[j] += __shfl_xor(qj[j], d);
      }
    }
    if (col == 0) {
      int c0 = blockIdx.y * 128 + wm * 64 + m * 16 + rowq * 4;
#pragma unroll
      for (int j = 0; j < 4; ++j) {
        psum[(size_t)(c0 + j) * NSLOT + slot] = sj[j];
        psumsq[(size_t)(c0 + j) * NSLOT + slot] = qj[j];
      }
    }
  }
}

// ---------------- gemm1 with fused input BN+ReLU (T14 reg-staged B side) ----------------
// B-tile: load raw Y (gemm0 output) to regs, apply H = relu(scale0*y+shift0)
// per GLOBAL channel (k = k0 + cg*8, cg = (lane&7)^(row&7)), convert to bf16,
// ds_write to the same swizzled LDS layout global_load_lds produced.
// Removes the standalone bnrelu pass (64MB HBM round-trip + launch).
__global__ __launch_bounds__(256) void gemm_bn_kernel(const unsigned short* __restrict__ X,
                                                      const unsigned short* __restrict__ Wb,
                                                      const float* __restrict__ bias,
                                                      const float* __restrict__ scale,
                                                      const float* __restrict__ shift,
                                                      unsigned short* __restrict__ Y,
                                                      float* __restrict__ psum,
                                                      float* __restrict__ psumsq) {
  const int Cin = C;  // 256
  __shared__ unsigned short As[128 * 64];  // 16KB, swizzled
  __shared__ unsigned short Bs[128 * 64];  // 16KB, swizzled
  __shared__ float sscale[256], sshift[256];
  int n0 = blockIdx.x * 128, o0 = blockIdx.y * 128, b = blockIdx.z;
  int tid = threadIdx.x, lane = tid & 63, wid = tid >> 6;
  int wm = wid >> 1, wn = wid & 1;
  sscale[tid] = scale[tid];
  sshift[tid] = shift[tid];
  floatx4 acc[4][4];
#pragma unroll
  for (int m = 0; m < 4; ++m)
#pragma unroll
    for (int nt = 0; nt < 4; ++nt) acc[m][nt] = (floatx4)(0.0f);

  size_t rsA = (size_t)Cin * 2;
  int cg = (lane & 7) ^ ((lane >> 3) & 7);  // this lane's GLOBAL chunk index
  int chunkSwz = cg * 16;
  const char* Abase = (const char*)Wb + (size_t)(o0 + wid * 32 + (lane >> 3)) * rsA + chunkSwz;
  const char* Bbase = (const char*)X + ((size_t)b * N + n0 + wid * 32 + (lane >> 3)) * rsA + chunkSwz;
  size_t rstep8 = 8 * rsA;
  int fr = lane & 15;
  int cbase = lane >> 4;
  int rswz = lane & 7;
  __syncthreads();  // sscale/sshift visible before first staging use

  for (int k0 = 0; k0 < Cin; k0 += 64) {
    int kb = k0 + cg * 8;
    float4 sc0 = *(const float4*)&sscale[kb];
    float4 sc1 = *(const float4*)&sscale[kb + 4];
    float4 sh0 = *(const float4*)&sshift[kb];
    float4 sh1 = *(const float4*)&sshift[kb + 4];
#pragma unroll
    for (int l = 0; l < 4; ++l) {
      load_lds16(Abase + (size_t)k0 * 2 + (size_t)l * rstep8, &As[(wid * 32 + l * 8) * 64]);
      ushort8v raw = *(const ushort8v*)(Bbase + (size_t)k0 * 2 + (size_t)l * rstep8);
      ushort8v tv;
      tv[0] = f2bf(fmaxf(fmaf(bf2f(raw[0]), sc0.x, sh0.x), 0.f));
      tv[1] = f2bf(fmaxf(fmaf(bf2f(raw[1]), sc0.y, sh0.y), 0.f));
      tv[2] = f2bf(fmaxf(fmaf(bf2f(raw[2]), sc0.z, sh0.z), 0.f));
      tv[3] = f2bf(fmaxf(fmaf(bf2f(raw[3]), sc0.w, sh0.w), 0.f));
      tv[4] = f2bf(fmaxf(fmaf(bf2f(raw[4]), sc1.x, sh1.x), 0.f));
      tv[5] = f2bf(fmaxf(fmaf(bf2f(raw[5]), sc1.y, sh1.y), 0.f));
      tv[6] = f2bf(fmaxf(fmaf(bf2f(raw[6]), sc1.z, sh1.z), 0.f));
      tv[7] = f2bf(fmaxf(fmaf(bf2f(raw[7]), sc1.w, sh1.w), 0.f));
      *(ushort8v*)&Bs[(wid * 32 + l * 8) * 64 + lane * 8] = tv;
    }
    __syncthreads();
#pragma unroll
    for (int kk = 0; kk < 2; ++kk) {
      int chunk = (cbase + kk * 4) ^ rswz;
      bf16x8 af[4], bfv[4];
#pragma unroll
      for (int m = 0; m < 4; ++m)
        af[m] = *(const bf16x8*)&As[(wm * 64 + m * 16 + fr) * 64 + chunk * 8];
#pragma unroll
      for (int nt = 0; nt < 4; ++nt)
        bfv[nt] = *(const bf16x8*)&Bs[(wn * 64 + nt * 16 + fr) * 64 + chunk * 8];
#pragma unroll
      for (int m = 0; m < 4; ++m)
#pragma unroll
        for (int nt = 0; nt < 4; ++nt)
          acc[m][nt] = __builtin_amdgcn_mfma_f32_16x16x32_bf16(af[m], bfv[nt], acc[m][nt], 0, 0, 0);
    }
    __syncthreads();
  }

  int col = lane & 15, rowq = lane >> 4;
  int slot = ((b * 64 + blockIdx.x) * 2) + wn;
#pragma unroll
  for (int m = 0; m < 4; ++m) {
    int ob = o0 + wm * 64 + m * 16 + rowq * 4;
    float4 bs = *(const float4*)&bias[ob];
    float sj[4] = {0.f, 0.f, 0.f, 0.f}, qj[4] = {0.f, 0.f, 0.f, 0.f};
#pragma unroll
    for (int nt = 0; nt < 4; ++nt) {
      int n = n0 + wn * 64 + nt * 16 + col;
      float y0 = acc[m][nt][0] + bs.x;
      float y1 = acc[m][nt][1] + bs.y;
      float y2 = acc[m][nt][2] + bs.z;
      float y3 = acc[m][nt][3] + bs.w;
      ushort4v v;
      v[0] = f2bf(y0); v[1] = f2bf(y1); v[2] = f2bf(y2); v[3] = f2bf(y3);
      *(ushort4v*)&Y[((size_t)b * N + n) * 256 + ob] = v;
      sj[0] += y0; qj[0] = fmaf(y0, y0, qj[0]);
      sj[1] += y1; qj[1] = fmaf(y1, y1, qj[1]);
      sj[2] += y2; qj[2] = fmaf(y2, y2, qj[2]);
      sj[3] += y3; qj[3] = fmaf(y3, y3, qj[3]);
    }
#pragma unroll
    for (int j = 0; j < 4; ++j) {
#pragma unroll
      for (int d = 1; d <= 8; d <<= 1) {
        sj[j] += __shfl_xor(sj[j], d);
        qj[j] += __shfl_xor(qj[j], d);
      }
    }
    if (col == 0) {
      int c0 = blockIdx.y * 128 + wm * 64 + m * 16 + rowq * 4;
#pragma unroll
      for (int j = 0; j < 4; ++j) {
        psum[(size_t)(c0 + j) * NSLOT + slot] = sj[j];
        psumsq[(size_t)(c0 + j) * NSLOT + slot] = qj[j];
      }
    }
  }
}

// ---------------- parallel reduce partials -> BN scale/shift (256 blocks) ----------------
__global__ __launch_bounds__(256) void bnparam_kernel(const float* __restrict__ psum,
                                                      const float* __restrict__ psumsq,
                                                      const float* __restrict__ gamma,
                                                      const float* __restrict__ beta,
                                                      float* __restrict__ scale,
                                                      float* __restrict__ shift) {
  int c = blockIdx.x, tid = threadIdx.x;
  const float* ps = psum + (size_t)c * NSLOT;
  const float* pq = psumsq + (size_t)c * NSLOT;
  float s = 0.f, q = 0.f;
#pragma unroll
  for (int i = 0; i < NSLOT / 256; ++i) {
    s += ps[tid + i * 256];
    q += pq[tid + i * 256];
  }
#pragma unroll
  for (int d = 1; d <= 32; d <<= 1) {
    s += __shfl_xor(s, d);
    q += __shfl_xor(q, d);
  }
  __shared__ float ls[4], lq[4];
  int wid = tid >> 6;
  if ((tid & 63) == 0) { ls[wid] = s; lq[wid] = q; }
  __syncthreads();
  if (tid == 0) {
    s = ls[0] + ls[1] + ls[2] + ls[3];
    q = lq[0] + lq[1] + lq[2] + lq[3];
    float m = s * (1.0f / CNT);
    float v = q * (1.0f / CNT) - m * m;
    float sc = gamma[c] * rsqrtf(v + 1e-5f);
    scale[c] = sc;
    shift[c] = beta[c] - m * sc;
  }
}

// ---------------- final: BN+ReLU + transpose [b][n][o] bf16 -> out [b][o][n] f32 ----------------
__global__ __launch_bounds__(256) void bnreluT_kernel(const unsigned short* __restrict__ Y,
                                                      const float* __restrict__ scale,
                                                      const float* __restrict__ shift,
                                                      float* __restrict__ out) {
  __shared__ float t[64][65];
  int n0 = blockIdx.x * 64, o0 = blockIdx.y * 64, b = blockIdx.z;
  int tid = threadIdx.x, r = tid >> 2, q = tid & 3;
  const unsigned short* yp = Y + ((size_t)b * N + n0 + r) * 256 + o0 + q * 16;
#pragma unroll
  for (int h = 0; h < 2; ++h) {
    ushort8v v = *(const ushort8v*)(yp + h * 8);
#pragma unroll
    for (int i = 0; i < 8; ++i) {
      int oc = q * 16 + h * 8 + i;
      float f = fmaxf(fmaf(bf2f(v[i]), scale[o0 + oc], shift[o0 + oc]), 0.f);
      t[oc][r] = f;
    }
  }
  __syncthreads();
  float* op = out + ((size_t)b * 256 + o0 + r) * N + n0 + q * 16;
#pragma unroll
  for (int i = 0; i < 4; ++i) {
    float4 v = make_float4(t[r][q * 16 + i * 4 + 0], t[r][q * 16 + i * 4 + 1],
                           t[r][q * 16 + i * 4 + 2], t[r][q * 16 + i * 4 + 3]);
    *(float4*)(op + i * 4) = v;
  }
}

extern "C" void kernel_launch(void* const* d_in, const int* in_sizes, int n_in,
                              void* d_out, int out_size, void* d_ws, size_t ws_size,
                              hipStream_t stream) {
  const float* xyz1 = (const float*)d_in[0];
  const float* xyz2 = (const float*)d_in[1];
  const float* points1 = (const float*)d_in[2];
  const float* points2 = (const float*)d_in[3];
  const float* w0 = (const float*)d_in[4];
  const float* b0 = (const float*)d_in[5];
  const float* g0 = (const float*)d_in[6];
  const float* be0 = (const float*)d_in[7];
  const float* w1 = (const float*)d_in[8];
  const float* b1 = (const float*)d_in[9];
  const float* g1 = (const float*)d_in[10];
  const float* be1 = (const float*)d_in[11];
  float* out = (float*)d_out;

  char* ws = (char*)d_ws;
  float* scale0 = (float*)ws;          ws += 256 * 4;
  float* shift0 = (float*)ws;          ws += 256 * 4;
  float* scale1 = (float*)ws;          ws += 256 * 4;
  float* shift1 = (float*)ws;          ws += 256 * 4;
  float* psum = (float*)ws;            ws += (size_t)C * NSLOT * 4;    // 1MB
  float* psumsq = (float*)ws;          ws += (size_t)C * NSLOT * 4;    // 1MB
  unsigned short* w0b = (unsigned short*)ws;  ws += (size_t)C * CIN * 2;   // 256KB
  unsigned short* w1b = (unsigned short*)ws;  ws += (size_t)C * C * 2;     // 128KB
  unsigned short* p2t = (unsigned short*)ws;  ws += (size_t)B * S * 256 * 2;   // 8MB
  unsigned short* Xb = (unsigned short*)ws;   ws += (size_t)B * N * 512 * 2;   // 64MB
  unsigned short* Yb = (unsigned short*)ws;   ws += (size_t)B * N * 256 * 2;   // 32MB
  unsigned short* Zb = Xb;  // gemm1 output reuses Xb (dead after gemm0)

  prep_kernel<<<dim3(4096 + 1024 + 768), 256, 0, stream>>>(points1, points2, w0, w1,
                                                           Xb, p2t, w0b, w1b);
  nn3_kernel<<<dim3(B * N / 32), 256, 0, stream>>>(xyz1, xyz2, p2t, Xb);
  gemm_kernel<<<dim3(N / 128, 2, B), 256, 0, stream>>>(Xb, w0b, b0, Yb, psum, psumsq, CIN);
  bnparam_kernel<<<dim3(C), 256, 0, stream>>>(psum, psumsq, g0, be0, scale0, shift0);
  gemm_bn_kernel<<<dim3(N / 128, 2, B), 256, 0, stream>>>(Yb, w1b, b1, scale0, shift0,
                                                          Zb, psum, psumsq);
  bnparam_kernel<<<dim3(C), 256, 0, stream>>>(psum, psumsq, g1, be1, scale1, shift1);
  bnreluT_kernel<<<dim3(N / 64, 4, B), 256, 0, stream>>>(Zb, scale1, shift1, out);
}

// Round 17
// 186.574 us; speedup vs baseline: 4.1555x; 1.0043x over previous
//
#include <hip/hip_runtime.h>
#include <math.h>

#define B 8
#define N 8192
#define S 2048
#define SCH 1024  // points per LDS chunk
#define C 256
#define CIN 512
#define CNT (B * N)  // 65536
#define NSLOT 1024   // (b*64 + bx)*2 + wn

typedef unsigned long long ull;
typedef __attribute__((ext_vector_type(8))) short bf16x8;
typedef __attribute__((ext_vector_type(4))) float floatx4;
typedef __attribute__((ext_vector_type(8))) unsigned short ushort8v;
typedef __attribute__((ext_vector_type(4))) unsigned short ushort4v;

__device__ inline unsigned short f2bf(float f) {
  unsigned u = __builtin_bit_cast(unsigned, f);
  u += 0x7FFF + ((u >> 16) & 1);  // RNE
  return (unsigned short)(u >> 16);
}
__device__ inline float bf2f(unsigned short h) {
  unsigned u = ((unsigned)h) << 16;
  return __builtin_bit_cast(float, u);
}

__device__ inline void load_lds16(const void* g, void* l) {
  __builtin_amdgcn_global_load_lds(
      (const __attribute__((address_space(1))) unsigned int*)g,
      (__attribute__((address_space(3))) unsigned int*)l, 16, 0, 0);
}

// ---------------- 3-NN v17: v15 two-phase + co-dispatched points1 tconv ----------------
// Blocks [0,2048): nn3 (VALU-bound, HBM 13%). Blocks [2048,6144): points1
// transpose-convert (memory-bound) riding along — the scheduler overlaps the
// two pipes (m114). Disjoint Xb column ranges -> no race. tconv reuses sp as
// an unpadded stride-64 tile (4-way LDS conflict, hidden under memory).
__device__ inline void ins3u(ull k, ull& k0, ull& k1, ull& k2) {
  if (k < k2) {
    if (k < k1) {
      k2 = k1;
      if (k < k0) { k1 = k0; k0 = k; } else k1 = k;
    } else k2 = k;
  }
}

__device__ inline void insf(float k, float& m0, float& m1, float& m2) {
  float n1 = __builtin_amdgcn_fmed3f(k, m0, m1);
  float n2 = __builtin_amdgcn_fmed3f(k, m1, m2);
  m0 = fminf(k, m0);
  m1 = n1;
  m2 = n2;
}

__device__ inline unsigned sortkey(float f) {
  unsigned u = __float_as_uint(f);
  return u ^ (((unsigned)((int)u >> 31)) | 0x80000000u);
}
__device__ inline float unsortkey(unsigned u) {
  unsigned m = ((int)u < 0) ? 0x80000000u : 0xFFFFFFFFu;
  return __uint_as_float(u ^ m);
}

#define QDECL(q)                                                            \
  float d0_##q = INFINITY, d1_##q = INFINITY, d2_##q = INFINITY;            \
  float qx_##q, qy_##q, qz_##q, q2_##q;

#define QLOAD(q)                                                            \
  {                                                                         \
    float ox = p1[nq + q], oy = p1[N + nq + q], oz = p1[2 * N + nq + q];    \
    q2_##q = ox * ox + oy * oy + oz * oz;                                   \
    qx_##q = -2.0f * ox; qy_##q = -2.0f * oy; qz_##q = -2.0f * oz;          \
  }

#define QINSD(q)                                                            \
  {                                                                         \
    float d = fmaf(qx_##q, pc.x, fmaf(qy_##q, pc.y, fmaf(qz_##q, pc.z, pc.w))); \
    float n1 = __builtin_amdgcn_fmed3f(d, d0_##q, d1_##q);                  \
    float n2 = __builtin_amdgcn_fmed3f(d, d1_##q, d2_##q);                  \
    d0_##q = fminf(d, d0_##q);                                              \
    d1_##q = n1;                                                            \
    d2_##q = n2;                                                            \
  }

__global__ __launch_bounds__(256, 4) void nn3_kernel(const float* __restrict__ xyz1,
                                                     const float* __restrict__ xyz2,
                                                     const unsigned short* __restrict__ p2t,
                                                     const float* __restrict__ points1,
                                                     unsigned short* __restrict__ Xb) {
  __shared__ float4 sp[SCH];  // 16KB staging; aliased by tconv tile & merges
  __shared__ float t2q[32];
  __shared__ int ccnt[32];
  __shared__ float cand_d[32][8];
  __shared__ int cand_s[32][8];
  __shared__ int sidx[32][3];
  __shared__ float swt[32][3];
  int tid = threadIdx.x;

  if (blockIdx.x >= 2048) {
    // ---- co-dispatched points1 tconv: [b][256][N] f32 -> Xb[b][n][0:256] bf16 ----
    int id = blockIdx.x - 2048;  // [0,4096)
    int bx = id & 127, by = (id >> 7) & 3, bz = id >> 9;
    int n0 = bx * 64, c0 = by * 64;
    float* t = (float*)sp;  // [64][64] stride-64, exactly 16KB
    int r = tid >> 2, q = tid & 3;
    const float* srcp = points1 + ((size_t)bz * 256 + c0 + r) * N + n0 + q * 16;
#pragma unroll
    for (int i = 0; i < 4; ++i) {
      float4 v = *(const float4*)(srcp + i * 4);
      t[r * 64 + q * 16 + i * 4 + 0] = v.x;
      t[r * 64 + q * 16 + i * 4 + 1] = v.y;
      t[r * 64 + q * 16 + i * 4 + 2] = v.z;
      t[r * 64 + q * 16 + i * 4 + 3] = v.w;
    }
    __syncthreads();
    unsigned short* dp = Xb + ((size_t)bz * N + n0 + r) * 512 + c0 + q * 16;
    ushort8v o0, o1;
#pragma unroll
    for (int i = 0; i < 8; ++i) o0[i] = f2bf(t[(q * 16 + i) * 64 + r]);
#pragma unroll
    for (int i = 0; i < 8; ++i) o1[i] = f2bf(t[(q * 16 + 8 + i) * 64 + r]);
    *(ushort8v*)dp = o0;
    *(ushort8v*)(dp + 8) = o1;
    return;
  }

  int b = blockIdx.x >> 8;            // nn3: 2048 blocks
  int n0 = (blockIdx.x & 255) * 32;
  const float* p2 = xyz2 + (size_t)b * 3 * S;
  int sub = tid & 15, grp = tid >> 4;  // 16 grps x 2 queries = 32 queries/block
  const float* p1 = xyz1 + (size_t)b * 3 * N;
  int nq = n0 + grp * 2;
  QDECL(0) QDECL(1)
  QLOAD(0) QLOAD(1)

  // ---- phase 1: d-only scan over 2 chunks ----
  for (int ch = 0; ch < 2; ++ch) {
    if (ch) __syncthreads();
    for (int i = tid; i < SCH; i += 256) {
      int g = ch * SCH + i;
      float px = p2[g], py = p2[S + g], pz = p2[2 * S + g];
      sp[i] = make_float4(px, py, pz, px * px + py * py + pz * pz);
    }
    __syncthreads();
    const float4* spp = sp + sub;
    float4 pc = spp[0];
    for (int t = 0; t < SCH / 16 - 1; ++t) {
      float4 pn = spp[(t + 1) * 16];
      QINSD(0) QINSD(1)
      pc = pn;
    }
    QINSD(0) QINSD(1)
  }

  // ---- merge per-sub top-3 distances -> per-query 3rd-best threshold ----
  __syncthreads();
  float* tm = (float*)sp;  // [32 queries][16 subs][3] floats (6KB)
  tm[((grp * 2 + 0) * 16 + sub) * 3 + 0] = d0_0;
  tm[((grp * 2 + 0) * 16 + sub) * 3 + 1] = d1_0;
  tm[((grp * 2 + 0) * 16 + sub) * 3 + 2] = d2_0;
  tm[((grp * 2 + 1) * 16 + sub) * 3 + 0] = d0_1;
  tm[((grp * 2 + 1) * 16 + sub) * 3 + 1] = d1_1;
  tm[((grp * 2 + 1) * 16 + sub) * 3 + 2] = d2_1;
  if (tid < 32) ccnt[tid] = 0;
  __syncthreads();
  if (sub < 4) {
#pragma unroll
    for (int q = 0; q < 2; ++q) {
      int qi = grp * 2 + q;
      float m0 = INFINITY, m1 = INFINITY, m2 = INFINITY;
#pragma unroll
      for (int jj = 0; jj < 4; ++jj) {
        int ss = sub + 4 * jj;
        insf(tm[(qi * 16 + ss) * 3 + 0], m0, m1, m2);
        insf(tm[(qi * 16 + ss) * 3 + 1], m0, m1, m2);
        insf(tm[(qi * 16 + ss) * 3 + 2], m0, m1, m2);
      }
#pragma unroll
      for (int mm = 1; mm <= 2; mm <<= 1) {
        float e0 = __shfl_xor(m0, mm);
        float e1 = __shfl_xor(m1, mm);
        float e2 = __shfl_xor(m2, mm);
        insf(e0, m0, m1, m2);
        insf(e1, m0, m1, m2);
        insf(e2, m0, m1, m2);
      }
      if (sub == 0) t2q[qi] = m2;
    }
  }
  __syncthreads();
  float t2_0 = t2q[grp * 2], t2_1 = t2q[grp * 2 + 1];

  // ---- phase 2: rescan with threshold, collect candidates ----
  for (int ch = 0; ch < 2; ++ch) {
    if (ch) __syncthreads();
    for (int i = tid; i < SCH; i += 256) {
      int g = ch * SCH + i;
      float px = p2[g], py = p2[S + g], pz = p2[2 * S + g];
      sp[i] = make_float4(px, py, pz, px * px + py * py + pz * pz);
    }
    __syncthreads();
    const float4* spp = sp + sub;
    for (int t = 0; t < SCH / 16; ++t) {
      float4 pc = spp[t * 16];
      int s = ch * SCH + t * 16 + sub;
      {
        float d = fmaf(qx_0, pc.x, fmaf(qy_0, pc.y, fmaf(qz_0, pc.z, pc.w)));
        if (d <= t2_0) {
          int sl = atomicAdd(&ccnt[grp * 2], 1);
          if (sl < 8) { cand_d[grp * 2][sl] = d; cand_s[grp * 2][sl] = s; }
        }
      }
      {
        float d = fmaf(qx_1, pc.x, fmaf(qy_1, pc.y, fmaf(qz_1, pc.z, pc.w)));
        if (d <= t2_1) {
          int sl = atomicAdd(&ccnt[grp * 2 + 1], 1);
          if (sl < 8) { cand_d[grp * 2 + 1][sl] = d; cand_s[grp * 2 + 1][sl] = s; }
        }
      }
    }
  }
  __syncthreads();

  // ---- select 3 smallest (d, s) lexicographic + weights ----
  if (sub == 0) {
#pragma unroll
    for (int q = 0; q < 2; ++q) {
      int qi = grp * 2 + q;
      int n = min(ccnt[qi], 8);
      ull k0 = ~0ull, k1 = ~0ull, k2 = ~0ull;
      for (int i = 0; i < n; ++i) {
        ull k = ((ull)sortkey(cand_d[qi][i]) << 32) | (unsigned)cand_s[qi][i];
        ins3u(k, k0, k1, k2);
      }
      float q2v = q ? q2_1 : q2_0;
      float e0 = fmaxf(unsortkey((unsigned)(k0 >> 32)) + q2v, 0.0f);
      float e1 = fmaxf(unsortkey((unsigned)(k1 >> 32)) + q2v, 0.0f);
      float e2 = fmaxf(unsortkey((unsigned)(k2 >> 32)) + q2v, 0.0f);
      float r0 = 1.0f / (e0 + 1e-8f);
      float r1 = 1.0f / (e1 + 1e-8f);
      float r2 = 1.0f / (e2 + 1e-8f);
      float rs = 1.0f / (r0 + r1 + r2);
      sidx[qi][0] = (int)(unsigned)k0;
      sidx[qi][1] = (int)(unsigned)k1;
      sidx[qi][2] = (int)(unsigned)k2;
      swt[qi][0] = r0 * rs;
      swt[qi][1] = r1 * rs;
      swt[qi][2] = r2 * rs;
    }
  }
  __syncthreads();

  // ---- fused gather tail: 8 threads per query, 4 x 16B chunks each ----
  int qi = tid >> 3, cc = tid & 7;
  int j0 = sidx[qi][0], j1 = sidx[qi][1], j2 = sidx[qi][2];
  float w0v = swt[qi][0], w1v = swt[qi][1], w2v = swt[qi][2];
  const unsigned short* pb = p2t + (size_t)b * S * 256;
  const unsigned short* r0p = pb + (size_t)j0 * 256;
  const unsigned short* r1p = pb + (size_t)j1 * 256;
  const unsigned short* r2p = pb + (size_t)j2 * 256;
  unsigned short* xp = Xb + ((size_t)b * N + n0 + qi) * 512 + 256;
#pragma unroll
  for (int h = 0; h < 4; ++h) {
    int co = (cc + h * 8) * 8;
    ushort8v v0 = *(const ushort8v*)(r0p + co);
    ushort8v v1 = *(const ushort8v*)(r1p + co);
    ushort8v v2 = *(const ushort8v*)(r2p + co);
    ushort8v o;
#pragma unroll
    for (int i = 0; i < 8; ++i)
      o[i] = f2bf(w0v * bf2f(v0[i]) + w1v * bf2f(v1[i]) + w2v * bf2f(v2[i]));
    *(ushort8v*)(xp + co) = o;
  }
}

// ---------------- small prep: tconv(points2) + weight convert ----------------
__global__ __launch_bounds__(256) void prep_kernel(const float* __restrict__ points2,
                                                   const float* __restrict__ w0,
                                                   const float* __restrict__ w1,
                                                   unsigned short* __restrict__ p2t,
                                                   unsigned short* __restrict__ w0b,
                                                   unsigned short* __restrict__ w1b) {
  __shared__ float t[64][65];
  int id = blockIdx.x;
  if (id < 1024) {  // points2 -> p2t [b][s][256]
    int bx = id & 31, by = (id >> 5) & 3, bz = id >> 7;
    int n0 = bx * 64, c0 = by * 64;
    int tid = threadIdx.x, r = tid >> 2, q = tid & 3;
    const float* sp = points2 + ((size_t)bz * 256 + c0 + r) * S + n0 + q * 16;
#pragma unroll
    for (int i = 0; i < 4; ++i) {
      float4 v = *(const float4*)(sp + i * 4);
      t[r][q * 16 + i * 4 + 0] = v.x;
      t[r][q * 16 + i * 4 + 1] = v.y;
      t[r][q * 16 + i * 4 + 2] = v.z;
      t[r][q * 16 + i * 4 + 3] = v.w;
    }
    __syncthreads();
    unsigned short* dp = p2t + ((size_t)bz * S + n0 + r) * 256 + c0 + q * 16;
    ushort8v o0, o1;
#pragma unroll
    for (int i = 0; i < 8; ++i) o0[i] = f2bf(t[q * 16 + i][r]);
#pragma unroll
    for (int i = 0; i < 8; ++i) o1[i] = f2bf(t[q * 16 + 8 + i][r]);
    *(ushort8v*)dp = o0;
    *(ushort8v*)(dp + 8) = o1;
  } else {  // weights
    int i = (id - 1024) * 256 + threadIdx.x;
    if (i < C * CIN) w0b[i] = f2bf(w0[i]);
    else {
      int j = i - C * CIN;
      if (j < C * C) w1b[j] = f2bf(w1[j]);
    }
  }
}

// ---------------- bf16 MFMA GEMM, BK=64 + channel-major partial stats ----------------
__global__ __launch_bounds__(256) void gemm_kernel(const unsigned short* __restrict__ X,
                                                   const unsigned short* __restrict__ Wb,
                                                   const float* __restrict__ bias,
                                                   unsigned short* __restrict__ Y,
                                                   float* __restrict__ psum,
                                                   float* __restrict__ psumsq,
                                                   int Cin) {
  __shared__ unsigned short As[128 * 64];  // [o_row][k] 16KB, swizzled
  __shared__ unsigned short Bs[128 * 64];  // [n_row][k] 16KB, swizzled
  int n0 = blockIdx.x * 128, o0 = blockIdx.y * 128, b = blockIdx.z;
  int tid = threadIdx.x, lane = tid & 63, wid = tid >> 6;
  int wm = wid >> 1, wn = wid & 1;
  floatx4 acc[4][4];
#pragma unroll
  for (int m = 0; m < 4; ++m)
#pragma unroll
    for (int nt = 0; nt < 4; ++nt) acc[m][nt] = (floatx4)(0.0f);

  size_t rsA = (size_t)Cin * 2;  // row stride bytes
  int chunkSwz = ((lane & 7) ^ ((lane >> 3) & 7)) * 16;
  const char* Abase = (const char*)Wb + (size_t)(o0 + wid * 32 + (lane >> 3)) * rsA + chunkSwz;
  const char* Bbase = (const char*)X + ((size_t)b * N + n0 + wid * 32 + (lane >> 3)) * rsA + chunkSwz;
  size_t rstep8 = 8 * rsA;
  int fr = lane & 15;
  int cbase = lane >> 4;   // 0..3
  int rswz = lane & 7;     // row&7 for this lane's fragment reads

  for (int k0 = 0; k0 < Cin; k0 += 64) {
#pragma unroll
    for (int l = 0; l < 4; ++l) {
      load_lds16(Abase + (size_t)k0 * 2 + (size_t)l * rstep8, &As[(wid * 32 + l * 8) * 64]);
      load_lds16(Bbase + (size_t)k0 * 2 + (size_t)l * rstep8, &Bs[(wid * 32 + l * 8) * 64]);
    }
    __syncthreads();
#pragma unroll
    for (int kk = 0; kk < 2; ++kk) {
      int chunk = (cbase + kk * 4) ^ rswz;
      bf16x8 af[4], bfv[4];
#pragma unroll
      for (int m = 0; m < 4; ++m)
        af[m] = *(const bf16x8*)&As[(wm * 64 + m * 16 + fr) * 64 + chunk * 8];
#pragma unroll
      for (int nt = 0; nt < 4; ++nt)
        bfv[nt] = *(const bf16x8*)&Bs[(wn * 64 + nt * 16 + fr) * 64 + chunk * 8];
#pragma unroll
      for (int m = 0; m < 4; ++m)
#pragma unroll
        for (int nt = 0; nt < 4; ++nt)
          acc[m][nt] = __builtin_amdgcn_mfma_f32_16x16x32_bf16(af[m], bfv[nt], acc[m][nt], 0, 0, 0);
    }
    __syncthreads();
  }

  int col = lane & 15, rowq = lane >> 4;
  int slot = ((b * 64 + blockIdx.x) * 2) + wn;
#pragma unroll
  for (int m = 0; m < 4; ++m) {
    int ob = o0 + wm * 64 + m * 16 + rowq * 4;
    float4 bs = *(const float4*)&bias[ob];
    float sj[4] = {0.f, 0.f, 0.f, 0.f}, qj[4] = {0.f, 0.f, 0.f, 0.f};
#pragma unroll
    for (int nt = 0; nt < 4; ++nt) {
      int n = n0 + wn * 64 + nt * 16 + col;
      float y0 = acc[m][nt][0] + bs.x;
      float y1 = acc[m][nt][1] + bs.y;
      float y2 = acc[m][nt][2] + bs.z;
      float y3 = acc[m][nt][3] + bs.w;
      ushort4v v;
      v[0] = f2bf(y0); v[1] = f2bf(y1); v[2] = f2bf(y2); v[3] = f2bf(y3);
      *(ushort4v*)&Y[((size_t)b * N + n) * 256 + ob] = v;
      sj[0] += y0; qj[0] = fmaf(y0, y0, qj[0]);
      sj[1] += y1; qj[1] = fmaf(y1, y1, qj[1]);
      sj[2] += y2; qj[2] = fmaf(y2, y2, qj[2]);
      sj[3] += y3; qj[3] = fmaf(y3, y3, qj[3]);
    }
#pragma unroll
    for (int j = 0; j < 4; ++j) {
#pragma unroll
      for (int d = 1; d <= 8; d <<= 1) {
        sj[j] += __shfl_xor(sj[j], d);
        qj[j] += __shfl_xor(qj[j], d);
      }
    }
    if (col == 0) {
      int c0 = blockIdx.y * 128 + wm * 64 + m * 16 + rowq * 4;
#pragma unroll
      for (int j = 0; j < 4; ++j) {
        psum[(size_t)(c0 + j) * NSLOT + slot] = sj[j];
        psumsq[(size_t)(c0 + j) * NSLOT + slot] = qj[j];
      }
    }
  }
}

// ---------------- gemm1 with fused input BN+ReLU (reg-staged B side) ----------------
__global__ __launch_bounds__(256) void gemm_bn_kernel(const unsigned short* __restrict__ X,
                                                      const unsigned short* __restrict__ Wb,
                                                      const float* __restrict__ bias,
                                                      const float* __restrict__ scale,
                                                      const float* __restrict__ shift,
                                                      unsigned short* __restrict__ Y,
                                                      float* __restrict__ psum,
                                                      float* __restrict__ psumsq) {
  const int Cin = C;  // 256
  __shared__ unsigned short As[128 * 64];  // 16KB, swizzled
  __shared__ unsigned short Bs[128 * 64];  // 16KB, swizzled
  __shared__ float sscale[256], sshift[256];
  int n0 = blockIdx.x * 128, o0 = blockIdx.y * 128, b = blockIdx.z;
  int tid = threadIdx.x, lane = tid & 63, wid = tid >> 6;
  int wm = wid >> 1, wn = wid & 1;
  sscale[tid] = scale[tid];
  sshift[tid] = shift[tid];
  floatx4 acc[4][4];
#pragma unroll
  for (int m = 0; m < 4; ++m)
#pragma unroll
    for (int nt = 0; nt < 4; ++nt) acc[m][nt] = (floatx4)(0.0f);

  size_t rsA = (size_t)Cin * 2;
  int cg = (lane & 7) ^ ((lane >> 3) & 7);  // this lane's GLOBAL chunk index
  int chunkSwz = cg * 16;
  const char* Abase = (const char*)Wb + (size_t)(o0 + wid * 32 + (lane >> 3)) * rsA + chunkSwz;
  const char* Bbase = (const char*)X + ((size_t)b * N + n0 + wid * 32 + (lane >> 3)) * rsA + chunkSwz;
  size_t rstep8 = 8 * rsA;
  int fr = lane & 15;
  int cbase = lane >> 4;
  int rswz = lane & 7;
  __syncthreads();  // sscale/sshift visible before first staging use

  for (int k0 = 0; k0 < Cin; k0 += 64) {
    int kb = k0 + cg * 8;
    float4 sc0 = *(const float4*)&sscale[kb];
    float4 sc1 = *(const float4*)&sscale[kb + 4];
    float4 sh0 = *(const float4*)&sshift[kb];
    float4 sh1 = *(const float4*)&sshift[kb + 4];
#pragma unroll
    for (int l = 0; l < 4; ++l) {
      load_lds16(Abase + (size_t)k0 * 2 + (size_t)l * rstep8, &As[(wid * 32 + l * 8) * 64]);
      ushort8v raw = *(const ushort8v*)(Bbase + (size_t)k0 * 2 + (size_t)l * rstep8);
      ushort8v tv;
      tv[0] = f2bf(fmaxf(fmaf(bf2f(raw[0]), sc0.x, sh0.x), 0.f));
      tv[1] = f2bf(fmaxf(fmaf(bf2f(raw[1]), sc0.y, sh0.y), 0.f));
      tv[2] = f2bf(fmaxf(fmaf(bf2f(raw[2]), sc0.z, sh0.z), 0.f));
      tv[3] = f2bf(fmaxf(fmaf(bf2f(raw[3]), sc0.w, sh0.w), 0.f));
      tv[4] = f2bf(fmaxf(fmaf(bf2f(raw[4]), sc1.x, sh1.x), 0.f));
      tv[5] = f2bf(fmaxf(fmaf(bf2f(raw[5]), sc1.y, sh1.y), 0.f));
      tv[6] = f2bf(fmaxf(fmaf(bf2f(raw[6]), sc1.z, sh1.z), 0.f));
      tv[7] = f2bf(fmaxf(fmaf(bf2f(raw[7]), sc1.w, sh1.w), 0.f));
      *(ushort8v*)&Bs[(wid * 32 + l * 8) * 64 + lane * 8] = tv;
    }
    __syncthreads();
#pragma unroll
    for (int kk = 0; kk < 2; ++kk) {
      int chunk = (cbase + kk * 4) ^ rswz;
      bf16x8 af[4], bfv[4];
#pragma unroll
      for (int m = 0; m < 4; ++m)
        af[m] = *(const bf16x8*)&As[(wm * 64 + m * 16 + fr) * 64 + chunk * 8];
#pragma unroll
      for (int nt = 0; nt < 4; ++nt)
        bfv[nt] = *(const bf16x8*)&Bs[(wn * 64 + nt * 16 + fr) * 64 + chunk * 8];
#pragma unroll
      for (int m = 0; m < 4; ++m)
#pragma unroll
        for (int nt = 0; nt < 4; ++nt)
          acc[m][nt] = __builtin_amdgcn_mfma_f32_16x16x32_bf16(af[m], bfv[nt], acc[m][nt], 0, 0, 0);
    }
    __syncthreads();
  }

  int col = lane & 15, rowq = lane >> 4;
  int slot = ((b * 64 + blockIdx.x) * 2) + wn;
#pragma unroll
  for (int m = 0; m < 4; ++m) {
    int ob = o0 + wm * 64 + m * 16 + rowq * 4;
    float4 bs = *(const float4*)&bias[ob];
    float sj[4] = {0.f, 0.f, 0.f, 0.f}, qj[4] = {0.f, 0.f, 0.f, 0.f};
#pragma unroll
    for (int nt = 0; nt < 4; ++nt) {
      int n = n0 + wn * 64 + nt * 16 + col;
      float y0 = acc[m][nt][0] + bs.x;
      float y1 = acc[m][nt][1] + bs.y;
      float y2 = acc[m][nt][2] + bs.z;
      float y3 = acc[m][nt][3] + bs.w;
      ushort4v v;
      v[0] = f2bf(y0); v[1] = f2bf(y1); v[2] = f2bf(y2); v[3] = f2bf(y3);
      *(ushort4v*)&Y[((size_t)b * N + n) * 256 + ob] = v;
      sj[0] += y0; qj[0] = fmaf(y0, y0, qj[0]);
      sj[1] += y1; qj[1] = fmaf(y1, y1, qj[1]);
      sj[2] += y2; qj[2] = fmaf(y2, y2, qj[2]);
      sj[3] += y3; qj[3] = fmaf(y3, y3, qj[3]);
    }
#pragma unroll
    for (int j = 0; j < 4; ++j) {
#pragma unroll
      for (int d = 1; d <= 8; d <<= 1) {
        sj[j] += __shfl_xor(sj[j], d);
        qj[j] += __shfl_xor(qj[j], d);
      }
    }
    if (col == 0) {
      int c0 = blockIdx.y * 128 + wm * 64 + m * 16 + rowq * 4;
#pragma unroll
      for (int j = 0; j < 4; ++j) {
        psum[(size_t)(c0 + j) * NSLOT + slot] = sj[j];
        psumsq[(size_t)(c0 + j) * NSLOT + slot] = qj[j];
      }
    }
  }
}

// ---------------- parallel reduce partials -> BN scale/shift (256 blocks) ----------------
__global__ __launch_bounds__(256) void bnparam_kernel(const float* __restrict__ psum,
                                                      const float* __restrict__ psumsq,
                                                      const float* __restrict__ gamma,
                                                      const float* __restrict__ beta,
                                                      float* __restrict__ scale,
                                                      float* __restrict__ shift) {
  int c = blockIdx.x, tid = threadIdx.x;
  const float* ps = psum + (size_t)c * NSLOT;
  const float* pq = psumsq + (size_t)c * NSLOT;
  float s = 0.f, q = 0.f;
#pragma unroll
  for (int i = 0; i < NSLOT / 256; ++i) {
    s += ps[tid + i * 256];
    q += pq[tid + i * 256];
  }
#pragma unroll
  for (int d = 1; d <= 32; d <<= 1) {
    s += __shfl_xor(s, d);
    q += __shfl_xor(q, d);
  }
  __shared__ float ls[4], lq[4];
  int wid = tid >> 6;
  if ((tid & 63) == 0) { ls[wid] = s; lq[wid] = q; }
  __syncthreads();
  if (tid == 0) {
    s = ls[0] + ls[1] + ls[2] + ls[3];
    q = lq[0] + lq[1] + lq[2] + lq[3];
    float m = s * (1.0f / CNT);
    float v = q * (1.0f / CNT) - m * m;
    float sc = gamma[c] * rsqrtf(v + 1e-5f);
    scale[c] = sc;
    shift[c] = beta[c] - m * sc;
  }
}

// ---------------- final: BN+ReLU + transpose [b][n][o] bf16 -> out [b][o][n] f32 ----------------
__global__ __launch_bounds__(256) void bnreluT_kernel(const unsigned short* __restrict__ Y,
                                                      const float* __restrict__ scale,
                                                      const float* __restrict__ shift,
                                                      float* __restrict__ out) {
  __shared__ float t[64][65];
  int n0 = blockIdx.x * 64, o0 = blockIdx.y * 64, b = blockIdx.z;
  int tid = threadIdx.x, r = tid >> 2, q = tid & 3;
  const unsigned short* yp = Y + ((size_t)b * N + n0 + r) * 256 + o0 + q * 16;
#pragma unroll
  for (int h = 0; h < 2; ++h) {
    ushort8v v = *(const ushort8v*)(yp + h * 8);
#pragma unroll
    for (int i = 0; i < 8; ++i) {
      int oc = q * 16 + h * 8 + i;
      float f = fmaxf(fmaf(bf2f(v[i]), scale[o0 + oc], shift[o0 + oc]), 0.f);
      t[oc][r] = f;
    }
  }
  __syncthreads();
  float* op = out + ((size_t)b * 256 + o0 + r) * N + n0 + q * 16;
#pragma unroll
  for (int i = 0; i < 4; ++i) {
    float4 v = make_float4(t[r][q * 16 + i * 4 + 0], t[r][q * 16 + i * 4 + 1],
                           t[r][q * 16 + i * 4 + 2], t[r][q * 16 + i * 4 + 3]);
    *(float4*)(op + i * 4) = v;
  }
}

extern "C" void kernel_launch(void* const* d_in, const int* in_sizes, int n_in,
                              void* d_out, int out_size, void* d_ws, size_t ws_size,
                              hipStream_t stream) {
  const float* xyz1 = (const float*)d_in[0];
  const float* xyz2 = (const float*)d_in[1];
  const float* points1 = (const float*)d_in[2];
  const float* points2 = (const float*)d_in[3];
  const float* w0 = (const float*)d_in[4];
  const float* b0 = (const float*)d_in[5];
  const float* g0 = (const float*)d_in[6];
  const float* be0 = (const float*)d_in[7];
  const float* w1 = (const float*)d_in[8];
  const float* b1 = (const float*)d_in[9];
  const float* g1 = (const float*)d_in[10];
  const float* be1 = (const float*)d_in[11];
  float* out = (float*)d_out;

  char* ws = (char*)d_ws;
  float* scale0 = (float*)ws;          ws += 256 * 4;
  float* shift0 = (float*)ws;          ws += 256 * 4;
  float* scale1 = (float*)ws;          ws += 256 * 4;
  float* shift1 = (float*)ws;          ws += 256 * 4;
  float* psum = (float*)ws;            ws += (size_t)C * NSLOT * 4;    // 1MB
  float* psumsq = (float*)ws;          ws += (size_t)C * NSLOT * 4;    // 1MB
  unsigned short* w0b = (unsigned short*)ws;  ws += (size_t)C * CIN * 2;   // 256KB
  unsigned short* w1b = (unsigned short*)ws;  ws += (size_t)C * C * 2;     // 128KB
  unsigned short* p2t = (unsigned short*)ws;  ws += (size_t)B * S * 256 * 2;   // 8MB
  unsigned short* Xb = (unsigned short*)ws;   ws += (size_t)B * N * 512 * 2;   // 64MB
  unsigned short* Yb = (unsigned short*)ws;   ws += (size_t)B * N * 256 * 2;   // 32MB
  unsigned short* Zb = Xb;  // gemm1 output reuses Xb (dead after gemm0)

  prep_kernel<<<dim3(1024 + 768), 256, 0, stream>>>(points2, w0, w1, p2t, w0b, w1b);
  nn3_kernel<<<dim3(2048 + 4096), 256, 0, stream>>>(xyz1, xyz2, p2t, points1, Xb);
  gemm_kernel<<<dim3(N / 128, 2, B), 256, 0, stream>>>(Xb, w0b, b0, Yb, psum, psumsq, CIN);
  bnparam_kernel<<<dim3(C), 256, 0, stream>>>(psum, psumsq, g0, be0, scale0, shift0);
  gemm_bn_kernel<<<dim3(N / 128, 2, B), 256, 0, stream>>>(Yb, w1b, b1, scale0, shift0,
                                                          Zb, psum, psumsq);
  bnparam_kernel<<<dim3(C), 256, 0, stream>>>(psum, psumsq, g1, be1, scale1, shift1);
  bnreluT_kernel<<<dim3(N / 64, 4, B), 256, 0, stream>>>(Zb, scale1, shift1, out);
}

// Round 18
// 183.987 us; speedup vs baseline: 4.2140x; 1.0141x over previous
//
#include <hip/hip_runtime.h>
#include <math.h>

#define B 8
#define N 8192
#define S 2048
#define SCH 1024  // points per LDS chunk
#define C 256
#define CIN 512
#define CNT (B * N)  // 65536
#define NSLOT 1024   // (b*64 + bx)*2 + wn

typedef unsigned long long ull;
typedef __attribute__((ext_vector_type(8))) short bf16x8;
typedef __attribute__((ext_vector_type(4))) float floatx4;
typedef __attribute__((ext_vector_type(8))) unsigned short ushort8v;
typedef __attribute__((ext_vector_type(4))) unsigned short ushort4v;

__device__ inline unsigned short f2bf(float f) {
  unsigned u = __builtin_bit_cast(unsigned, f);
  u += 0x7FFF + ((u >> 16) & 1);  // RNE
  return (unsigned short)(u >> 16);
}
__device__ inline float bf2f(unsigned short h) {
  unsigned u = ((unsigned)h) << 16;
  return __builtin_bit_cast(float, u);
}

__device__ inline void load_lds16(const void* g, void* l) {
  __builtin_amdgcn_global_load_lds(
      (const __attribute__((address_space(1))) unsigned int*)g,
      (__attribute__((address_space(3))) unsigned int*)l, 16, 0, 0);
}

// ---------------- 3-NN v18: v17 fat kernel + INTERLEAVED block mapping ----------------
// r17 failed to overlap: in-order dispatch ran the 2048 nn3 blocks first, then
// the 4096 tconv blocks (near-serial). Fix: bid%3==0 -> nn3 (bid/3), else ->
// tconv ((bid/3)*2 + bid%3 - 1). Every CU now holds VALU-bound nn3 waves AND
// memory-bound tconv waves simultaneously -> tconv's HBM work hides under
// nn3's ~87%-idle memory pipe (m114 pipe complementarity).
__device__ inline void ins3u(ull k, ull& k0, ull& k1, ull& k2) {
  if (k < k2) {
    if (k < k1) {
      k2 = k1;
      if (k < k0) { k1 = k0; k0 = k; } else k1 = k;
    } else k2 = k;
  }
}

__device__ inline void insf(float k, float& m0, float& m1, float& m2) {
  float n1 = __builtin_amdgcn_fmed3f(k, m0, m1);
  float n2 = __builtin_amdgcn_fmed3f(k, m1, m2);
  m0 = fminf(k, m0);
  m1 = n1;
  m2 = n2;
}

__device__ inline unsigned sortkey(float f) {
  unsigned u = __float_as_uint(f);
  return u ^ (((unsigned)((int)u >> 31)) | 0x80000000u);
}
__device__ inline float unsortkey(unsigned u) {
  unsigned m = ((int)u < 0) ? 0x80000000u : 0xFFFFFFFFu;
  return __uint_as_float(u ^ m);
}

#define QDECL(q)                                                            \
  float d0_##q = INFINITY, d1_##q = INFINITY, d2_##q = INFINITY;            \
  float qx_##q, qy_##q, qz_##q, q2_##q;

#define QLOAD(q)                                                            \
  {                                                                         \
    float ox = p1[nq + q], oy = p1[N + nq + q], oz = p1[2 * N + nq + q];    \
    q2_##q = ox * ox + oy * oy + oz * oz;                                   \
    qx_##q = -2.0f * ox; qy_##q = -2.0f * oy; qz_##q = -2.0f * oz;          \
  }

#define QINSD(q)                                                            \
  {                                                                         \
    float d = fmaf(qx_##q, pc.x, fmaf(qy_##q, pc.y, fmaf(qz_##q, pc.z, pc.w))); \
    float n1 = __builtin_amdgcn_fmed3f(d, d0_##q, d1_##q);                  \
    float n2 = __builtin_amdgcn_fmed3f(d, d1_##q, d2_##q);                  \
    d0_##q = fminf(d, d0_##q);                                              \
    d1_##q = n1;                                                            \
    d2_##q = n2;                                                            \
  }

__global__ __launch_bounds__(256, 4) void nn3_kernel(const float* __restrict__ xyz1,
                                                     const float* __restrict__ xyz2,
                                                     const unsigned short* __restrict__ p2t,
                                                     const float* __restrict__ points1,
                                                     unsigned short* __restrict__ Xb) {
  __shared__ float4 sp[SCH];  // 16KB staging; aliased by tconv tile & merges
  __shared__ float t2q[32];
  __shared__ int ccnt[32];
  __shared__ float cand_d[32][8];
  __shared__ int cand_s[32][8];
  __shared__ int sidx[32][3];
  __shared__ float swt[32][3];
  int tid = threadIdx.x;
  int bid = blockIdx.x;
  int bdiv = bid / 3, bmod = bid - bdiv * 3;

  if (bmod != 0) {
    // ---- co-dispatched points1 tconv: [b][256][N] f32 -> Xb[b][n][0:256] bf16 ----
    int id = bdiv * 2 + bmod - 1;  // [0,4096) bijective
    int bx = id & 127, by = (id >> 7) & 3, bz = id >> 9;
    int n0 = bx * 64, c0 = by * 64;
    float* t = (float*)sp;  // [64][64] stride-64, exactly 16KB
    int r = tid >> 2, q = tid & 3;
    const float* srcp = points1 + ((size_t)bz * 256 + c0 + r) * N + n0 + q * 16;
#pragma unroll
    for (int i = 0; i < 4; ++i) {
      float4 v = *(const float4*)(srcp + i * 4);
      t[r * 64 + q * 16 + i * 4 + 0] = v.x;
      t[r * 64 + q * 16 + i * 4 + 1] = v.y;
      t[r * 64 + q * 16 + i * 4 + 2] = v.z;
      t[r * 64 + q * 16 + i * 4 + 3] = v.w;
    }
    __syncthreads();
    unsigned short* dp = Xb + ((size_t)bz * N + n0 + r) * 512 + c0 + q * 16;
    ushort8v o0, o1;
#pragma unroll
    for (int i = 0; i < 8; ++i) o0[i] = f2bf(t[(q * 16 + i) * 64 + r]);
#pragma unroll
    for (int i = 0; i < 8; ++i) o1[i] = f2bf(t[(q * 16 + 8 + i) * 64 + r]);
    *(ushort8v*)dp = o0;
    *(ushort8v*)(dp + 8) = o1;
    return;
  }

  int nb = bdiv;                      // nn3 block id in [0,2048)
  int b = nb >> 8;
  int n0 = (nb & 255) * 32;
  const float* p2 = xyz2 + (size_t)b * 3 * S;
  int sub = tid & 15, grp = tid >> 4;  // 16 grps x 2 queries = 32 queries/block
  const float* p1 = xyz1 + (size_t)b * 3 * N;
  int nq = n0 + grp * 2;
  QDECL(0) QDECL(1)
  QLOAD(0) QLOAD(1)

  // ---- phase 1: d-only scan over 2 chunks ----
  for (int ch = 0; ch < 2; ++ch) {
    if (ch) __syncthreads();
    for (int i = tid; i < SCH; i += 256) {
      int g = ch * SCH + i;
      float px = p2[g], py = p2[S + g], pz = p2[2 * S + g];
      sp[i] = make_float4(px, py, pz, px * px + py * py + pz * pz);
    }
    __syncthreads();
    const float4* spp = sp + sub;
    float4 pc = spp[0];
    for (int t = 0; t < SCH / 16 - 1; ++t) {
      float4 pn = spp[(t + 1) * 16];
      QINSD(0) QINSD(1)
      pc = pn;
    }
    QINSD(0) QINSD(1)
  }

  // ---- merge per-sub top-3 distances -> per-query 3rd-best threshold ----
  __syncthreads();
  float* tm = (float*)sp;  // [32 queries][16 subs][3] floats (6KB)
  tm[((grp * 2 + 0) * 16 + sub) * 3 + 0] = d0_0;
  tm[((grp * 2 + 0) * 16 + sub) * 3 + 1] = d1_0;
  tm[((grp * 2 + 0) * 16 + sub) * 3 + 2] = d2_0;
  tm[((grp * 2 + 1) * 16 + sub) * 3 + 0] = d0_1;
  tm[((grp * 2 + 1) * 16 + sub) * 3 + 1] = d1_1;
  tm[((grp * 2 + 1) * 16 + sub) * 3 + 2] = d2_1;
  if (tid < 32) ccnt[tid] = 0;
  __syncthreads();
  if (sub < 4) {
#pragma unroll
    for (int q = 0; q < 2; ++q) {
      int qi = grp * 2 + q;
      float m0 = INFINITY, m1 = INFINITY, m2 = INFINITY;
#pragma unroll
      for (int jj = 0; jj < 4; ++jj) {
        int ss = sub + 4 * jj;
        insf(tm[(qi * 16 + ss) * 3 + 0], m0, m1, m2);
        insf(tm[(qi * 16 + ss) * 3 + 1], m0, m1, m2);
        insf(tm[(qi * 16 + ss) * 3 + 2], m0, m1, m2);
      }
#pragma unroll
      for (int mm = 1; mm <= 2; mm <<= 1) {
        float e0 = __shfl_xor(m0, mm);
        float e1 = __shfl_xor(m1, mm);
        float e2 = __shfl_xor(m2, mm);
        insf(e0, m0, m1, m2);
        insf(e1, m0, m1, m2);
        insf(e2, m0, m1, m2);
      }
      if (sub == 0) t2q[qi] = m2;
    }
  }
  __syncthreads();
  float t2_0 = t2q[grp * 2], t2_1 = t2q[grp * 2 + 1];

  // ---- phase 2: rescan with threshold, collect candidates ----
  for (int ch = 0; ch < 2; ++ch) {
    if (ch) __syncthreads();
    for (int i = tid; i < SCH; i += 256) {
      int g = ch * SCH + i;
      float px = p2[g], py = p2[S + g], pz = p2[2 * S + g];
      sp[i] = make_float4(px, py, pz, px * px + py * py + pz * pz);
    }
    __syncthreads();
    const float4* spp = sp + sub;
    for (int t = 0; t < SCH / 16; ++t) {
      float4 pc = spp[t * 16];
      int s = ch * SCH + t * 16 + sub;
      {
        float d = fmaf(qx_0, pc.x, fmaf(qy_0, pc.y, fmaf(qz_0, pc.z, pc.w)));
        if (d <= t2_0) {
          int sl = atomicAdd(&ccnt[grp * 2], 1);
          if (sl < 8) { cand_d[grp * 2][sl] = d; cand_s[grp * 2][sl] = s; }
        }
      }
      {
        float d = fmaf(qx_1, pc.x, fmaf(qy_1, pc.y, fmaf(qz_1, pc.z, pc.w)));
        if (d <= t2_1) {
          int sl = atomicAdd(&ccnt[grp * 2 + 1], 1);
          if (sl < 8) { cand_d[grp * 2 + 1][sl] = d; cand_s[grp * 2 + 1][sl] = s; }
        }
      }
    }
  }
  __syncthreads();

  // ---- select 3 smallest (d, s) lexicographic + weights ----
  if (sub == 0) {
#pragma unroll
    for (int q = 0; q < 2; ++q) {
      int qi = grp * 2 + q;
      int n = min(ccnt[qi], 8);
      ull k0 = ~0ull, k1 = ~0ull, k2 = ~0ull;
      for (int i = 0; i < n; ++i) {
        ull k = ((ull)sortkey(cand_d[qi][i]) << 32) | (unsigned)cand_s[qi][i];
        ins3u(k, k0, k1, k2);
      }
      float q2v = q ? q2_1 : q2_0;
      float e0 = fmaxf(unsortkey((unsigned)(k0 >> 32)) + q2v, 0.0f);
      float e1 = fmaxf(unsortkey((unsigned)(k1 >> 32)) + q2v, 0.0f);
      float e2 = fmaxf(unsortkey((unsigned)(k2 >> 32)) + q2v, 0.0f);
      float r0 = 1.0f / (e0 + 1e-8f);
      float r1 = 1.0f / (e1 + 1e-8f);
      float r2 = 1.0f / (e2 + 1e-8f);
      float rs = 1.0f / (r0 + r1 + r2);
      sidx[qi][0] = (int)(unsigned)k0;
      sidx[qi][1] = (int)(unsigned)k1;
      sidx[qi][2] = (int)(unsigned)k2;
      swt[qi][0] = r0 * rs;
      swt[qi][1] = r1 * rs;
      swt[qi][2] = r2 * rs;
    }
  }
  __syncthreads();

  // ---- fused gather tail: 8 threads per query, 4 x 16B chunks each ----
  int qi = tid >> 3, cc = tid & 7;
  int j0 = sidx[qi][0], j1 = sidx[qi][1], j2 = sidx[qi][2];
  float w0v = swt[qi][0], w1v = swt[qi][1], w2v = swt[qi][2];
  const unsigned short* pb = p2t + (size_t)b * S * 256;
  const unsigned short* r0p = pb + (size_t)j0 * 256;
  const unsigned short* r1p = pb + (size_t)j1 * 256;
  const unsigned short* r2p = pb + (size_t)j2 * 256;
  unsigned short* xp = Xb + ((size_t)b * N + n0 + qi) * 512 + 256;
#pragma unroll
  for (int h = 0; h < 4; ++h) {
    int co = (cc + h * 8) * 8;
    ushort8v v0 = *(const ushort8v*)(r0p + co);
    ushort8v v1 = *(const ushort8v*)(r1p + co);
    ushort8v v2 = *(const ushort8v*)(r2p + co);
    ushort8v o;
#pragma unroll
    for (int i = 0; i < 8; ++i)
      o[i] = f2bf(w0v * bf2f(v0[i]) + w1v * bf2f(v1[i]) + w2v * bf2f(v2[i]));
    *(ushort8v*)(xp + co) = o;
  }
}

// ---------------- small prep: tconv(points2) + weight convert ----------------
__global__ __launch_bounds__(256) void prep_kernel(const float* __restrict__ points2,
                                                   const float* __restrict__ w0,
                                                   const float* __restrict__ w1,
                                                   unsigned short* __restrict__ p2t,
                                                   unsigned short* __restrict__ w0b,
                                                   unsigned short* __restrict__ w1b) {
  __shared__ float t[64][65];
  int id = blockIdx.x;
  if (id < 1024) {  // points2 -> p2t [b][s][256]
    int bx = id & 31, by = (id >> 5) & 3, bz = id >> 7;
    int n0 = bx * 64, c0 = by * 64;
    int tid = threadIdx.x, r = tid >> 2, q = tid & 3;
    const float* sp = points2 + ((size_t)bz * 256 + c0 + r) * S + n0 + q * 16;
#pragma unroll
    for (int i = 0; i < 4; ++i) {
      float4 v = *(const float4*)(sp + i * 4);
      t[r][q * 16 + i * 4 + 0] = v.x;
      t[r][q * 16 + i * 4 + 1] = v.y;
      t[r][q * 16 + i * 4 + 2] = v.z;
      t[r][q * 16 + i * 4 + 3] = v.w;
    }
    __syncthreads();
    unsigned short* dp = p2t + ((size_t)bz * S + n0 + r) * 256 + c0 + q * 16;
    ushort8v o0, o1;
#pragma unroll
    for (int i = 0; i < 8; ++i) o0[i] = f2bf(t[q * 16 + i][r]);
#pragma unroll
    for (int i = 0; i < 8; ++i) o1[i] = f2bf(t[q * 16 + 8 + i][r]);
    *(ushort8v*)dp = o0;
    *(ushort8v*)(dp + 8) = o1;
  } else {  // weights
    int i = (id - 1024) * 256 + threadIdx.x;
    if (i < C * CIN) w0b[i] = f2bf(w0[i]);
    else {
      int j = i - C * CIN;
      if (j < C * C) w1b[j] = f2bf(w1[j]);
    }
  }
}

// ---------------- bf16 MFMA GEMM, BK=64 + channel-major partial stats ----------------
__global__ __launch_bounds__(256) void gemm_kernel(const unsigned short* __restrict__ X,
                                                   const unsigned short* __restrict__ Wb,
                                                   const float* __restrict__ bias,
                                                   unsigned short* __restrict__ Y,
                                                   float* __restrict__ psum,
                                                   float* __restrict__ psumsq,
                                                   int Cin) {
  __shared__ unsigned short As[128 * 64];  // [o_row][k] 16KB, swizzled
  __shared__ unsigned short Bs[128 * 64];  // [n_row][k] 16KB, swizzled
  int n0 = blockIdx.x * 128, o0 = blockIdx.y * 128, b = blockIdx.z;
  int tid = threadIdx.x, lane = tid & 63, wid = tid >> 6;
  int wm = wid >> 1, wn = wid & 1;
  floatx4 acc[4][4];
#pragma unroll
  for (int m = 0; m < 4; ++m)
#pragma unroll
    for (int nt = 0; nt < 4; ++nt) acc[m][nt] = (floatx4)(0.0f);

  size_t rsA = (size_t)Cin * 2;  // row stride bytes
  int chunkSwz = ((lane & 7) ^ ((lane >> 3) & 7)) * 16;
  const char* Abase = (const char*)Wb + (size_t)(o0 + wid * 32 + (lane >> 3)) * rsA + chunkSwz;
  const char* Bbase = (const char*)X + ((size_t)b * N + n0 + wid * 32 + (lane >> 3)) * rsA + chunkSwz;
  size_t rstep8 = 8 * rsA;
  int fr = lane & 15;
  int cbase = lane >> 4;   // 0..3
  int rswz = lane & 7;     // row&7 for this lane's fragment reads

  for (int k0 = 0; k0 < Cin; k0 += 64) {
#pragma unroll
    for (int l = 0; l < 4; ++l) {
      load_lds16(Abase + (size_t)k0 * 2 + (size_t)l * rstep8, &As[(wid * 32 + l * 8) * 64]);
      load_lds16(Bbase + (size_t)k0 * 2 + (size_t)l * rstep8, &Bs[(wid * 32 + l * 8) * 64]);
    }
    __syncthreads();
#pragma unroll
    for (int kk = 0; kk < 2; ++kk) {
      int chunk = (cbase + kk * 4) ^ rswz;
      bf16x8 af[4], bfv[4];
#pragma unroll
      for (int m = 0; m < 4; ++m)
        af[m] = *(const bf16x8*)&As[(wm * 64 + m * 16 + fr) * 64 + chunk * 8];
#pragma unroll
      for (int nt = 0; nt < 4; ++nt)
        bfv[nt] = *(const bf16x8*)&Bs[(wn * 64 + nt * 16 + fr) * 64 + chunk * 8];
#pragma unroll
      for (int m = 0; m < 4; ++m)
#pragma unroll
        for (int nt = 0; nt < 4; ++nt)
          acc[m][nt] = __builtin_amdgcn_mfma_f32_16x16x32_bf16(af[m], bfv[nt], acc[m][nt], 0, 0, 0);
    }
    __syncthreads();
  }

  int col = lane & 15, rowq = lane >> 4;
  int slot = ((b * 64 + blockIdx.x) * 2) + wn;
#pragma unroll
  for (int m = 0; m < 4; ++m) {
    int ob = o0 + wm * 64 + m * 16 + rowq * 4;
    float4 bs = *(const float4*)&bias[ob];
    float sj[4] = {0.f, 0.f, 0.f, 0.f}, qj[4] = {0.f, 0.f, 0.f, 0.f};
#pragma unroll
    for (int nt = 0; nt < 4; ++nt) {
      int n = n0 + wn * 64 + nt * 16 + col;
      float y0 = acc[m][nt][0] + bs.x;
      float y1 = acc[m][nt][1] + bs.y;
      float y2 = acc[m][nt][2] + bs.z;
      float y3 = acc[m][nt][3] + bs.w;
      ushort4v v;
      v[0] = f2bf(y0); v[1] = f2bf(y1); v[2] = f2bf(y2); v[3] = f2bf(y3);
      *(ushort4v*)&Y[((size_t)b * N + n) * 256 + ob] = v;
      sj[0] += y0; qj[0] = fmaf(y0, y0, qj[0]);
      sj[1] += y1; qj[1] = fmaf(y1, y1, qj[1]);
      sj[2] += y2; qj[2] = fmaf(y2, y2, qj[2]);
      sj[3] += y3; qj[3] = fmaf(y3, y3, qj[3]);
    }
#pragma unroll
    for (int j = 0; j < 4; ++j) {
#pragma unroll
      for (int d = 1; d <= 8; d <<= 1) {
        sj[j] += __shfl_xor(sj[j], d);
        qj[j] += __shfl_xor(qj[j], d);
      }
    }
    if (col == 0) {
      int c0 = blockIdx.y * 128 + wm * 64 + m * 16 + rowq * 4;
#pragma unroll
      for (int j = 0; j < 4; ++j) {
        psum[(size_t)(c0 + j) * NSLOT + slot] = sj[j];
        psumsq[(size_t)(c0 + j) * NSLOT + slot] = qj[j];
      }
    }
  }
}

// ---------------- gemm1 with fused input BN+ReLU (reg-staged B side) ----------------
__global__ __launch_bounds__(256) void gemm_bn_kernel(const unsigned short* __restrict__ X,
                                                      const unsigned short* __restrict__ Wb,
                                                      const float* __restrict__ bias,
                                                      const float* __restrict__ scale,
                                                      const float* __restrict__ shift,
                                                      unsigned short* __restrict__ Y,
                                                      float* __restrict__ psum,
                                                      float* __restrict__ psumsq) {
  const int Cin = C;  // 256
  __shared__ unsigned short As[128 * 64];  // 16KB, swizzled
  __shared__ unsigned short Bs[128 * 64];  // 16KB, swizzled
  __shared__ float sscale[256], sshift[256];
  int n0 = blockIdx.x * 128, o0 = blockIdx.y * 128, b = blockIdx.z;
  int tid = threadIdx.x, lane = tid & 63, wid = tid >> 6;
  int wm = wid >> 1, wn = wid & 1;
  sscale[tid] = scale[tid];
  sshift[tid] = shift[tid];
  floatx4 acc[4][4];
#pragma unroll
  for (int m = 0; m < 4; ++m)
#pragma unroll
    for (int nt = 0; nt < 4; ++nt) acc[m][nt] = (floatx4)(0.0f);

  size_t rsA = (size_t)Cin * 2;
  int cg = (lane & 7) ^ ((lane >> 3) & 7);  // this lane's GLOBAL chunk index
  int chunkSwz = cg * 16;
  const char* Abase = (const char*)Wb + (size_t)(o0 + wid * 32 + (lane >> 3)) * rsA + chunkSwz;
  const char* Bbase = (const char*)X + ((size_t)b * N + n0 + wid * 32 + (lane >> 3)) * rsA + chunkSwz;
  size_t rstep8 = 8 * rsA;
  int fr = lane & 15;
  int cbase = lane >> 4;
  int rswz = lane & 7;
  __syncthreads();  // sscale/sshift visible before first staging use

  for (int k0 = 0; k0 < Cin; k0 += 64) {
    int kb = k0 + cg * 8;
    float4 sc0 = *(const float4*)&sscale[kb];
    float4 sc1 = *(const float4*)&sscale[kb + 4];
    float4 sh0 = *(const float4*)&sshift[kb];
    float4 sh1 = *(const float4*)&sshift[kb + 4];
#pragma unroll
    for (int l = 0; l < 4; ++l) {
      load_lds16(Abase + (size_t)k0 * 2 + (size_t)l * rstep8, &As[(wid * 32 + l * 8) * 64]);
      ushort8v raw = *(const ushort8v*)(Bbase + (size_t)k0 * 2 + (size_t)l * rstep8);
      ushort8v tv;
      tv[0] = f2bf(fmaxf(fmaf(bf2f(raw[0]), sc0.x, sh0.x), 0.f));
      tv[1] = f2bf(fmaxf(fmaf(bf2f(raw[1]), sc0.y, sh0.y), 0.f));
      tv[2] = f2bf(fmaxf(fmaf(bf2f(raw[2]), sc0.z, sh0.z), 0.f));
      tv[3] = f2bf(fmaxf(fmaf(bf2f(raw[3]), sc0.w, sh0.w), 0.f));
      tv[4] = f2bf(fmaxf(fmaf(bf2f(raw[4]), sc1.x, sh1.x), 0.f));
      tv[5] = f2bf(fmaxf(fmaf(bf2f(raw[5]), sc1.y, sh1.y), 0.f));
      tv[6] = f2bf(fmaxf(fmaf(bf2f(raw[6]), sc1.z, sh1.z), 0.f));
      tv[7] = f2bf(fmaxf(fmaf(bf2f(raw[7]), sc1.w, sh1.w), 0.f));
      *(ushort8v*)&Bs[(wid * 32 + l * 8) * 64 + lane * 8] = tv;
    }
    __syncthreads();
#pragma unroll
    for (int kk = 0; kk < 2; ++kk) {
      int chunk = (cbase + kk * 4) ^ rswz;
      bf16x8 af[4], bfv[4];
#pragma unroll
      for (int m = 0; m < 4; ++m)
        af[m] = *(const bf16x8*)&As[(wm * 64 + m * 16 + fr) * 64 + chunk * 8];
#pragma unroll
      for (int nt = 0; nt < 4; ++nt)
        bfv[nt] = *(const bf16x8*)&Bs[(wn * 64 + nt * 16 + fr) * 64 + chunk * 8];
#pragma unroll
      for (int m = 0; m < 4; ++m)
#pragma unroll
        for (int nt = 0; nt < 4; ++nt)
          acc[m][nt] = __builtin_amdgcn_mfma_f32_16x16x32_bf16(af[m], bfv[nt], acc[m][nt], 0, 0, 0);
    }
    __syncthreads();
  }

  int col = lane & 15, rowq = lane >> 4;
  int slot = ((b * 64 + blockIdx.x) * 2) + wn;
#pragma unroll
  for (int m = 0; m < 4; ++m) {
    int ob = o0 + wm * 64 + m * 16 + rowq * 4;
    float4 bs = *(const float4*)&bias[ob];
    float sj[4] = {0.f, 0.f, 0.f, 0.f}, qj[4] = {0.f, 0.f, 0.f, 0.f};
#pragma unroll
    for (int nt = 0; nt < 4; ++nt) {
      int n = n0 + wn * 64 + nt * 16 + col;
      float y0 = acc[m][nt][0] + bs.x;
      float y1 = acc[m][nt][1] + bs.y;
      float y2 = acc[m][nt][2] + bs.z;
      float y3 = acc[m][nt][3] + bs.w;
      ushort4v v;
      v[0] = f2bf(y0); v[1] = f2bf(y1); v[2] = f2bf(y2); v[3] = f2bf(y3);
      *(ushort4v*)&Y[((size_t)b * N + n) * 256 + ob] = v;
      sj[0] += y0; qj[0] = fmaf(y0, y0, qj[0]);
      sj[1] += y1; qj[1] = fmaf(y1, y1, qj[1]);
      sj[2] += y2; qj[2] = fmaf(y2, y2, qj[2]);
      sj[3] += y3; qj[3] = fmaf(y3, y3, qj[3]);
    }
#pragma unroll
    for (int j = 0; j < 4; ++j) {
#pragma unroll
      for (int d = 1; d <= 8; d <<= 1) {
        sj[j] += __shfl_xor(sj[j], d);
        qj[j] += __shfl_xor(qj[j], d);
      }
    }
    if (col == 0) {
      int c0 = blockIdx.y * 128 + wm * 64 + m * 16 + rowq * 4;
#pragma unroll
      for (int j = 0; j < 4; ++j) {
        psum[(size_t)(c0 + j) * NSLOT + slot] = sj[j];
        psumsq[(size_t)(c0 + j) * NSLOT + slot] = qj[j];
      }
    }
  }
}

// ---------------- parallel reduce partials -> BN scale/shift (256 blocks) ----------------
__global__ __launch_bounds__(256) void bnparam_kernel(const float* __restrict__ psum,
                                                      const float* __restrict__ psumsq,
                                                      const float* __restrict__ gamma,
                                                      const float* __restrict__ beta,
                                                      float* __restrict__ scale,
                                                      float* __restrict__ shift) {
  int c = blockIdx.x, tid = threadIdx.x;
  const float* ps = psum + (size_t)c * NSLOT;
  const float* pq = psumsq + (size_t)c * NSLOT;
  float s = 0.f, q = 0.f;
#pragma unroll
  for (int i = 0; i < NSLOT / 256; ++i) {
    s += ps[tid + i * 256];
    q += pq[tid + i * 256];
  }
#pragma unroll
  for (int d = 1; d <= 32; d <<= 1) {
    s += __shfl_xor(s, d);
    q += __shfl_xor(q, d);
  }
  __shared__ float ls[4], lq[4];
  int wid = tid >> 6;
  if ((tid & 63) == 0) { ls[wid] = s; lq[wid] = q; }
  __syncthreads();
  if (tid == 0) {
    s = ls[0] + ls[1] + ls[2] + ls[3];
    q = lq[0] + lq[1] + lq[2] + lq[3];
    float m = s * (1.0f / CNT);
    float v = q * (1.0f / CNT) - m * m;
    float sc = gamma[c] * rsqrtf(v + 1e-5f);
    scale[c] = sc;
    shift[c] = beta[c] - m * sc;
  }
}

// ---------------- final: BN+ReLU + transpose [b][n][o] bf16 -> out [b][o][n] f32 ----------------
__global__ __launch_bounds__(256) void bnreluT_kernel(const unsigned short* __restrict__ Y,
                                                      const float* __restrict__ scale,
                                                      const float* __restrict__ shift,
                                                      float* __restrict__ out) {
  __shared__ float t[64][65];
  int n0 = blockIdx.x * 64, o0 = blockIdx.y * 64, b = blockIdx.z;
  int tid = threadIdx.x, r = tid >> 2, q = tid & 3;
  const unsigned short* yp = Y + ((size_t)b * N + n0 + r) * 256 + o0 + q * 16;
#pragma unroll
  for (int h = 0; h < 2; ++h) {
    ushort8v v = *(const ushort8v*)(yp + h * 8);
#pragma unroll
    for (int i = 0; i < 8; ++i) {
      int oc = q * 16 + h * 8 + i;
      float f = fmaxf(fmaf(bf2f(v[i]), scale[o0 + oc], shift[o0 + oc]), 0.f);
      t[oc][r] = f;
    }
  }
  __syncthreads();
  float* op = out + ((size_t)b * 256 + o0 + r) * N + n0 + q * 16;
#pragma unroll
  for (int i = 0; i < 4; ++i) {
    float4 v = make_float4(t[r][q * 16 + i * 4 + 0], t[r][q * 16 + i * 4 + 1],
                           t[r][q * 16 + i * 4 + 2], t[r][q * 16 + i * 4 + 3]);
    *(float4*)(op + i * 4) = v;
  }
}

extern "C" void kernel_launch(void* const* d_in, const int* in_sizes, int n_in,
                              void* d_out, int out_size, void* d_ws, size_t ws_size,
                              hipStream_t stream) {
  const float* xyz1 = (const float*)d_in[0];
  const float* xyz2 = (const float*)d_in[1];
  const float* points1 = (const float*)d_in[2];
  const float* points2 = (const float*)d_in[3];
  const float* w0 = (const float*)d_in[4];
  const float* b0 = (const float*)d_in[5];
  const float* g0 = (const float*)d_in[6];
  const float* be0 = (const float*)d_in[7];
  const float* w1 = (const float*)d_in[8];
  const float* b1 = (const float*)d_in[9];
  const float* g1 = (const float*)d_in[10];
  const float* be1 = (const float*)d_in[11];
  float* out = (float*)d_out;

  char* ws = (char*)d_ws;
  float* scale0 = (float*)ws;          ws += 256 * 4;
  float* shift0 = (float*)ws;          ws += 256 * 4;
  float* scale1 = (float*)ws;          ws += 256 * 4;
  float* shift1 = (float*)ws;          ws += 256 * 4;
  float* psum = (float*)ws;            ws += (size_t)C * NSLOT * 4;    // 1MB
  float* psumsq = (float*)ws;          ws += (size_t)C * NSLOT * 4;    // 1MB
  unsigned short* w0b = (unsigned short*)ws;  ws += (size_t)C * CIN * 2;   // 256KB
  unsigned short* w1b = (unsigned short*)ws;  ws += (size_t)C * C * 2;     // 128KB
  unsigned short* p2t = (unsigned short*)ws;  ws += (size_t)B * S * 256 * 2;   // 8MB
  unsigned short* Xb = (unsigned short*)ws;   ws += (size_t)B * N * 512 * 2;   // 64MB
  unsigned short* Yb = (unsigned short*)ws;   ws += (size_t)B * N * 256 * 2;   // 32MB
  unsigned short* Zb = Xb;  // gemm1 output reuses Xb (dead after gemm0)

  prep_kernel<<<dim3(1024 + 768), 256, 0, stream>>>(points2, w0, w1, p2t, w0b, w1b);
  nn3_kernel<<<dim3(2048 + 4096), 256, 0, stream>>>(xyz1, xyz2, p2t, points1, Xb);
  gemm_kernel<<<dim3(N / 128, 2, B), 256, 0, stream>>>(Xb, w0b, b0, Yb, psum, psumsq, CIN);
  bnparam_kernel<<<dim3(C), 256, 0, stream>>>(psum, psumsq, g0, be0, scale0, shift0);
  gemm_bn_kernel<<<dim3(N / 128, 2, B), 256, 0, stream>>>(Yb, w1b, b1, scale0, shift0,
                                                          Zb, psum, psumsq);
  bnparam_kernel<<<dim3(C), 256, 0, stream>>>(psum, psumsq, g1, be1, scale1, shift1);
  bnreluT_kernel<<<dim3(N / 64, 4, B), 256, 0, stream>>>(Zb, scale1, shift1, out);
}